// Round 16
// baseline (945.620 us; speedup 1.0000x reference)
//
#include <hip/hip_runtime.h>
#include <math.h>

#define H 256
#define NHEAD 4
#define HD 64
#define NEXP 8
#define SEQL 200
#define BATCH 128
#define NF (BATCH*SEQL)
#define KT 64
#define QT 64
#define QW 8   // queries per wave (8 waves x 8 q = QT)

// ---------------- helpers ----------------
__device__ __forceinline__ float blk_sum256(float v, float* s4) {
    #pragma unroll
    for (int o = 32; o > 0; o >>= 1) v += __shfl_xor(v, o, 64);
    __syncthreads();
    if ((threadIdx.x & 63) == 0) s4[threadIdx.x >> 6] = v;
    __syncthreads();
    return s4[0] + s4[1] + s4[2] + s4[3];
}

// ---------------- fused embedding + LN1 (block 0): writes raw x AND LN(x) --------------
__global__ __launch_bounds__(256) void embed_ln_kernel(
    const int* __restrict__ seqs, const float* __restrict__ item_emb,
    const float* __restrict__ pos_emb, float* __restrict__ x,
    float* __restrict__ xln, const float* __restrict__ w, const float* __restrict__ b)
{
    __shared__ float s4[4];
    int n = blockIdx.x, t = threadIdx.x;
    int id = seqs[n];
    int pos = (id != 0) ? (n % SEQL) + 1 : 0;
    float v = item_emb[(size_t)id*H + t] * 16.0f + pos_emb[(size_t)pos*H + t];
    x[(size_t)n*H + t] = v;
    float mean = blk_sum256(v, s4) * (1.f/H);
    float d = v - mean;
    float var = blk_sum256(d*d, s4) * (1.f/H);
    xln[(size_t)n*H + t] = d * rsqrtf(var + 1e-8f) * w[t] + b[t];
}

// ---------------- layernorm (gather + optional residual) ----------------
__global__ __launch_bounds__(256) void ln_kernel(
    const float* __restrict__ in, const float* __restrict__ res,
    float* __restrict__ out, const float* __restrict__ w, const float* __restrict__ b,
    float eps, int base, int step)
{
    __shared__ float s4[4];
    int r = blockIdx.x, t = threadIdx.x;
    float v = in[(size_t)(base + r*step)*H + t];
    if (res) v += res[(size_t)r*H + t];
    float mean = blk_sum256(v, s4) * (1.f/H);
    float d = v - mean;
    float var = blk_sum256(d*d, s4) * (1.f/H);
    out[(size_t)r*H + t] = d * rsqrtf(var + eps) * w[t] + b[t];
}

// ---------------- fused LN2 + gate top-2 (bit-identical values via LDS) ----------------
__global__ __launch_bounds__(256) void ln2_gate_kernel(
    const float* __restrict__ in, const float* __restrict__ res,
    float* __restrict__ out, const float* __restrict__ w, const float* __restrict__ b,
    const float* __restrict__ gw, const float* __restrict__ gb,
    int* __restrict__ top_idx, float* __restrict__ top_w)
{
    __shared__ float s4[4];
    __shared__ float xs[H];
    __shared__ float gl[NEXP];
    int n = blockIdx.x, t = threadIdx.x;
    float v = in[(size_t)n*H + t] + res[(size_t)n*H + t];
    float mean = blk_sum256(v, s4) * (1.f/H);
    float d = v - mean;
    float var = blk_sum256(d*d, s4) * (1.f/H);
    float r = d * rsqrtf(var + 1e-8f) * w[t] + b[t];
    out[(size_t)n*H + t] = r;
    xs[t] = r;
    __syncthreads();
    int wv = t >> 6, lane = t & 63;
    float xv[4];
    #pragma unroll
    for (int c = 0; c < 4; ++c) xv[c] = xs[lane + (c<<6)];
    #pragma unroll
    for (int s = 0; s < 2; ++s) {
        int e = wv*2 + s;
        float acc = 0.f;
        #pragma unroll
        for (int c = 0; c < 4; ++c) acc += xv[c] * gw[(size_t)e*H + lane + (c<<6)];
        #pragma unroll
        for (int o = 32; o > 0; o >>= 1) acc += __shfl_xor(acc, o, 64);
        if (lane == 0) gl[e] = acc + gb[e];
    }
    __syncthreads();
    if (t == 0) {
        int i0 = 0;
        for (int e = 1; e < NEXP; ++e) if (gl[e] > gl[i0]) i0 = e;
        int i1 = -1;
        for (int e = 0; e < NEXP; ++e) { if (e == i0) continue; if (i1 < 0 || gl[e] > gl[i1]) i1 = e; }
        float e1 = expf(gl[i1] - gl[i0]);
        float w0 = 1.f / (1.f + e1);
        top_idx[n*2+0] = i0; top_idx[n*2+1] = i1;
        top_w[n*2+0] = w0;  top_w[n*2+1] = 1.f - w0;
    }
}

// ---------------- fused moe combine + layernorm ----------------
__global__ __launch_bounds__(256) void moe_ln_kernel(
    const float* __restrict__ x, const float* __restrict__ ybuf,
    const int* __restrict__ tok_pair, const float* __restrict__ top_w,
    float* __restrict__ out, const float* __restrict__ w, const float* __restrict__ b,
    float eps)
{
    __shared__ float s4[4];
    int r = blockIdx.x, t = threadIdx.x;
    int p0 = tok_pair[r*2], p1 = tok_pair[r*2+1];
    float v = x[(size_t)r*H + t]
            + top_w[r*2+0] * ybuf[(size_t)p0*H + t]
            + top_w[r*2+1] * ybuf[(size_t)p1*H + t];
    float mean = blk_sum256(v, s4) * (1.f/H);
    float d = v - mean;
    float var = blk_sum256(d*d, s4) * (1.f/H);
    out[(size_t)r*H + t] = d * rsqrtf(var + eps) * w[t] + b[t];
}

// ---------------- GEMM (64x64 tile) — proven bit-path ----------------
__global__ __launch_bounds__(256) void gemm_nt(
    const float* __restrict__ A, const float* __restrict__ W,
    const float* __restrict__ bias, float* __restrict__ out, int nrows)
{
    __shared__ float As[16][68];
    __shared__ float Ws[16][68];
    int r0 = blockIdx.x * 64;
    if (r0 >= nrows) return;
    int c0 = blockIdx.y * 64;
    int tid = threadIdx.x;
    int tx = tid & 15, ty = tid >> 4;
    int lrow = tid >> 2, lkg = (tid & 3) << 2;
    float acc[4][4] = {};
    for (int kk = 0; kk < H; kk += 16) {
        float4 av = make_float4(0.f,0.f,0.f,0.f);
        int gr = r0 + lrow;
        if (gr < nrows) av = *(const float4*)(A + (size_t)gr*H + kk + lkg);
        As[lkg+0][lrow]=av.x; As[lkg+1][lrow]=av.y; As[lkg+2][lrow]=av.z; As[lkg+3][lrow]=av.w;
        float4 wv = *(const float4*)(W + (size_t)(c0+lrow)*H + kk + lkg);
        Ws[lkg+0][lrow]=wv.x; Ws[lkg+1][lrow]=wv.y; Ws[lkg+2][lrow]=wv.z; Ws[lkg+3][lrow]=wv.w;
        __syncthreads();
        #pragma unroll
        for (int k = 0; k < 16; ++k) {
            float4 a = *(const float4*)&As[k][ty<<2];
            float4 bv = *(const float4*)&Ws[k][tx<<2];
            float aa[4] = {a.x,a.y,a.z,a.w};
            float bb[4] = {bv.x,bv.y,bv.z,bv.w};
            #pragma unroll
            for (int ii = 0; ii < 4; ++ii)
                #pragma unroll
                for (int jj = 0; jj < 4; ++jj)
                    acc[ii][jj] += aa[ii] * bb[jj];
        }
        __syncthreads();
    }
    #pragma unroll
    for (int ii = 0; ii < 4; ++ii) {
        int gr = r0 + (ty<<2) + ii;
        if (gr < nrows) {
            #pragma unroll
            for (int jj = 0; jj < 4; ++jj) {
                int gc = c0 + (tx<<2) + jj;
                out[(size_t)gr*H + gc] = acc[ii][jj] + bias[gc];
            }
        }
    }
}

// ---------------- 128x128 GEMM body: double-buffered, 1 barrier/step -------------------
template<int GATHER, int RELU, int BT>
__device__ __forceinline__ void gemm128_body(
    const float* __restrict__ A, const float* __restrict__ W,
    const float* __restrict__ bias, float* __restrict__ out, int nrows,
    const int* __restrict__ pair_tok)
{
    __shared__ float As[2][16*132];
    __shared__ float Ws[2][16*132];
    int r0 = blockIdx.x * 128;
    if (r0 >= nrows) return;
    int c0 = blockIdx.y * 128;
    int tid = threadIdx.x;
    int tx = tid & 15, ty = tid >> 4;
    int lrow = tid >> 1, lkg = (tid & 1) << 3;
    int ar = r0 + lrow;
    bool va = ar < nrows;
    int ga = ar;
    if (GATHER) ga = va ? pair_tok[r0 + lrow] : 0;
    const float* ap = A + (size_t)(va ? ga : 0)*H + lkg;
    const float* wpT = W + (size_t)(c0 + lrow)*H + lkg;
    int kr0 = tid >> 5, cg = (tid & 31) << 2;
    const float* wpN0 = W + (size_t)kr0*H + c0 + cg;
    const float* wpN1 = wpN0 + (size_t)8*H;
    const float4 f4z = make_float4(0.f,0.f,0.f,0.f);
    float4 av0, av1, wv0, wv1;

#define G128_LOAD(S) {                                                        \
        int kk_ = (S)*16;                                                     \
        if (va) { av0 = *(const float4*)(ap + kk_);                           \
                  av1 = *(const float4*)(ap + kk_ + 4); }                     \
        else { av0 = f4z; av1 = f4z; }                                        \
        if (BT) { wv0 = *(const float4*)(wpT + kk_);                          \
                  wv1 = *(const float4*)(wpT + kk_ + 4); }                    \
        else { wv0 = *(const float4*)(wpN0 + (size_t)kk_*H);                  \
               wv1 = *(const float4*)(wpN1 + (size_t)kk_*H); } }

#define G128_WRITE(BI) {                                                      \
        float* as_ = As[BI]; float* ws_ = Ws[BI];                             \
        as_[(lkg+0)*132 + lrow]=av0.x; as_[(lkg+1)*132 + lrow]=av0.y;         \
        as_[(lkg+2)*132 + lrow]=av0.z; as_[(lkg+3)*132 + lrow]=av0.w;         \
        as_[(lkg+4)*132 + lrow]=av1.x; as_[(lkg+5)*132 + lrow]=av1.y;         \
        as_[(lkg+6)*132 + lrow]=av1.z; as_[(lkg+7)*132 + lrow]=av1.w;         \
        if (BT) {                                                             \
            ws_[(lkg+0)*132 + lrow]=wv0.x; ws_[(lkg+1)*132 + lrow]=wv0.y;     \
            ws_[(lkg+2)*132 + lrow]=wv0.z; ws_[(lkg+3)*132 + lrow]=wv0.w;     \
            ws_[(lkg+4)*132 + lrow]=wv1.x; ws_[(lkg+5)*132 + lrow]=wv1.y;     \
            ws_[(lkg+6)*132 + lrow]=wv1.z; ws_[(lkg+7)*132 + lrow]=wv1.w;     \
        } else {                                                              \
            *(float4*)&ws_[kr0*132 + cg]     = wv0;                           \
            *(float4*)&ws_[(kr0+8)*132 + cg] = wv1;                           \
        } }

    const int NS = H/16;   // 16 steps
    float acc[8][8] = {};
    G128_LOAD(0)
    G128_WRITE(0)
    G128_LOAD(1)
    __syncthreads();
    for (int s = 0; s < NS; ++s) {
        int cur = s & 1;
        if (s + 1 < NS) {
            G128_WRITE((s+1) & 1)
            if (s + 2 < NS) G128_LOAD(s+2)
        }
        const float* as = As[cur];
        const float* bs = Ws[cur];
        #pragma unroll
        for (int k = 0; k < 16; ++k) {
            float4 a0 = *(const float4*)&as[k*132 + (ty<<2)];
            float4 a1 = *(const float4*)&as[k*132 + 64 + (ty<<2)];
            float4 b0 = *(const float4*)&bs[k*132 + (tx<<2)];
            float4 b1 = *(const float4*)&bs[k*132 + 64 + (tx<<2)];
            float aa[8] = {a0.x,a0.y,a0.z,a0.w,a1.x,a1.y,a1.z,a1.w};
            float bb[8] = {b0.x,b0.y,b0.z,b0.w,b1.x,b1.y,b1.z,b1.w};
            #pragma unroll
            for (int ii = 0; ii < 8; ++ii)
                #pragma unroll
                for (int jj = 0; jj < 8; ++jj)
                    acc[ii][jj] += aa[ii] * bb[jj];
        }
        __syncthreads();
    }
#undef G128_LOAD
#undef G128_WRITE
    #pragma unroll
    for (int hr = 0; hr < 2; ++hr)
        #pragma unroll
        for (int ii = 0; ii < 4; ++ii) {
            int row = r0 + 64*hr + (ty<<2) + ii;
            if (row < nrows) {
                #pragma unroll
                for (int hc = 0; hc < 2; ++hc) {
                    int col = c0 + 64*hc + (tx<<2);
                    #pragma unroll
                    for (int jj = 0; jj < 4; ++jj) {
                        float o = acc[4*hr+ii][4*hc+jj] + bias[col+jj];
                        if (RELU) o = fmaxf(o, 0.f);
                        out[(size_t)row*H + col + jj] = o;
                    }
                }
            }
        }
}

// fused multi-GEMM over z: A = (z==0 ? A0 : A1), W += z*H*H, bias += z*H, out += z*NF*H
__global__ __launch_bounds__(256) void gemm_nt128z(
    const float* __restrict__ A0, const float* __restrict__ A1,
    const float* __restrict__ Wbase, const float* __restrict__ biasbase,
    float* __restrict__ outbase, int nrows)
{
    int z = blockIdx.z;
    const float* A = (z == 0) ? A0 : A1;
    gemm128_body<0,0,1>(A, Wbase + (size_t)z*H*H, biasbase + (size_t)z*H,
                        outbase + (size_t)z*NF*H, nrows, nullptr);
}

__global__ __launch_bounds__(256) void gemm_nt128(
    const float* __restrict__ A, const float* __restrict__ W,
    const float* __restrict__ bias, float* __restrict__ out, int nrows)
{
    gemm128_body<0,0,1>(A, W, bias, out, nrows, nullptr);
}

__global__ __launch_bounds__(256) void moe1_128(
    const float* __restrict__ X, const float* __restrict__ W1base,
    const float* __restrict__ b1base, const int* __restrict__ pair_tok,
    const int* __restrict__ offsets, const int* __restrict__ counts,
    float* __restrict__ hbuf)
{
    int e = blockIdx.z;
    int cnt = counts[e], off = offsets[e];
    gemm128_body<1,1,0>(X, W1base + (size_t)e*H*H, b1base + (size_t)e*H,
                        hbuf + (size_t)off*H, cnt, pair_tok + off);
}

__global__ __launch_bounds__(256) void moe2_128(
    const float* __restrict__ Hbuf, const float* __restrict__ W2base,
    const float* __restrict__ b2base, const int* __restrict__ offsets,
    const int* __restrict__ counts, float* __restrict__ ybuf)
{
    int e = blockIdx.z;
    int cnt = counts[e], off = offsets[e];
    gemm128_body<0,0,0>(Hbuf + (size_t)off*H, W2base + (size_t)e*H*H, b2base + (size_t)e*H,
                        ybuf + (size_t)off*H, cnt, nullptr);
}

// ---------------- flash attention — R12 kernel + z-interleaved grid ----------------
// grid (B*nz, NH); z = bx % nz interleaves heavy (high-z) blocks through dispatch.
__global__ __launch_bounds__(512) void attn_kernel(
    const float* __restrict__ qbuf, const float* __restrict__ kbuf,
    const float* __restrict__ vbuf, float* __restrict__ ctx, int nq, int nz)
{
    __shared__ float kv[KT*(HD+4)];     // K: kv[row*68+d] ; V^T: kv[d*68+key]
    __shared__ float qs[QT][HD+4];
    __shared__ float ps[QT][KT+4];
    int bx = blockIdx.x;
    int b = bx / nz, z = bx % nz;
    int h = blockIdx.y;
    int qbase = z * QT;
    int nqt = nq - qbase;
    if (nqt <= 0) return;
    if (nqt > QT) nqt = QT;
    int tid = threadIdx.x, w = tid >> 6, lane = tid & 63;   // w in 0..7
    int off = SEQL - nq;
    for (int i = tid; i < QT*(HD/4); i += 512) {
        int row = i >> 4, c4 = (i & 15) << 2;
        float4 qv = make_float4(0.f,0.f,0.f,0.f);
        if (row < nqt) qv = *(const float4*)(qbuf + (size_t)(b*nq + qbase + row)*H + h*HD + c4);
        *(float4*)&qs[row][c4] = qv;
    }
    float m[QW], l[QW], acc[QW];
    #pragma unroll
    for (int i = 0; i < QW; ++i) { m[i] = -3e30f; l[i] = 0.f; acc[i] = 0.f; }
    int wq0 = w * QW;
    int wqn = nqt - wq0; if (wqn > QW) wqn = QW;    // may be <= 0 (idle wave)
    int wmaxpos = qbase + wq0 + (wqn > 0 ? wqn - 1 : 0) + off;
    int ntiles = (qbase + nqt - 1 + off) / KT + 1;
    int q_sub = lane >> 3, kq = lane & 7;
    for (int t = 0; t < ntiles; ++t) {
        int kbase = t * KT;
        bool active = (wqn > 0) && (kbase <= wmaxpos);
        __syncthreads();                 // prev PV (and qs stage at t=0) complete
        // ---- stage K rows ----
        for (int i = tid; i < KT*(HD/4); i += 512) {
            int row = i >> 4, c4 = (i & 15) << 2;
            int key = kbase + row;
            float4 kvv = make_float4(0.f,0.f,0.f,0.f);
            if (key < SEQL) kvv = *(const float4*)(kbuf + (size_t)(b*SEQL + key)*H + h*HD + c4);
            *(float4*)&kv[row*(HD+4) + c4] = kvv;
        }
        __syncthreads();
        // ---- phase 1: scores, lane = key ----
        if (active) {
            float s[QW];
            #pragma unroll
            for (int qi = 0; qi < QW; ++qi) s[qi] = 0.f;
            #pragma unroll 4
            for (int d4 = 0; d4 < HD; d4 += 4) {
                float4 k4 = *(const float4*)&kv[lane*(HD+4) + d4];
                #pragma unroll
                for (int qi = 0; qi < QW; ++qi) {
                    float4 q4 = *(const float4*)&qs[wq0+qi][d4];
                    s[qi] += k4.x*q4.x + k4.y*q4.y + k4.z*q4.z + k4.w*q4.w;
                }
            }
            #pragma unroll
            for (int qi = 0; qi < QW; ++qi) {
                if (qi < wqn) {
                    int qpos = qbase + wq0 + qi + off;
                    bool valid = (kbase + lane) <= qpos;
                    ps[wq0+qi][lane] = valid ? s[qi]*0.125f : -3e30f;
                }
            }
        }
        __syncthreads();                 // scores done reading K from kv
        // ---- stage V transposed into same buffer ----
        {
            int key = kbase + lane;
            bool kval = key < SEQL;
            const float* vp = vbuf + (size_t)(b*SEQL + (kval ? key : 0))*H + h*HD;
            #pragma unroll
            for (int it = 0; it < 2; ++it) {
                int c4 = ((it << 3) + w) << 2;
                float4 vv = make_float4(0.f,0.f,0.f,0.f);
                if (kval) vv = *(const float4*)(vp + c4);
                kv[(c4+0)*(KT+4) + lane] = vv.x;
                kv[(c4+1)*(KT+4) + lane] = vv.y;
                kv[(c4+2)*(KT+4) + lane] = vv.z;
                kv[(c4+3)*(KT+4) + lane] = vv.w;
            }
        }
        __syncthreads();
        if (active) {
            // ---- phase 2: transposed softmax ----
            float mq = m[0];
            #pragma unroll
            for (int i = 1; i < QW; ++i) if (q_sub == i) mq = m[i];
            const float2* pr = (const float2*)&ps[wq0+q_sub][kq*8];
            float2 a0 = pr[0], a1 = pr[1], a2 = pr[2], a3 = pr[3];
            float mloc = fmaxf(fmaxf(fmaxf(a0.x,a0.y), fmaxf(a1.x,a1.y)),
                               fmaxf(fmaxf(a2.x,a2.y), fmaxf(a3.x,a3.y)));
            float tm = mloc;
            #pragma unroll
            for (int o = 1; o < 8; o <<= 1) tm = fmaxf(tm, __shfl_xor(tm, o, 64));
            float mn = fmaxf(mq, tm);
            float p0 = expf(a0.x-mn), p1 = expf(a0.y-mn), p2 = expf(a1.x-mn), p3 = expf(a1.y-mn);
            float p4 = expf(a2.x-mn), p5 = expf(a2.y-mn), p6 = expf(a3.x-mn), p7 = expf(a3.y-mn);
            float psum = ((p0+p1)+(p2+p3)) + ((p4+p5)+(p6+p7));
            #pragma unroll
            for (int o = 1; o < 8; o <<= 1) psum += __shfl_xor(psum, o, 64);
            float2* pw = (float2*)&ps[wq0+q_sub][kq*8];
            pw[0] = make_float2(p0,p1); pw[1] = make_float2(p2,p3);
            pw[2] = make_float2(p4,p5); pw[3] = make_float2(p6,p7);
            #pragma unroll
            for (int qi = 0; qi < QW; ++qi) {
                float tmv = __shfl(tm, qi*8, 64);
                float psv = __shfl(psum, qi*8, 64);
                if (qi < wqn) {
                    float mn2 = fmaxf(m[qi], tmv);
                    float scl = expf(m[qi] - mn2);
                    l[qi] = l[qi]*scl + psv;
                    acc[qi] *= scl;
                    m[qi] = mn2;
                }
            }
            // ---- phase 3: PV, lane = dim ----
            #pragma unroll 4
            for (int k4 = 0; k4 < KT; k4 += 4) {
                float4 v4 = *(const float4*)&kv[lane*(KT+4) + k4];
                #pragma unroll
                for (int qi = 0; qi < QW; ++qi) {
                    if (qi < wqn) {
                        float4 p4v = *(const float4*)&ps[wq0+qi][k4];
                        acc[qi] += p4v.x*v4.x + p4v.y*v4.y + p4v.z*v4.z + p4v.w*v4.w;
                    }
                }
            }
        }
    }
    #pragma unroll
    for (int qi = 0; qi < QW; ++qi) {
        if (qi < wqn) {
            ctx[(size_t)(b*nq + qbase + wq0 + qi)*H + h*HD + lane] = acc[qi] / l[qi];
        }
    }
}

// ---------------- count: LDS histogram ----------------
__global__ __launch_bounds__(256) void count_kernel(
    const int* __restrict__ top_idx, int* __restrict__ counts, int nrows)
{
    __shared__ int hist[NEXP];
    int tid = threadIdx.x;
    if (tid < NEXP) hist[tid] = 0;
    __syncthreads();
    int n = blockIdx.x * 256 + tid;
    if (n < nrows) {
        atomicAdd(&hist[top_idx[n*2+0]], 1);
        atomicAdd(&hist[top_idx[n*2+1]], 1);
    }
    __syncthreads();
    if (tid < NEXP && hist[tid] > 0) atomicAdd(&counts[tid], hist[tid]);
}

__global__ void scan_kernel(const int* __restrict__ counts, int* __restrict__ offsets,
                            int* __restrict__ cursor)
{
    int s = 0;
    for (int e = 0; e < NEXP; ++e) { offsets[e] = s; cursor[e] = s; s += counts[e]; }
}

// ---------------- block-aggregated scatter (+ inverse map tok_pair) ----------------
__global__ __launch_bounds__(256) void scatter_kernel(
    const int* __restrict__ top_idx,
    int* __restrict__ cursor, int* __restrict__ pair_tok, int* __restrict__ tok_pair, int nrows)
{
    __shared__ int lcnt[NEXP];
    __shared__ int lbase[NEXP];
    int tid = threadIdx.x;
    if (tid < NEXP) lcnt[tid] = 0;
    __syncthreads();
    int n = blockIdx.x * 256 + tid;
    int e0 = 0, e1 = 0, p0 = 0, p1 = 0;
    bool act = n < nrows;
    if (act) {
        e0 = top_idx[n*2+0]; e1 = top_idx[n*2+1];
        p0 = atomicAdd(&lcnt[e0], 1);
        p1 = atomicAdd(&lcnt[e1], 1);
    }
    __syncthreads();
    if (tid < NEXP) lbase[tid] = (lcnt[tid] > 0) ? atomicAdd(&cursor[tid], lcnt[tid]) : 0;
    __syncthreads();
    if (act) {
        int q0 = lbase[e0] + p0, q1 = lbase[e1] + p1;
        pair_tok[q0] = n; pair_tok[q1] = n;
        tok_pair[n*2+0] = q0; tok_pair[n*2+1] = q1;
    }
}

// ---------------- small MoE GEMMs (64-tile, proven) for block-1 sized problems ----------
__global__ __launch_bounds__(256) void moe_gemm1(
    const float* __restrict__ X, const float* __restrict__ W1base,
    const float* __restrict__ b1base, const int* __restrict__ pair_tok,
    const int* __restrict__ offsets, const int* __restrict__ counts,
    float* __restrict__ hbuf)
{
    int e = blockIdx.z;
    int cnt = counts[e];
    int r0 = blockIdx.x * 64;
    if (r0 >= cnt) return;
    int off = offsets[e];
    int c0 = blockIdx.y * 64;
    const float* W = W1base + (size_t)e * H * H;
    const float* bias = b1base + (size_t)e * H;
    __shared__ float As[16][68];
    __shared__ float Bs[16][68];
    int tid = threadIdx.x, tx = tid & 15, ty = tid >> 4;
    int lrow = tid >> 2, lkg = (tid & 3) << 2;
    float acc[4][4] = {};
    for (int kk = 0; kk < H; kk += 16) {
        float4 av = make_float4(0.f,0.f,0.f,0.f);
        int pr = r0 + lrow;
        if (pr < cnt) {
            int tok = pair_tok[off + pr];
            av = *(const float4*)(X + (size_t)tok*H + kk + lkg);
        }
        As[lkg+0][lrow]=av.x; As[lkg+1][lrow]=av.y; As[lkg+2][lrow]=av.z; As[lkg+3][lrow]=av.w;
        float4 wv = *(const float4*)(W + (size_t)(kk+ty)*H + c0 + (tx<<2));
        *(float4*)&Bs[ty][tx<<2] = wv;
        __syncthreads();
        #pragma unroll
        for (int k = 0; k < 16; ++k) {
            float4 a = *(const float4*)&As[k][ty<<2];
            float4 bv = *(const float4*)&Bs[k][tx<<2];
            float aa[4] = {a.x,a.y,a.z,a.w};
            float bb[4] = {bv.x,bv.y,bv.z,bv.w};
            #pragma unroll
            for (int ii = 0; ii < 4; ++ii)
                #pragma unroll
                for (int jj = 0; jj < 4; ++jj)
                    acc[ii][jj] += aa[ii] * bb[jj];
        }
        __syncthreads();
    }
    #pragma unroll
    for (int ii = 0; ii < 4; ++ii) {
        int pr = r0 + (ty<<2) + ii;
        if (pr < cnt) {
            #pragma unroll
            for (int jj = 0; jj < 4; ++jj) {
                int gc = c0 + (tx<<2) + jj;
                hbuf[(size_t)(off+pr)*H + gc] = fmaxf(acc[ii][jj] + bias[gc], 0.f);
            }
        }
    }
}

__global__ __launch_bounds__(256) void moe_gemm2(
    const float* __restrict__ Hbuf, const float* __restrict__ W2base,
    const float* __restrict__ b2base, const int* __restrict__ offsets,
    const int* __restrict__ counts, float* __restrict__ ybuf)
{
    int e = blockIdx.z;
    int cnt = counts[e];
    int r0 = blockIdx.x * 64;
    if (r0 >= cnt) return;
    int off = offsets[e];
    int c0 = blockIdx.y * 64;
    const float* W = W2base + (size_t)e * H * H;
    const float* bias = b2base + (size_t)e * H;
    __shared__ float As[16][68];
    __shared__ float Bs[16][68];
    int tid = threadIdx.x, tx = tid & 15, ty = tid >> 4;
    int lrow = tid >> 2, lkg = (tid & 3) << 2;
    float acc[4][4] = {};
    for (int kk = 0; kk < H; kk += 16) {
        float4 av = make_float4(0.f,0.f,0.f,0.f);
        int pr = r0 + lrow;
        if (pr < cnt) av = *(const float4*)(Hbuf + (size_t)(off+pr)*H + kk + lkg);
        As[lkg+0][lrow]=av.x; As[lkg+1][lrow]=av.y; As[lkg+2][lrow]=av.z; As[lkg+3][lrow]=av.w;
        float4 wv = *(const float4*)(W + (size_t)(kk+ty)*H + c0 + (tx<<2));
        *(float4*)&Bs[ty][tx<<2] = wv;
        __syncthreads();
        #pragma unroll
        for (int k = 0; k < 16; ++k) {
            float4 a = *(const float4*)&As[k][ty<<2];
            float4 bv = *(const float4*)&Bs[k][tx<<2];
            float aa[4] = {a.x,a.y,a.z,a.w};
            float bb[4] = {bv.x,bv.y,bv.z,bv.w};
            #pragma unroll
            for (int ii = 0; ii < 4; ++ii)
                #pragma unroll
                for (int jj = 0; jj < 4; ++jj)
                    acc[ii][jj] += aa[ii] * bb[jj];
        }
        __syncthreads();
    }
    #pragma unroll
    for (int ii = 0; ii < 4; ++ii) {
        int pr = r0 + (ty<<2) + ii;
        if (pr < cnt) {
            #pragma unroll
            for (int jj = 0; jj < 4; ++jj) {
                int gc = c0 + (tx<<2) + jj;
                ybuf[(size_t)(off+pr)*H + gc] = acc[ii][jj] + bias[gc];
            }
        }
    }
}

__global__ void zero_kernel(float* __restrict__ p, int n) {
    int i = blockIdx.x * 256 + threadIdx.x;
    if (i < n) p[i] = 0.f;
}

// ---------------- final: LN + user emb + dot(item emb) ----------------
__global__ __launch_bounds__(256) void final_kernel(
    const float* __restrict__ xf, const float* __restrict__ lnw, const float* __restrict__ lnb,
    const float* __restrict__ user_emb, const float* __restrict__ item_emb,
    const int* __restrict__ user_ids, const int* __restrict__ item_ids, float* __restrict__ out)
{
    __shared__ float s4[4];
    int bb = blockIdx.x, t = threadIdx.x;
    float v = xf[(size_t)bb*H + t];
    float mean = blk_sum256(v, s4) * (1.f/H);
    float d = v - mean;
    float var = blk_sum256(d*d, s4) * (1.f/H);
    float lnv = d * rsqrtf(var + 1e-8f) * lnw[t] + lnb[t];
    float fin = lnv + user_emb[(size_t)user_ids[bb]*H + t];
    float prod = fin * item_emb[(size_t)item_ids[bb]*H + t];
    float tot = blk_sum256(prod, s4);
    if (t == 0) out[bb] = tot;
}

// ---------------- launch ----------------
extern "C" void kernel_launch(void* const* d_in, const int* in_sizes, int n_in,
                              void* d_out, int out_size, void* d_ws, size_t ws_size,
                              hipStream_t stream)
{
    (void)in_sizes; (void)n_in; (void)out_size; (void)ws_size;
    const int*   user_ids  = (const int*)d_in[0];
    const int*   log_seqs  = (const int*)d_in[1];
    const int*   item_ids  = (const int*)d_in[2];
    const float* item_emb  = (const float*)d_in[3];
    const float* pos_emb   = (const float*)d_in[4];
    const float* user_emb  = (const float*)d_in[5];
    const float* ln1_w     = (const float*)d_in[6];
    const float* ln1_b     = (const float*)d_in[7];
    const float* inproj_w  = (const float*)d_in[8];
    const float* inproj_b  = (const float*)d_in[9];
    const float* outproj_w = (const float*)d_in[10];
    const float* outproj_b = (const float*)d_in[11];
    const float* ln2_w     = (const float*)d_in[12];
    const float* ln2_b     = (const float*)d_in[13];
    const float* gate_w    = (const float*)d_in[14];
    const float* gate_b    = (const float*)d_in[15];
    const float* e_w1      = (const float*)d_in[16];
    const float* e_b1      = (const float*)d_in[17];
    const float* e_w2      = (const float*)d_in[18];
    const float* e_b2      = (const float*)d_in[19];
    const float* moeln_w   = (const float*)d_in[20];
    const float* moeln_b   = (const float*)d_in[21];
    const float* lastln_w  = (const float*)d_in[22];
    const float* lastln_b  = (const float*)d_in[23];

    float* ws = (float*)d_ws;
    const size_t NFH = (size_t)NF * H;
    float* buf0 = ws;
    float* buf1 = buf0 + NFH;   // buf1+buf2 contiguous -> ybuf region (2*NF rows)
    float* buf2 = buf1 + NFH;
    float* buf3 = buf2 + NFH;   // buf3+buf4 contiguous -> MoE h region (2*NF rows)
    float* buf4 = buf3 + NFH;
    float* s0   = buf4 + NFH;
    float* s1   = s0 + (size_t)BATCH*H;
    float* s2   = s1 + (size_t)BATCH*H;
    float* s3   = s2 + (size_t)BATCH*H;
    float* s6   = s3 + (size_t)BATCH*H;
    float* s4   = s6 + (size_t)BATCH*H;            // 2*BATCH rows (h)
    float* s5   = s4 + (size_t)2*BATCH*H;          // 2*BATCH rows (y)
    float* top_w   = s5 + (size_t)2*BATCH*H;
    int*   top_idx = (int*)(top_w + (size_t)NF*2);
    int*   pair_tok= top_idx + (size_t)NF*2;
    int*   tok_pair= pair_tok + (size_t)NF*2;
    int*   counts  = tok_pair + (size_t)NF*2;
    int*   offsets = counts + NEXP;
    int*   cursor  = offsets + NEXP;

    dim3 blk(256);
    dim3 ablk(512);
    dim3 g128((NF+127)/128, H/128);
    dim3 g128z3((NF+127)/128, H/128, 3);
    dim3 g128z2((NF+127)/128, H/128, 2);
    dim3 gsmall((BATCH+63)/64, H/64);
    dim3 m128((NF+127)/128, H/128, NEXP);
    dim3 msmall((BATCH+63)/64, H/64, NEXP);

    // ================= block 0 : full sequence =================
    {
        const int i = 0;
        const float* Wq = inproj_w + (size_t)i*3*H*H;
        const float* bq = inproj_b + (size_t)i*3*H;
        embed_ln_kernel<<<NF, blk, 0, stream>>>(log_seqs, item_emb, pos_emb, buf0, buf1,
                                                ln1_w + i*H, ln1_b + i*H);
        gemm_nt128z<<<g128z3, blk, 0, stream>>>(buf1, buf0, Wq, bq, buf2, NF);
        attn_kernel<<<dim3(BATCH*4, NHEAD), ablk, 0, stream>>>(buf2, buf3, buf4, buf2, SEQL, 4);
        gemm_nt128<<<g128, blk, 0, stream>>>(buf2, outproj_w + (size_t)i*H*H, outproj_b + i*H, buf3, NF);
        ln2_gate_kernel<<<NF, blk, 0, stream>>>(buf1, buf3, buf0, ln2_w + i*H, ln2_b + i*H,
                                                gate_w + (size_t)i*NEXP*H, gate_b + i*NEXP,
                                                top_idx, top_w);
        zero_kernel<<<1, 32, 0, stream>>>((float*)counts, NEXP);
        count_kernel<<<(NF+255)/256, blk, 0, stream>>>(top_idx, counts, NF);
        scan_kernel<<<1, 1, 0, stream>>>(counts, offsets, cursor);
        scatter_kernel<<<(NF+255)/256, blk, 0, stream>>>(top_idx, cursor, pair_tok, tok_pair, NF);
        moe1_128<<<m128, blk, 0, stream>>>(buf0, e_w1 + (size_t)i*NEXP*H*H, e_b1 + (size_t)i*NEXP*H,
                                           pair_tok, offsets, counts, buf3);
        moe2_128<<<m128, blk, 0, stream>>>(buf3, e_w2 + (size_t)i*NEXP*H*H, e_b2 + (size_t)i*NEXP*H,
                                           offsets, counts, buf1);
        moe_ln_kernel<<<NF, blk, 0, stream>>>(buf0, buf1, tok_pair, top_w, buf3,
                                              moeln_w + i*H, moeln_b + i*H, 1e-5f);
    }

    // ================= block 1 : only last position matters downstream =================
    {
        const int i = 1;
        const float* Wq = inproj_w + (size_t)i*3*H*H;
        const float* bq = inproj_b + (size_t)i*3*H;
        float* X = buf3;
        ln_kernel<<<BATCH, blk, 0, stream>>>(X, nullptr, s0, ln1_w + i*H, ln1_b + i*H, 1e-8f, SEQL-1, SEQL);
        gemm_nt<<<gsmall, blk, 0, stream>>>(s0, Wq, bq, s1, BATCH);            // q (last rows only)
        gemm_nt128z<<<g128z2, blk, 0, stream>>>(X, X, Wq + (size_t)H*H, bq + H, buf0, NF);
        attn_kernel<<<dim3(BATCH, NHEAD), ablk, 0, stream>>>(s1, buf0, buf1, s2, 1, 1);
        gemm_nt<<<gsmall, blk, 0, stream>>>(s2, outproj_w + (size_t)i*H*H, outproj_b + i*H, s3, BATCH);
        ln2_gate_kernel<<<BATCH, blk, 0, stream>>>(s0, s3, s2, ln2_w + i*H, ln2_b + i*H,
                                                   gate_w + (size_t)i*NEXP*H, gate_b + i*NEXP,
                                                   top_idx, top_w);
        zero_kernel<<<1, 32, 0, stream>>>((float*)counts, NEXP);
        count_kernel<<<1, blk, 0, stream>>>(top_idx, counts, BATCH);
        scan_kernel<<<1, 1, 0, stream>>>(counts, offsets, cursor);
        scatter_kernel<<<1, blk, 0, stream>>>(top_idx, cursor, pair_tok, tok_pair, BATCH);
        moe_gemm1<<<msmall, blk, 0, stream>>>(s2, e_w1 + (size_t)i*NEXP*H*H, e_b1 + (size_t)i*NEXP*H,
                                              pair_tok, offsets, counts, s4);
        moe_gemm2<<<msmall, blk, 0, stream>>>(s4, e_w2 + (size_t)i*NEXP*H*H, e_b2 + (size_t)i*NEXP*H,
                                              offsets, counts, s5);
        moe_ln_kernel<<<BATCH, blk, 0, stream>>>(s2, s5, tok_pair, top_w, s6,
                                                 moeln_w + i*H, moeln_b + i*H, 1e-5f);
    }

    final_kernel<<<BATCH, blk, 0, stream>>>(s6, lastln_w, lastln_b, user_emb, item_emb,
                                            user_ids, item_ids, (float*)d_out);
}

// Round 17
// 916.885 us; speedup vs baseline: 1.0313x; 1.0313x over previous
//
#include <hip/hip_runtime.h>
#include <math.h>

#define H 256
#define NHEAD 4
#define HD 64
#define NEXP 8
#define SEQL 200
#define BATCH 128
#define NF (BATCH*SEQL)
#define KT 64
#define QT 64
#define QW 8

typedef __bf16 bf16x8 __attribute__((ext_vector_type(8)));
typedef float  f32x4  __attribute__((ext_vector_type(4)));

__device__ __forceinline__ void split8(const float* __restrict__ p, bf16x8& hi, bf16x8& lo, bool valid) {
    if (valid) {
        float4 a = *(const float4*)p;
        float4 b = *(const float4*)(p + 4);
        float x[8] = {a.x,a.y,a.z,a.w,b.x,b.y,b.z,b.w};
        #pragma unroll
        for (int j = 0; j < 8; ++j) {
            __bf16 h = (__bf16)x[j];
            hi[j] = h;
            lo[j] = (__bf16)(x[j] - (float)h);
        }
    } else {
        #pragma unroll
        for (int j = 0; j < 8; ++j) { hi[j] = (__bf16)0.f; lo[j] = (__bf16)0.f; }
    }
}

#define MFMA3(AH,AL,BH,BL,ACC) \
    ACC = __builtin_amdgcn_mfma_f32_16x16x32_bf16(AH, BH, ACC, 0, 0, 0); \
    ACC = __builtin_amdgcn_mfma_f32_16x16x32_bf16(AH, BL, ACC, 0, 0, 0); \
    ACC = __builtin_amdgcn_mfma_f32_16x16x32_bf16(AL, BH, ACC, 0, 0, 0);

// ---------------- helpers ----------------
__device__ __forceinline__ float blk_sum256(float v, float* s4) {
    #pragma unroll
    for (int o = 32; o > 0; o >>= 1) v += __shfl_xor(v, o, 64);
    __syncthreads();
    if ((threadIdx.x & 63) == 0) s4[threadIdx.x >> 6] = v;
    __syncthreads();
    return s4[0] + s4[1] + s4[2] + s4[3];
}

// ---------------- weight pre-split ----------------
__global__ __launch_bounds__(256) void split_plain(
    const float* __restrict__ in, __bf16* __restrict__ hi, __bf16* __restrict__ lo, int n)
{
    for (int i = blockIdx.x * 256 + threadIdx.x; i < n; i += gridDim.x * 256) {
        float x = in[i];
        __bf16 h = (__bf16)x;
        hi[i] = h;
        lo[i] = (__bf16)(x - (float)h);
    }
}

// experts: in [m][k][n] -> out [m][n][k]
__global__ __launch_bounds__(256) void split_trans(
    const float* __restrict__ in, __bf16* __restrict__ hi, __bf16* __restrict__ lo, int nmats)
{
    int n = nmats * H * H;
    for (int i = blockIdx.x * 256 + threadIdx.x; i < n; i += gridDim.x * 256) {
        int m = i / (H*H), rem = i % (H*H);
        int nn = rem / H, k = rem % H;
        float x = in[(size_t)m*H*H + (size_t)k*H + nn];
        __bf16 h = (__bf16)x;
        hi[i] = h;
        lo[i] = (__bf16)(x - (float)h);
    }
}

// ---------------- fused embedding + LN1 ----------------
__global__ __launch_bounds__(256) void embed_ln_kernel(
    const int* __restrict__ seqs, const float* __restrict__ item_emb,
    const float* __restrict__ pos_emb, float* __restrict__ x,
    float* __restrict__ xln, const float* __restrict__ w, const float* __restrict__ b)
{
    __shared__ float s4[4];
    int n = blockIdx.x, t = threadIdx.x;
    int id = seqs[n];
    int pos = (id != 0) ? (n % SEQL) + 1 : 0;
    float v = item_emb[(size_t)id*H + t] * 16.0f + pos_emb[(size_t)pos*H + t];
    x[(size_t)n*H + t] = v;
    float mean = blk_sum256(v, s4) * (1.f/H);
    float d = v - mean;
    float var = blk_sum256(d*d, s4) * (1.f/H);
    xln[(size_t)n*H + t] = d * rsqrtf(var + 1e-8f) * w[t] + b[t];
}

// ---------------- layernorm ----------------
__global__ __launch_bounds__(256) void ln_kernel(
    const float* __restrict__ in, const float* __restrict__ res,
    float* __restrict__ out, const float* __restrict__ w, const float* __restrict__ b,
    float eps, int base, int step)
{
    __shared__ float s4[4];
    int r = blockIdx.x, t = threadIdx.x;
    float v = in[(size_t)(base + r*step)*H + t];
    if (res) v += res[(size_t)r*H + t];
    float mean = blk_sum256(v, s4) * (1.f/H);
    float d = v - mean;
    float var = blk_sum256(d*d, s4) * (1.f/H);
    out[(size_t)r*H + t] = d * rsqrtf(var + eps) * w[t] + b[t];
}

// ---------------- fused LN2 + gate top-2 ----------------
__global__ __launch_bounds__(256) void ln2_gate_kernel(
    const float* __restrict__ in, const float* __restrict__ res,
    float* __restrict__ out, const float* __restrict__ w, const float* __restrict__ b,
    const float* __restrict__ gw, const float* __restrict__ gb,
    int* __restrict__ top_idx, float* __restrict__ top_w)
{
    __shared__ float s4[4];
    __shared__ float xs[H];
    __shared__ float gl[NEXP];
    int n = blockIdx.x, t = threadIdx.x;
    float v = in[(size_t)n*H + t] + res[(size_t)n*H + t];
    float mean = blk_sum256(v, s4) * (1.f/H);
    float d = v - mean;
    float var = blk_sum256(d*d, s4) * (1.f/H);
    float r = d * rsqrtf(var + 1e-8f) * w[t] + b[t];
    out[(size_t)n*H + t] = r;
    xs[t] = r;
    __syncthreads();
    int wv = t >> 6, lane = t & 63;
    float xv[4];
    #pragma unroll
    for (int c = 0; c < 4; ++c) xv[c] = xs[lane + (c<<6)];
    #pragma unroll
    for (int s = 0; s < 2; ++s) {
        int e = wv*2 + s;
        float acc = 0.f;
        #pragma unroll
        for (int c = 0; c < 4; ++c) acc += xv[c] * gw[(size_t)e*H + lane + (c<<6)];
        #pragma unroll
        for (int o = 32; o > 0; o >>= 1) acc += __shfl_xor(acc, o, 64);
        if (lane == 0) gl[e] = acc + gb[e];
    }
    __syncthreads();
    if (t == 0) {
        int i0 = 0;
        for (int e = 1; e < NEXP; ++e) if (gl[e] > gl[i0]) i0 = e;
        int i1 = -1;
        for (int e = 0; e < NEXP; ++e) { if (e == i0) continue; if (i1 < 0 || gl[e] > gl[i1]) i1 = e; }
        float e1 = expf(gl[i1] - gl[i0]);
        float w0 = 1.f / (1.f + e1);
        top_idx[n*2+0] = i0; top_idx[n*2+1] = i1;
        top_w[n*2+0] = w0;  top_w[n*2+1] = 1.f - w0;
    }
}

// ---------------- fused moe combine + layernorm ----------------
__global__ __launch_bounds__(256) void moe_ln_kernel(
    const float* __restrict__ x, const float* __restrict__ ybuf,
    const int* __restrict__ tok_pair, const float* __restrict__ top_w,
    float* __restrict__ out, const float* __restrict__ w, const float* __restrict__ b,
    float eps)
{
    __shared__ float s4[4];
    int r = blockIdx.x, t = threadIdx.x;
    int p0 = tok_pair[r*2], p1 = tok_pair[r*2+1];
    float v = x[(size_t)r*H + t]
            + top_w[r*2+0] * ybuf[(size_t)p0*H + t]
            + top_w[r*2+1] * ybuf[(size_t)p1*H + t];
    float mean = blk_sum256(v, s4) * (1.f/H);
    float d = v - mean;
    float var = blk_sum256(d*d, s4) * (1.f/H);
    out[(size_t)r*H + t] = d * rsqrtf(var + eps) * w[t] + b[t];
}

// ---------------- small fp32 GEMM (64x64) — proven, block-1 paths ----------------
__global__ __launch_bounds__(256) void gemm_nt(
    const float* __restrict__ A, const float* __restrict__ W,
    const float* __restrict__ bias, float* __restrict__ out, int nrows)
{
    __shared__ float As[16][68];
    __shared__ float Ws[16][68];
    int r0 = blockIdx.x * 64;
    if (r0 >= nrows) return;
    int c0 = blockIdx.y * 64;
    int tid = threadIdx.x;
    int tx = tid & 15, ty = tid >> 4;
    int lrow = tid >> 2, lkg = (tid & 3) << 2;
    float acc[4][4] = {};
    for (int kk = 0; kk < H; kk += 16) {
        float4 av = make_float4(0.f,0.f,0.f,0.f);
        int gr = r0 + lrow;
        if (gr < nrows) av = *(const float4*)(A + (size_t)gr*H + kk + lkg);
        As[lkg+0][lrow]=av.x; As[lkg+1][lrow]=av.y; As[lkg+2][lrow]=av.z; As[lkg+3][lrow]=av.w;
        float4 wv = *(const float4*)(W + (size_t)(c0+lrow)*H + kk + lkg);
        Ws[lkg+0][lrow]=wv.x; Ws[lkg+1][lrow]=wv.y; Ws[lkg+2][lrow]=wv.z; Ws[lkg+3][lrow]=wv.w;
        __syncthreads();
        #pragma unroll
        for (int k = 0; k < 16; ++k) {
            float4 a = *(const float4*)&As[k][ty<<2];
            float4 bv = *(const float4*)&Ws[k][tx<<2];
            float aa[4] = {a.x,a.y,a.z,a.w};
            float bb[4] = {bv.x,bv.y,bv.z,bv.w};
            #pragma unroll
            for (int ii = 0; ii < 4; ++ii)
                #pragma unroll
                for (int jj = 0; jj < 4; ++jj)
                    acc[ii][jj] += aa[ii] * bb[jj];
        }
        __syncthreads();
    }
    #pragma unroll
    for (int ii = 0; ii < 4; ++ii) {
        int gr = r0 + (ty<<2) + ii;
        if (gr < nrows) {
            #pragma unroll
            for (int jj = 0; jj < 4; ++jj) {
                int gc = c0 + (tx<<2) + jj;
                out[(size_t)gr*H + gc] = acc[ii][jj] + bias[gc];
            }
        }
    }
}

// ---------------- split-bf16 MFMA GEMM body (64x64 tile, R2-proven layout) -------------
// W pre-split bf16 [n][k] layout. A fp32, split inline.
template<int GATHER, int RELU>
__device__ __forceinline__ void mfma64_body(
    const float* __restrict__ A, const __bf16* __restrict__ Whi, const __bf16* __restrict__ Wlo,
    const float* __restrict__ bias, float* __restrict__ out, int nrows,
    const int* __restrict__ pair_tok)
{
    int r0 = blockIdx.x * 64;
    if (r0 >= nrows) return;
    int c0 = blockIdx.y * 64;
    int tid = threadIdx.x;
    int wid = tid >> 6, lane = tid & 63;
    int wm = wid >> 1, wn = wid & 1;
    int rbase = r0 + wm*32, cbase = c0 + wn*32;
    int lr = lane & 15, lk = (lane >> 4) << 3;
    f32x4 acc[2][2] = {};
    int ar0 = rbase + lr, ar1 = ar0 + 16;
    bool v0 = ar0 < nrows, v1 = ar1 < nrows;
    int ga0 = ar0, ga1 = ar1;
    if (GATHER) { ga0 = v0 ? pair_tok[ar0] : 0; ga1 = v1 ? pair_tok[ar1] : 0; }
    const float* ap0 = A + (size_t)(v0 ? ga0 : 0)*H + lk;
    const float* ap1 = A + (size_t)(v1 ? ga1 : 0)*H + lk;
    size_t woff = (size_t)(cbase + lr)*H + lk;
    #pragma unroll
    for (int kk = 0; kk < H; kk += 32) {
        bf16x8 ah0, al0, ah1, al1;
        split8(ap0 + kk, ah0, al0, v0);
        split8(ap1 + kk, ah1, al1, v1);
        bf16x8 bh0 = *(const bf16x8*)(Whi + woff + kk);
        bf16x8 bl0 = *(const bf16x8*)(Wlo + woff + kk);
        bf16x8 bh1 = *(const bf16x8*)(Whi + woff + (size_t)16*H + kk);
        bf16x8 bl1 = *(const bf16x8*)(Wlo + woff + (size_t)16*H + kk);
        MFMA3(ah0, al0, bh0, bl0, acc[0][0]);
        MFMA3(ah0, al0, bh1, bl1, acc[0][1]);
        MFMA3(ah1, al1, bh0, bl0, acc[1][0]);
        MFMA3(ah1, al1, bh1, bl1, acc[1][1]);
    }
    int lro = (lane >> 4) << 2;
    #pragma unroll
    for (int mi = 0; mi < 2; ++mi)
        #pragma unroll
        for (int ni = 0; ni < 2; ++ni)
            #pragma unroll
            for (int j = 0; j < 4; ++j) {
                int row = rbase + mi*16 + lro + j;
                int col = cbase + ni*16 + lr;
                if (row < nrows) {
                    float o = acc[mi][ni][j] + bias[col];
                    if (RELU) o = fmaxf(o, 0.f);
                    out[(size_t)row*H + col] = o;
                }
            }
}

// z-fused: A = (z==0 ? A0 : A1), W += z*H*H, bias += z*H, out += z*NF*H
__global__ __launch_bounds__(256) void mfma_z(
    const float* __restrict__ A0, const float* __restrict__ A1,
    const __bf16* __restrict__ Whi, const __bf16* __restrict__ Wlo,
    const float* __restrict__ biasbase, float* __restrict__ outbase, int nrows)
{
    int z = blockIdx.z;
    const float* A = (z == 0) ? A0 : A1;
    mfma64_body<0,0>(A, Whi + (size_t)z*H*H, Wlo + (size_t)z*H*H,
                     biasbase + (size_t)z*H, outbase + (size_t)z*NF*H, nrows, nullptr);
}

__global__ __launch_bounds__(256) void mfma_moe1(
    const float* __restrict__ X, const __bf16* __restrict__ Whi, const __bf16* __restrict__ Wlo,
    const float* __restrict__ b1base, const int* __restrict__ pair_tok,
    const int* __restrict__ offsets, const int* __restrict__ counts,
    float* __restrict__ hbuf)
{
    int e = blockIdx.z;
    int cnt = counts[e], off = offsets[e];
    mfma64_body<1,1>(X, Whi + (size_t)e*H*H, Wlo + (size_t)e*H*H,
                     b1base + (size_t)e*H, hbuf + (size_t)off*H, cnt, pair_tok + off);
}

__global__ __launch_bounds__(256) void mfma_moe2(
    const float* __restrict__ Hbuf, const __bf16* __restrict__ Whi, const __bf16* __restrict__ Wlo,
    const float* __restrict__ b2base, const int* __restrict__ offsets,
    const int* __restrict__ counts, float* __restrict__ ybuf)
{
    int e = blockIdx.z;
    int cnt = counts[e], off = offsets[e];
    mfma64_body<0,0>(Hbuf + (size_t)off*H, Whi + (size_t)e*H*H, Wlo + (size_t)e*H*H,
                     b2base + (size_t)e*H, ybuf + (size_t)off*H, cnt, nullptr);
}

// ---------------- flash attention — EXACT R15 kernel (proven 175us, 3D grid) ----------
__global__ __launch_bounds__(512) void attn_kernel(
    const float* __restrict__ qbuf, const float* __restrict__ kbuf,
    const float* __restrict__ vbuf, float* __restrict__ ctx, int nq)
{
    __shared__ float kv[KT*(HD+4)];
    __shared__ float qs[QT][HD+4];
    __shared__ float ps[QT][KT+4];
    int b = blockIdx.x, h = blockIdx.y, z = blockIdx.z;
    int qbase = z * QT;
    int nqt = nq - qbase;
    if (nqt <= 0) return;
    if (nqt > QT) nqt = QT;
    int tid = threadIdx.x, w = tid >> 6, lane = tid & 63;
    int off = SEQL - nq;
    for (int i = tid; i < QT*(HD/4); i += 512) {
        int row = i >> 4, c4 = (i & 15) << 2;
        float4 qv = make_float4(0.f,0.f,0.f,0.f);
        if (row < nqt) qv = *(const float4*)(qbuf + (size_t)(b*nq + qbase + row)*H + h*HD + c4);
        *(float4*)&qs[row][c4] = qv;
    }
    float m[QW], l[QW], acc[QW];
    #pragma unroll
    for (int i = 0; i < QW; ++i) { m[i] = -3e30f; l[i] = 0.f; acc[i] = 0.f; }
    int wq0 = w * QW;
    int wqn = nqt - wq0; if (wqn > QW) wqn = QW;
    int wmaxpos = qbase + wq0 + (wqn > 0 ? wqn - 1 : 0) + off;
    int ntiles = (qbase + nqt - 1 + off) / KT + 1;
    int q_sub = lane >> 3, kq = lane & 7;
    for (int t = 0; t < ntiles; ++t) {
        int kbase = t * KT;
        bool active = (wqn > 0) && (kbase <= wmaxpos);
        __syncthreads();
        for (int i = tid; i < KT*(HD/4); i += 512) {
            int row = i >> 4, c4 = (i & 15) << 2;
            int key = kbase + row;
            float4 kvv = make_float4(0.f,0.f,0.f,0.f);
            if (key < SEQL) kvv = *(const float4*)(kbuf + (size_t)(b*SEQL + key)*H + h*HD + c4);
            *(float4*)&kv[row*(HD+4) + c4] = kvv;
        }
        __syncthreads();
        if (active) {
            float s[QW];
            #pragma unroll
            for (int qi = 0; qi < QW; ++qi) s[qi] = 0.f;
            #pragma unroll 4
            for (int d4 = 0; d4 < HD; d4 += 4) {
                float4 k4 = *(const float4*)&kv[lane*(HD+4) + d4];
                #pragma unroll
                for (int qi = 0; qi < QW; ++qi) {
                    float4 q4 = *(const float4*)&qs[wq0+qi][d4];
                    s[qi] += k4.x*q4.x + k4.y*q4.y + k4.z*q4.z + k4.w*q4.w;
                }
            }
            #pragma unroll
            for (int qi = 0; qi < QW; ++qi) {
                if (qi < wqn) {
                    int qpos = qbase + wq0 + qi + off;
                    bool valid = (kbase + lane) <= qpos;
                    ps[wq0+qi][lane] = valid ? s[qi]*0.125f : -3e30f;
                }
            }
        }
        __syncthreads();
        {
            int key = kbase + lane;
            bool kval = key < SEQL;
            const float* vp = vbuf + (size_t)(b*SEQL + (kval ? key : 0))*H + h*HD;
            #pragma unroll
            for (int it = 0; it < 2; ++it) {
                int c4 = ((it << 3) + w) << 2;
                float4 vv = make_float4(0.f,0.f,0.f,0.f);
                if (kval) vv = *(const float4*)(vp + c4);
                kv[(c4+0)*(KT+4) + lane] = vv.x;
                kv[(c4+1)*(KT+4) + lane] = vv.y;
                kv[(c4+2)*(KT+4) + lane] = vv.z;
                kv[(c4+3)*(KT+4) + lane] = vv.w;
            }
        }
        __syncthreads();
        if (active) {
            float mq = m[0];
            #pragma unroll
            for (int i = 1; i < QW; ++i) if (q_sub == i) mq = m[i];
            const float2* pr = (const float2*)&ps[wq0+q_sub][kq*8];
            float2 a0 = pr[0], a1 = pr[1], a2 = pr[2], a3 = pr[3];
            float mloc = fmaxf(fmaxf(fmaxf(a0.x,a0.y), fmaxf(a1.x,a1.y)),
                               fmaxf(fmaxf(a2.x,a2.y), fmaxf(a3.x,a3.y)));
            float tm = mloc;
            #pragma unroll
            for (int o = 1; o < 8; o <<= 1) tm = fmaxf(tm, __shfl_xor(tm, o, 64));
            float mn = fmaxf(mq, tm);
            float p0 = expf(a0.x-mn), p1 = expf(a0.y-mn), p2 = expf(a1.x-mn), p3 = expf(a1.y-mn);
            float p4 = expf(a2.x-mn), p5 = expf(a2.y-mn), p6 = expf(a3.x-mn), p7 = expf(a3.y-mn);
            float psum = ((p0+p1)+(p2+p3)) + ((p4+p5)+(p6+p7));
            #pragma unroll
            for (int o = 1; o < 8; o <<= 1) psum += __shfl_xor(psum, o, 64);
            float2* pw = (float2*)&ps[wq0+q_sub][kq*8];
            pw[0] = make_float2(p0,p1); pw[1] = make_float2(p2,p3);
            pw[2] = make_float2(p4,p5); pw[3] = make_float2(p6,p7);
            #pragma unroll
            for (int qi = 0; qi < QW; ++qi) {
                float tmv = __shfl(tm, qi*8, 64);
                float psv = __shfl(psum, qi*8, 64);
                if (qi < wqn) {
                    float mn2 = fmaxf(m[qi], tmv);
                    float scl = expf(m[qi] - mn2);
                    l[qi] = l[qi]*scl + psv;
                    acc[qi] *= scl;
                    m[qi] = mn2;
                }
            }
            #pragma unroll 4
            for (int k4 = 0; k4 < KT; k4 += 4) {
                float4 v4 = *(const float4*)&kv[lane*(KT+4) + k4];
                #pragma unroll
                for (int qi = 0; qi < QW; ++qi) {
                    if (qi < wqn) {
                        float4 p4v = *(const float4*)&ps[wq0+qi][k4];
                        acc[qi] += p4v.x*v4.x + p4v.y*v4.y + p4v.z*v4.z + p4v.w*v4.w;
                    }
                }
            }
        }
    }
    #pragma unroll
    for (int qi = 0; qi < QW; ++qi) {
        if (qi < wqn) {
            ctx[(size_t)(b*nq + qbase + wq0 + qi)*H + h*HD + lane] = acc[qi] / l[qi];
        }
    }
}

// ---------------- count / scan / scatter ----------------
__global__ __launch_bounds__(256) void count_kernel(
    const int* __restrict__ top_idx, int* __restrict__ counts, int nrows)
{
    __shared__ int hist[NEXP];
    int tid = threadIdx.x;
    if (tid < NEXP) hist[tid] = 0;
    __syncthreads();
    int n = blockIdx.x * 256 + tid;
    if (n < nrows) {
        atomicAdd(&hist[top_idx[n*2+0]], 1);
        atomicAdd(&hist[top_idx[n*2+1]], 1);
    }
    __syncthreads();
    if (tid < NEXP && hist[tid] > 0) atomicAdd(&counts[tid], hist[tid]);
}

__global__ void scan_kernel(const int* __restrict__ counts, int* __restrict__ offsets,
                            int* __restrict__ cursor)
{
    int s = 0;
    for (int e = 0; e < NEXP; ++e) { offsets[e] = s; cursor[e] = s; s += counts[e]; }
}

__global__ __launch_bounds__(256) void scatter_kernel(
    const int* __restrict__ top_idx,
    int* __restrict__ cursor, int* __restrict__ pair_tok, int* __restrict__ tok_pair, int nrows)
{
    __shared__ int lcnt[NEXP];
    __shared__ int lbase[NEXP];
    int tid = threadIdx.x;
    if (tid < NEXP) lcnt[tid] = 0;
    __syncthreads();
    int n = blockIdx.x * 256 + tid;
    int e0 = 0, e1 = 0, p0 = 0, p1 = 0;
    bool act = n < nrows;
    if (act) {
        e0 = top_idx[n*2+0]; e1 = top_idx[n*2+1];
        p0 = atomicAdd(&lcnt[e0], 1);
        p1 = atomicAdd(&lcnt[e1], 1);
    }
    __syncthreads();
    if (tid < NEXP) lbase[tid] = (lcnt[tid] > 0) ? atomicAdd(&cursor[tid], lcnt[tid]) : 0;
    __syncthreads();
    if (act) {
        int q0 = lbase[e0] + p0, q1 = lbase[e1] + p1;
        pair_tok[q0] = n; pair_tok[q1] = n;
        tok_pair[n*2+0] = q0; tok_pair[n*2+1] = q1;
    }
}

// ---------------- small fp32 MoE GEMMs (block-1) ----------------
__global__ __launch_bounds__(256) void moe_gemm1(
    const float* __restrict__ X, const float* __restrict__ W1base,
    const float* __restrict__ b1base, const int* __restrict__ pair_tok,
    const int* __restrict__ offsets, const int* __restrict__ counts,
    float* __restrict__ hbuf)
{
    int e = blockIdx.z;
    int cnt = counts[e];
    int r0 = blockIdx.x * 64;
    if (r0 >= cnt) return;
    int off = offsets[e];
    int c0 = blockIdx.y * 64;
    const float* W = W1base + (size_t)e * H * H;
    const float* bias = b1base + (size_t)e * H;
    __shared__ float As[16][68];
    __shared__ float Bs[16][68];
    int tid = threadIdx.x, tx = tid & 15, ty = tid >> 4;
    int lrow = tid >> 2, lkg = (tid & 3) << 2;
    float acc[4][4] = {};
    for (int kk = 0; kk < H; kk += 16) {
        float4 av = make_float4(0.f,0.f,0.f,0.f);
        int pr = r0 + lrow;
        if (pr < cnt) {
            int tok = pair_tok[off + pr];
            av = *(const float4*)(X + (size_t)tok*H + kk + lkg);
        }
        As[lkg+0][lrow]=av.x; As[lkg+1][lrow]=av.y; As[lkg+2][lrow]=av.z; As[lkg+3][lrow]=av.w;
        float4 wv = *(const float4*)(W + (size_t)(kk+ty)*H + c0 + (tx<<2));
        *(float4*)&Bs[ty][tx<<2] = wv;
        __syncthreads();
        #pragma unroll
        for (int k = 0; k < 16; ++k) {
            float4 a = *(const float4*)&As[k][ty<<2];
            float4 bv = *(const float4*)&Bs[k][tx<<2];
            float aa[4] = {a.x,a.y,a.z,a.w};
            float bb[4] = {bv.x,bv.y,bv.z,bv.w};
            #pragma unroll
            for (int ii = 0; ii < 4; ++ii)
                #pragma unroll
                for (int jj = 0; jj < 4; ++jj)
                    acc[ii][jj] += aa[ii] * bb[jj];
        }
        __syncthreads();
    }
    #pragma unroll
    for (int ii = 0; ii < 4; ++ii) {
        int pr = r0 + (ty<<2) + ii;
        if (pr < cnt) {
            #pragma unroll
            for (int jj = 0; jj < 4; ++jj) {
                int gc = c0 + (tx<<2) + jj;
                hbuf[(size_t)(off+pr)*H + gc] = fmaxf(acc[ii][jj] + bias[gc], 0.f);
            }
        }
    }
}

__global__ __launch_bounds__(256) void moe_gemm2(
    const float* __restrict__ Hbuf, const float* __restrict__ W2base,
    const float* __restrict__ b2base, const int* __restrict__ offsets,
    const int* __restrict__ counts, float* __restrict__ ybuf)
{
    int e = blockIdx.z;
    int cnt = counts[e];
    int r0 = blockIdx.x * 64;
    if (r0 >= cnt) return;
    int off = offsets[e];
    int c0 = blockIdx.y * 64;
    const float* W = W2base + (size_t)e * H * H;
    const float* bias = b2base + (size_t)e * H;
    __shared__ float As[16][68];
    __shared__ float Bs[16][68];
    int tid = threadIdx.x, tx = tid & 15, ty = tid >> 4;
    int lrow = tid >> 2, lkg = (tid & 3) << 2;
    float acc[4][4] = {};
    for (int kk = 0; kk < H; kk += 16) {
        float4 av = make_float4(0.f,0.f,0.f,0.f);
        int pr = r0 + lrow;
        if (pr < cnt) av = *(const float4*)(Hbuf + (size_t)(off+pr)*H + kk + lkg);
        As[lkg+0][lrow]=av.x; As[lkg+1][lrow]=av.y; As[lkg+2][lrow]=av.z; As[lkg+3][lrow]=av.w;
        float4 wv = *(const float4*)(W + (size_t)(kk+ty)*H + c0 + (tx<<2));
        *(float4*)&Bs[ty][tx<<2] = wv;
        __syncthreads();
        #pragma unroll
        for (int k = 0; k < 16; ++k) {
            float4 a = *(const float4*)&As[k][ty<<2];
            float4 bv = *(const float4*)&Bs[k][tx<<2];
            float aa[4] = {a.x,a.y,a.z,a.w};
            float bb[4] = {bv.x,bv.y,bv.z,bv.w};
            #pragma unroll
            for (int ii = 0; ii < 4; ++ii)
                #pragma unroll
                for (int jj = 0; jj < 4; ++jj)
                    acc[ii][jj] += aa[ii] * bb[jj];
        }
        __syncthreads();
    }
    #pragma unroll
    for (int ii = 0; ii < 4; ++ii) {
        int pr = r0 + (ty<<2) + ii;
        if (pr < cnt) {
            #pragma unroll
            for (int jj = 0; jj < 4; ++jj) {
                int gc = c0 + (tx<<2) + jj;
                ybuf[(size_t)(off+pr)*H + gc] = acc[ii][jj] + bias[gc];
            }
        }
    }
}

__global__ void zero_kernel(float* __restrict__ p, int n) {
    int i = blockIdx.x * 256 + threadIdx.x;
    if (i < n) p[i] = 0.f;
}

// ---------------- final ----------------
__global__ __launch_bounds__(256) void final_kernel(
    const float* __restrict__ xf, const float* __restrict__ lnw, const float* __restrict__ lnb,
    const float* __restrict__ user_emb, const float* __restrict__ item_emb,
    const int* __restrict__ user_ids, const int* __restrict__ item_ids, float* __restrict__ out)
{
    __shared__ float s4[4];
    int bb = blockIdx.x, t = threadIdx.x;
    float v = xf[(size_t)bb*H + t];
    float mean = blk_sum256(v, s4) * (1.f/H);
    float d = v - mean;
    float var = blk_sum256(d*d, s4) * (1.f/H);
    float lnv = d * rsqrtf(var + 1e-8f) * lnw[t] + lnb[t];
    float fin = lnv + user_emb[(size_t)user_ids[bb]*H + t];
    float prod = fin * item_emb[(size_t)item_ids[bb]*H + t];
    float tot = blk_sum256(prod, s4);
    if (t == 0) out[bb] = tot;
}

// ---------------- launch ----------------
extern "C" void kernel_launch(void* const* d_in, const int* in_sizes, int n_in,
                              void* d_out, int out_size, void* d_ws, size_t ws_size,
                              hipStream_t stream)
{
    (void)in_sizes; (void)n_in; (void)out_size; (void)ws_size;
    const int*   user_ids  = (const int*)d_in[0];
    const int*   log_seqs  = (const int*)d_in[1];
    const int*   item_ids  = (const int*)d_in[2];
    const float* item_emb  = (const float*)d_in[3];
    const float* pos_emb   = (const float*)d_in[4];
    const float* user_emb  = (const float*)d_in[5];
    const float* ln1_w     = (const float*)d_in[6];
    const float* ln1_b     = (const float*)d_in[7];
    const float* inproj_w  = (const float*)d_in[8];
    const float* inproj_b  = (const float*)d_in[9];
    const float* outproj_w = (const float*)d_in[10];
    const float* outproj_b = (const float*)d_in[11];
    const float* ln2_w     = (const float*)d_in[12];
    const float* ln2_b     = (const float*)d_in[13];
    const float* gate_w    = (const float*)d_in[14];
    const float* gate_b    = (const float*)d_in[15];
    const float* e_w1      = (const float*)d_in[16];
    const float* e_b1      = (const float*)d_in[17];
    const float* e_w2      = (const float*)d_in[18];
    const float* e_b2      = (const float*)d_in[19];
    const float* moeln_w   = (const float*)d_in[20];
    const float* moeln_b   = (const float*)d_in[21];
    const float* lastln_w  = (const float*)d_in[22];
    const float* lastln_b  = (const float*)d_in[23];

    float* ws = (float*)d_ws;
    const size_t NFH = (size_t)NF * H;
    float* buf0 = ws;
    float* buf1 = buf0 + NFH;
    float* buf2 = buf1 + NFH;
    float* buf3 = buf2 + NFH;
    float* buf4 = buf3 + NFH;
    float* s0   = buf4 + NFH;
    float* s1   = s0 + (size_t)BATCH*H;
    float* s2   = s1 + (size_t)BATCH*H;
    float* s3   = s2 + (size_t)BATCH*H;
    float* s6   = s3 + (size_t)BATCH*H;
    float* s4   = s6 + (size_t)BATCH*H;
    float* s5   = s4 + (size_t)2*BATCH*H;
    float* top_w   = s5 + (size_t)2*BATCH*H;
    int*   top_idx = (int*)(top_w + (size_t)NF*2);
    int*   pair_tok= top_idx + (size_t)NF*2;
    int*   tok_pair= pair_tok + (size_t)NF*2;
    int*   counts  = tok_pair + (size_t)NF*2;
    int*   offsets = counts + NEXP;
    int*   cursor  = offsets + NEXP;
    // bf16 split-weight regions
    const size_t W_IP = (size_t)2*3*H*H;
    const size_t W_OP = (size_t)2*H*H;
    const size_t W_E  = (size_t)2*NEXP*H*H;
    __bf16* ip_hi = (__bf16*)(cursor + 64);
    __bf16* ip_lo = ip_hi + W_IP;
    __bf16* op_hi = ip_lo + W_IP;
    __bf16* op_lo = op_hi + W_OP;
    __bf16* e1_hi = op_lo + W_OP;
    __bf16* e1_lo = e1_hi + W_E;
    __bf16* e2_hi = e1_lo + W_E;
    __bf16* e2_lo = e2_hi + W_E;

    dim3 blk(256);
    dim3 ablk(512);
    dim3 m64z3(NF/64, H/64, 3);
    dim3 m64z2(NF/64, H/64, 2);
    dim3 m64z1(NF/64, H/64, 1);
    dim3 m64e(NF/64, H/64, NEXP);
    dim3 gsmall((BATCH+63)/64, H/64);
    dim3 msmall((BATCH+63)/64, H/64, NEXP);

    // pre-split weights (once per launch)
    split_plain<<<512, blk, 0, stream>>>(inproj_w,  ip_hi, ip_lo, (int)W_IP);
    split_plain<<<256, blk, 0, stream>>>(outproj_w, op_hi, op_lo, (int)W_OP);
    split_trans<<<1024, blk, 0, stream>>>(e_w1, e1_hi, e1_lo, 2*NEXP);
    split_trans<<<1024, blk, 0, stream>>>(e_w2, e2_hi, e2_lo, 2*NEXP);

    // ================= block 0 =================
    {
        const int i = 0;
        const float* bq = inproj_b + (size_t)i*3*H;
        embed_ln_kernel<<<NF, blk, 0, stream>>>(log_seqs, item_emb, pos_emb, buf0, buf1,
                                                ln1_w + i*H, ln1_b + i*H);
        mfma_z<<<m64z3, blk, 0, stream>>>(buf1, buf0, ip_hi, ip_lo, bq, buf2, NF);
        attn_kernel<<<dim3(BATCH, NHEAD, (SEQL+QT-1)/QT), ablk, 0, stream>>>(buf2, buf3, buf4, buf2, SEQL);
        mfma_z<<<m64z1, blk, 0, stream>>>(buf2, buf2, op_hi, op_lo, outproj_b, buf3, NF);
        ln2_gate_kernel<<<NF, blk, 0, stream>>>(buf1, buf3, buf0, ln2_w + i*H, ln2_b + i*H,
                                                gate_w + (size_t)i*NEXP*H, gate_b + i*NEXP,
                                                top_idx, top_w);
        zero_kernel<<<1, 32, 0, stream>>>((float*)counts, NEXP);
        count_kernel<<<(NF+255)/256, blk, 0, stream>>>(top_idx, counts, NF);
        scan_kernel<<<1, 1, 0, stream>>>(counts, offsets, cursor);
        scatter_kernel<<<(NF+255)/256, blk, 0, stream>>>(top_idx, cursor, pair_tok, tok_pair, NF);
        mfma_moe1<<<m64e, blk, 0, stream>>>(buf0, e1_hi, e1_lo, e_b1 + (size_t)i*NEXP*H,
                                            pair_tok, offsets, counts, buf3);
        mfma_moe2<<<m64e, blk, 0, stream>>>(buf3, e2_hi, e2_lo, e_b2 + (size_t)i*NEXP*H,
                                            offsets, counts, buf1);
        moe_ln_kernel<<<NF, blk, 0, stream>>>(buf0, buf1, tok_pair, top_w, buf3,
                                              moeln_w + i*H, moeln_b + i*H, 1e-5f);
    }

    // ================= block 1 =================
    {
        const int i = 1;
        const float* Wq = inproj_w + (size_t)i*3*H*H;
        const float* bq = inproj_b + (size_t)i*3*H;
        float* X = buf3;
        ln_kernel<<<BATCH, blk, 0, stream>>>(X, nullptr, s0, ln1_w + i*H, ln1_b + i*H, 1e-8f, SEQL-1, SEQL);
        gemm_nt<<<gsmall, blk, 0, stream>>>(s0, Wq, bq, s1, BATCH);
        mfma_z<<<m64z2, blk, 0, stream>>>(X, X, ip_hi + (size_t)3*H*H + (size_t)H*H,
                                          ip_lo + (size_t)3*H*H + (size_t)H*H, bq + H, buf0, NF);
        attn_kernel<<<dim3(BATCH, NHEAD, 1), ablk, 0, stream>>>(s1, buf0, buf1, s2, 1);
        gemm_nt<<<gsmall, blk, 0, stream>>>(s2, outproj_w + (size_t)i*H*H, outproj_b + i*H, s3, BATCH);
        ln2_gate_kernel<<<BATCH, blk, 0, stream>>>(s0, s3, s2, ln2_w + i*H, ln2_b + i*H,
                                                   gate_w + (size_t)i*NEXP*H, gate_b + i*NEXP,
                                                   top_idx, top_w);
        zero_kernel<<<1, 32, 0, stream>>>((float*)counts, NEXP);
        count_kernel<<<1, blk, 0, stream>>>(top_idx, counts, BATCH);
        scan_kernel<<<1, 1, 0, stream>>>(counts, offsets, cursor);
        scatter_kernel<<<1, blk, 0, stream>>>(top_idx, cursor, pair_tok, tok_pair, BATCH);
        moe_gemm1<<<msmall, blk, 0, stream>>>(s2, e_w1 + (size_t)i*NEXP*H*H, e_b1 + (size_t)i*NEXP*H,
                                              pair_tok, offsets, counts, s4);
        moe_gemm2<<<msmall, blk, 0, stream>>>(s4, e_w2 + (size_t)i*NEXP*H*H, e_b2 + (size_t)i*NEXP*H,
                                              offsets, counts, s5);
        moe_ln_kernel<<<BATCH, blk, 0, stream>>>(s2, s5, tok_pair, top_w, s6,
                                                 moeln_w + i*H, moeln_b + i*H, 1e-5f);
    }

    final_kernel<<<BATCH, blk, 0, stream>>>(s6, lastln_w, lastln_b, user_emb, item_emb,
                                            user_ids, item_ids, (float*)d_out);
}

// Round 18
// 892.190 us; speedup vs baseline: 1.0599x; 1.0277x over previous
//
#include <hip/hip_runtime.h>
#include <math.h>

#define H 256
#define NHEAD 4
#define HD 64
#define NEXP 8
#define SEQL 200
#define BATCH 128
#define NF (BATCH*SEQL)
#define KT 64
#define QT 64
#define QW 8

typedef __bf16 bf16x8 __attribute__((ext_vector_type(8)));
typedef float  f32x4  __attribute__((ext_vector_type(4)));

__device__ __forceinline__ void split8(const float* __restrict__ p, bf16x8& hi, bf16x8& lo, bool valid) {
    if (valid) {
        float4 a = *(const float4*)p;
        float4 b = *(const float4*)(p + 4);
        float x[8] = {a.x,a.y,a.z,a.w,b.x,b.y,b.z,b.w};
        #pragma unroll
        for (int j = 0; j < 8; ++j) {
            __bf16 h = (__bf16)x[j];
            hi[j] = h;
            lo[j] = (__bf16)(x[j] - (float)h);
        }
    } else {
        #pragma unroll
        for (int j = 0; j < 8; ++j) { hi[j] = (__bf16)0.f; lo[j] = (__bf16)0.f; }
    }
}

#define MFMA3(AH,AL,BH,BL,ACC) \
    ACC = __builtin_amdgcn_mfma_f32_16x16x32_bf16(AH, BH, ACC, 0, 0, 0); \
    ACC = __builtin_amdgcn_mfma_f32_16x16x32_bf16(AH, BL, ACC, 0, 0, 0); \
    ACC = __builtin_amdgcn_mfma_f32_16x16x32_bf16(AL, BH, ACC, 0, 0, 0);

// ---------------- helpers ----------------
__device__ __forceinline__ float blk_sum256(float v, float* s4) {
    #pragma unroll
    for (int o = 32; o > 0; o >>= 1) v += __shfl_xor(v, o, 64);
    __syncthreads();
    if ((threadIdx.x & 63) == 0) s4[threadIdx.x >> 6] = v;
    __syncthreads();
    return s4[0] + s4[1] + s4[2] + s4[3];
}

// ---------------- weight pre-split ----------------
__global__ __launch_bounds__(256) void split_plain(
    const float* __restrict__ in, __bf16* __restrict__ hi, __bf16* __restrict__ lo, int n)
{
    for (int i = blockIdx.x * 256 + threadIdx.x; i < n; i += gridDim.x * 256) {
        float x = in[i];
        __bf16 h = (__bf16)x;
        hi[i] = h;
        lo[i] = (__bf16)(x - (float)h);
    }
}

// experts: in [m][k][n] -> out [m][n][k]
__global__ __launch_bounds__(256) void split_trans(
    const float* __restrict__ in, __bf16* __restrict__ hi, __bf16* __restrict__ lo, int nmats)
{
    int n = nmats * H * H;
    for (int i = blockIdx.x * 256 + threadIdx.x; i < n; i += gridDim.x * 256) {
        int m = i / (H*H), rem = i % (H*H);
        int nn = rem / H, k = rem % H;
        float x = in[(size_t)m*H*H + (size_t)k*H + nn];
        __bf16 h = (__bf16)x;
        hi[i] = h;
        lo[i] = (__bf16)(x - (float)h);
    }
}

// ---------------- fused embedding + LN1 ----------------
__global__ __launch_bounds__(256) void embed_ln_kernel(
    const int* __restrict__ seqs, const float* __restrict__ item_emb,
    const float* __restrict__ pos_emb, float* __restrict__ x,
    float* __restrict__ xln, const float* __restrict__ w, const float* __restrict__ b)
{
    __shared__ float s4[4];
    int n = blockIdx.x, t = threadIdx.x;
    int id = seqs[n];
    int pos = (id != 0) ? (n % SEQL) + 1 : 0;
    float v = item_emb[(size_t)id*H + t] * 16.0f + pos_emb[(size_t)pos*H + t];
    x[(size_t)n*H + t] = v;
    float mean = blk_sum256(v, s4) * (1.f/H);
    float d = v - mean;
    float var = blk_sum256(d*d, s4) * (1.f/H);
    xln[(size_t)n*H + t] = d * rsqrtf(var + 1e-8f) * w[t] + b[t];
}

// ---------------- layernorm ----------------
__global__ __launch_bounds__(256) void ln_kernel(
    const float* __restrict__ in, const float* __restrict__ res,
    float* __restrict__ out, const float* __restrict__ w, const float* __restrict__ b,
    float eps, int base, int step)
{
    __shared__ float s4[4];
    int r = blockIdx.x, t = threadIdx.x;
    float v = in[(size_t)(base + r*step)*H + t];
    if (res) v += res[(size_t)r*H + t];
    float mean = blk_sum256(v, s4) * (1.f/H);
    float d = v - mean;
    float var = blk_sum256(d*d, s4) * (1.f/H);
    out[(size_t)r*H + t] = d * rsqrtf(var + eps) * w[t] + b[t];
}

// ---------------- fused LN2 + gate top-2 ----------------
__global__ __launch_bounds__(256) void ln2_gate_kernel(
    const float* __restrict__ in, const float* __restrict__ res,
    float* __restrict__ out, const float* __restrict__ w, const float* __restrict__ b,
    const float* __restrict__ gw, const float* __restrict__ gb,
    int* __restrict__ top_idx, float* __restrict__ top_w)
{
    __shared__ float s4[4];
    __shared__ float xs[H];
    __shared__ float gl[NEXP];
    int n = blockIdx.x, t = threadIdx.x;
    float v = in[(size_t)n*H + t] + res[(size_t)n*H + t];
    float mean = blk_sum256(v, s4) * (1.f/H);
    float d = v - mean;
    float var = blk_sum256(d*d, s4) * (1.f/H);
    float r = d * rsqrtf(var + 1e-8f) * w[t] + b[t];
    out[(size_t)n*H + t] = r;
    xs[t] = r;
    __syncthreads();
    int wv = t >> 6, lane = t & 63;
    float xv[4];
    #pragma unroll
    for (int c = 0; c < 4; ++c) xv[c] = xs[lane + (c<<6)];
    #pragma unroll
    for (int s = 0; s < 2; ++s) {
        int e = wv*2 + s;
        float acc = 0.f;
        #pragma unroll
        for (int c = 0; c < 4; ++c) acc += xv[c] * gw[(size_t)e*H + lane + (c<<6)];
        #pragma unroll
        for (int o = 32; o > 0; o >>= 1) acc += __shfl_xor(acc, o, 64);
        if (lane == 0) gl[e] = acc + gb[e];
    }
    __syncthreads();
    if (t == 0) {
        int i0 = 0;
        for (int e = 1; e < NEXP; ++e) if (gl[e] > gl[i0]) i0 = e;
        int i1 = -1;
        for (int e = 0; e < NEXP; ++e) { if (e == i0) continue; if (i1 < 0 || gl[e] > gl[i1]) i1 = e; }
        float e1 = expf(gl[i1] - gl[i0]);
        float w0 = 1.f / (1.f + e1);
        top_idx[n*2+0] = i0; top_idx[n*2+1] = i1;
        top_w[n*2+0] = w0;  top_w[n*2+1] = 1.f - w0;
    }
}

// ---------------- fused moe combine + layernorm ----------------
__global__ __launch_bounds__(256) void moe_ln_kernel(
    const float* __restrict__ x, const float* __restrict__ ybuf,
    const int* __restrict__ tok_pair, const float* __restrict__ top_w,
    float* __restrict__ out, const float* __restrict__ w, const float* __restrict__ b,
    float eps)
{
    __shared__ float s4[4];
    int r = blockIdx.x, t = threadIdx.x;
    int p0 = tok_pair[r*2], p1 = tok_pair[r*2+1];
    float v = x[(size_t)r*H + t]
            + top_w[r*2+0] * ybuf[(size_t)p0*H + t]
            + top_w[r*2+1] * ybuf[(size_t)p1*H + t];
    float mean = blk_sum256(v, s4) * (1.f/H);
    float d = v - mean;
    float var = blk_sum256(d*d, s4) * (1.f/H);
    out[(size_t)r*H + t] = d * rsqrtf(var + eps) * w[t] + b[t];
}

// ---------------- small fp32 GEMM (64x64) — proven, block-1 paths ----------------
__global__ __launch_bounds__(256) void gemm_nt(
    const float* __restrict__ A, const float* __restrict__ W,
    const float* __restrict__ bias, float* __restrict__ out, int nrows)
{
    __shared__ float As[16][68];
    __shared__ float Ws[16][68];
    int r0 = blockIdx.x * 64;
    if (r0 >= nrows) return;
    int c0 = blockIdx.y * 64;
    int tid = threadIdx.x;
    int tx = tid & 15, ty = tid >> 4;
    int lrow = tid >> 2, lkg = (tid & 3) << 2;
    float acc[4][4] = {};
    for (int kk = 0; kk < H; kk += 16) {
        float4 av = make_float4(0.f,0.f,0.f,0.f);
        int gr = r0 + lrow;
        if (gr < nrows) av = *(const float4*)(A + (size_t)gr*H + kk + lkg);
        As[lkg+0][lrow]=av.x; As[lkg+1][lrow]=av.y; As[lkg+2][lrow]=av.z; As[lkg+3][lrow]=av.w;
        float4 wv = *(const float4*)(W + (size_t)(c0+lrow)*H + kk + lkg);
        Ws[lkg+0][lrow]=wv.x; Ws[lkg+1][lrow]=wv.y; Ws[lkg+2][lrow]=wv.z; Ws[lkg+3][lrow]=wv.w;
        __syncthreads();
        #pragma unroll
        for (int k = 0; k < 16; ++k) {
            float4 a = *(const float4*)&As[k][ty<<2];
            float4 bv = *(const float4*)&Ws[k][tx<<2];
            float aa[4] = {a.x,a.y,a.z,a.w};
            float bb[4] = {bv.x,bv.y,bv.z,bv.w};
            #pragma unroll
            for (int ii = 0; ii < 4; ++ii)
                #pragma unroll
                for (int jj = 0; jj < 4; ++jj)
                    acc[ii][jj] += aa[ii] * bb[jj];
        }
        __syncthreads();
    }
    #pragma unroll
    for (int ii = 0; ii < 4; ++ii) {
        int gr = r0 + (ty<<2) + ii;
        if (gr < nrows) {
            #pragma unroll
            for (int jj = 0; jj < 4; ++jj) {
                int gc = c0 + (tx<<2) + jj;
                out[(size_t)gr*H + gc] = acc[ii][jj] + bias[gc];
            }
        }
    }
}

// ---------------- split-bf16 MFMA GEMM body: 64-row stripe, ALL 4 column tiles ----------
// A split ONCE per k-iter, reused across 4 column tiles (4x less split VALU than R17).
// Per-output MFMA order identical to R17 (bit-identical results).
template<int GATHER, int RELU>
__device__ __forceinline__ void mfma64_body(
    const float* __restrict__ A, const __bf16* __restrict__ Whi, const __bf16* __restrict__ Wlo,
    const float* __restrict__ bias, float* __restrict__ out, int nrows,
    const int* __restrict__ pair_tok)
{
    int r0 = blockIdx.x * 64;
    if (r0 >= nrows) return;
    int tid = threadIdx.x;
    int wid = tid >> 6, lane = tid & 63;
    int wm = wid >> 1, wn = wid & 1;
    int rbase = r0 + wm*32;
    int lr = lane & 15, lk = (lane >> 4) << 3;
    f32x4 acc[4][2][2] = {};
    int ar0 = rbase + lr, ar1 = ar0 + 16;
    bool v0 = ar0 < nrows, v1 = ar1 < nrows;
    int ga0 = ar0, ga1 = ar1;
    if (GATHER) { ga0 = v0 ? pair_tok[ar0] : 0; ga1 = v1 ? pair_tok[ar1] : 0; }
    const float* ap0 = A + (size_t)(v0 ? ga0 : 0)*H + lk;
    const float* ap1 = A + (size_t)(v1 ? ga1 : 0)*H + lk;
    size_t woff = (size_t)(wn*32 + lr)*H + lk;   // column tile ct adds ct*64*H
    #pragma unroll
    for (int kk = 0; kk < H; kk += 32) {
        bf16x8 ah0, al0, ah1, al1;
        split8(ap0 + kk, ah0, al0, v0);
        split8(ap1 + kk, ah1, al1, v1);
        #pragma unroll
        for (int ct = 0; ct < 4; ++ct) {
            size_t wo = woff + (size_t)ct*64*H + kk;
            bf16x8 bh0 = *(const bf16x8*)(Whi + wo);
            bf16x8 bl0 = *(const bf16x8*)(Wlo + wo);
            bf16x8 bh1 = *(const bf16x8*)(Whi + wo + (size_t)16*H);
            bf16x8 bl1 = *(const bf16x8*)(Wlo + wo + (size_t)16*H);
            MFMA3(ah0, al0, bh0, bl0, acc[ct][0][0]);
            MFMA3(ah0, al0, bh1, bl1, acc[ct][0][1]);
            MFMA3(ah1, al1, bh0, bl0, acc[ct][1][0]);
            MFMA3(ah1, al1, bh1, bl1, acc[ct][1][1]);
        }
    }
    int lro = (lane >> 4) << 2;
    #pragma unroll
    for (int ct = 0; ct < 4; ++ct)
        #pragma unroll
        for (int mi = 0; mi < 2; ++mi)
            #pragma unroll
            for (int ni = 0; ni < 2; ++ni)
                #pragma unroll
                for (int j = 0; j < 4; ++j) {
                    int row = rbase + mi*16 + lro + j;
                    int col = ct*64 + wn*32 + ni*16 + lr;
                    if (row < nrows) {
                        float o = acc[ct][mi][ni][j] + bias[col];
                        if (RELU) o = fmaxf(o, 0.f);
                        out[(size_t)row*H + col] = o;
                    }
                }
}

// z-fused: A = (z==0 ? A0 : A1), W += z*H*H, bias += z*H, out += z*NF*H
__global__ __launch_bounds__(256) void mfma_z(
    const float* __restrict__ A0, const float* __restrict__ A1,
    const __bf16* __restrict__ Whi, const __bf16* __restrict__ Wlo,
    const float* __restrict__ biasbase, float* __restrict__ outbase, int nrows)
{
    int z = blockIdx.z;
    const float* A = (z == 0) ? A0 : A1;
    mfma64_body<0,0>(A, Whi + (size_t)z*H*H, Wlo + (size_t)z*H*H,
                     biasbase + (size_t)z*H, outbase + (size_t)z*NF*H, nrows, nullptr);
}

__global__ __launch_bounds__(256) void mfma_moe1(
    const float* __restrict__ X, const __bf16* __restrict__ Whi, const __bf16* __restrict__ Wlo,
    const float* __restrict__ b1base, const int* __restrict__ pair_tok,
    const int* __restrict__ offsets, const int* __restrict__ counts,
    float* __restrict__ hbuf)
{
    int e = blockIdx.z;
    int cnt = counts[e], off = offsets[e];
    mfma64_body<1,1>(X, Whi + (size_t)e*H*H, Wlo + (size_t)e*H*H,
                     b1base + (size_t)e*H, hbuf + (size_t)off*H, cnt, pair_tok + off);
}

__global__ __launch_bounds__(256) void mfma_moe2(
    const float* __restrict__ Hbuf, const __bf16* __restrict__ Whi, const __bf16* __restrict__ Wlo,
    const float* __restrict__ b2base, const int* __restrict__ offsets,
    const int* __restrict__ counts, float* __restrict__ ybuf)
{
    int e = blockIdx.z;
    int cnt = counts[e], off = offsets[e];
    mfma64_body<0,0>(Hbuf + (size_t)off*H, Whi + (size_t)e*H*H, Wlo + (size_t)e*H*H,
                     b2base + (size_t)e*H, ybuf + (size_t)off*H, cnt, nullptr);
}

// ---------------- flash attention — EXACT R15 kernel (proven 175us, 3D grid) ----------
__global__ __launch_bounds__(512) void attn_kernel(
    const float* __restrict__ qbuf, const float* __restrict__ kbuf,
    const float* __restrict__ vbuf, float* __restrict__ ctx, int nq)
{
    __shared__ float kv[KT*(HD+4)];
    __shared__ float qs[QT][HD+4];
    __shared__ float ps[QT][KT+4];
    int b = blockIdx.x, h = blockIdx.y, z = blockIdx.z;
    int qbase = z * QT;
    int nqt = nq - qbase;
    if (nqt <= 0) return;
    if (nqt > QT) nqt = QT;
    int tid = threadIdx.x, w = tid >> 6, lane = tid & 63;
    int off = SEQL - nq;
    for (int i = tid; i < QT*(HD/4); i += 512) {
        int row = i >> 4, c4 = (i & 15) << 2;
        float4 qv = make_float4(0.f,0.f,0.f,0.f);
        if (row < nqt) qv = *(const float4*)(qbuf + (size_t)(b*nq + qbase + row)*H + h*HD + c4);
        *(float4*)&qs[row][c4] = qv;
    }
    float m[QW], l[QW], acc[QW];
    #pragma unroll
    for (int i = 0; i < QW; ++i) { m[i] = -3e30f; l[i] = 0.f; acc[i] = 0.f; }
    int wq0 = w * QW;
    int wqn = nqt - wq0; if (wqn > QW) wqn = QW;
    int wmaxpos = qbase + wq0 + (wqn > 0 ? wqn - 1 : 0) + off;
    int ntiles = (qbase + nqt - 1 + off) / KT + 1;
    int q_sub = lane >> 3, kq = lane & 7;
    for (int t = 0; t < ntiles; ++t) {
        int kbase = t * KT;
        bool active = (wqn > 0) && (kbase <= wmaxpos);
        __syncthreads();
        for (int i = tid; i < KT*(HD/4); i += 512) {
            int row = i >> 4, c4 = (i & 15) << 2;
            int key = kbase + row;
            float4 kvv = make_float4(0.f,0.f,0.f,0.f);
            if (key < SEQL) kvv = *(const float4*)(kbuf + (size_t)(b*SEQL + key)*H + h*HD + c4);
            *(float4*)&kv[row*(HD+4) + c4] = kvv;
        }
        __syncthreads();
        if (active) {
            float s[QW];
            #pragma unroll
            for (int qi = 0; qi < QW; ++qi) s[qi] = 0.f;
            #pragma unroll 4
            for (int d4 = 0; d4 < HD; d4 += 4) {
                float4 k4 = *(const float4*)&kv[lane*(HD+4) + d4];
                #pragma unroll
                for (int qi = 0; qi < QW; ++qi) {
                    float4 q4 = *(const float4*)&qs[wq0+qi][d4];
                    s[qi] += k4.x*q4.x + k4.y*q4.y + k4.z*q4.z + k4.w*q4.w;
                }
            }
            #pragma unroll
            for (int qi = 0; qi < QW; ++qi) {
                if (qi < wqn) {
                    int qpos = qbase + wq0 + qi + off;
                    bool valid = (kbase + lane) <= qpos;
                    ps[wq0+qi][lane] = valid ? s[qi]*0.125f : -3e30f;
                }
            }
        }
        __syncthreads();
        {
            int key = kbase + lane;
            bool kval = key < SEQL;
            const float* vp = vbuf + (size_t)(b*SEQL + (kval ? key : 0))*H + h*HD;
            #pragma unroll
            for (int it = 0; it < 2; ++it) {
                int c4 = ((it << 3) + w) << 2;
                float4 vv = make_float4(0.f,0.f,0.f,0.f);
                if (kval) vv = *(const float4*)(vp + c4);
                kv[(c4+0)*(KT+4) + lane] = vv.x;
                kv[(c4+1)*(KT+4) + lane] = vv.y;
                kv[(c4+2)*(KT+4) + lane] = vv.z;
                kv[(c4+3)*(KT+4) + lane] = vv.w;
            }
        }
        __syncthreads();
        if (active) {
            float mq = m[0];
            #pragma unroll
            for (int i = 1; i < QW; ++i) if (q_sub == i) mq = m[i];
            const float2* pr = (const float2*)&ps[wq0+q_sub][kq*8];
            float2 a0 = pr[0], a1 = pr[1], a2 = pr[2], a3 = pr[3];
            float mloc = fmaxf(fmaxf(fmaxf(a0.x,a0.y), fmaxf(a1.x,a1.y)),
                               fmaxf(fmaxf(a2.x,a2.y), fmaxf(a3.x,a3.y)));
            float tm = mloc;
            #pragma unroll
            for (int o = 1; o < 8; o <<= 1) tm = fmaxf(tm, __shfl_xor(tm, o, 64));
            float mn = fmaxf(mq, tm);
            float p0 = expf(a0.x-mn), p1 = expf(a0.y-mn), p2 = expf(a1.x-mn), p3 = expf(a1.y-mn);
            float p4 = expf(a2.x-mn), p5 = expf(a2.y-mn), p6 = expf(a3.x-mn), p7 = expf(a3.y-mn);
            float psum = ((p0+p1)+(p2+p3)) + ((p4+p5)+(p6+p7));
            #pragma unroll
            for (int o = 1; o < 8; o <<= 1) psum += __shfl_xor(psum, o, 64);
            float2* pw = (float2*)&ps[wq0+q_sub][kq*8];
            pw[0] = make_float2(p0,p1); pw[1] = make_float2(p2,p3);
            pw[2] = make_float2(p4,p5); pw[3] = make_float2(p6,p7);
            #pragma unroll
            for (int qi = 0; qi < QW; ++qi) {
                float tmv = __shfl(tm, qi*8, 64);
                float psv = __shfl(psum, qi*8, 64);
                if (qi < wqn) {
                    float mn2 = fmaxf(m[qi], tmv);
                    float scl = expf(m[qi] - mn2);
                    l[qi] = l[qi]*scl + psv;
                    acc[qi] *= scl;
                    m[qi] = mn2;
                }
            }
            #pragma unroll 4
            for (int k4 = 0; k4 < KT; k4 += 4) {
                float4 v4 = *(const float4*)&kv[lane*(KT+4) + k4];
                #pragma unroll
                for (int qi = 0; qi < QW; ++qi) {
                    if (qi < wqn) {
                        float4 p4v = *(const float4*)&ps[wq0+qi][k4];
                        acc[qi] += p4v.x*v4.x + p4v.y*v4.y + p4v.z*v4.z + p4v.w*v4.w;
                    }
                }
            }
        }
    }
    #pragma unroll
    for (int qi = 0; qi < QW; ++qi) {
        if (qi < wqn) {
            ctx[(size_t)(b*nq + qbase + wq0 + qi)*H + h*HD + lane] = acc[qi] / l[qi];
        }
    }
}

// ---------------- count / scan / scatter ----------------
__global__ __launch_bounds__(256) void count_kernel(
    const int* __restrict__ top_idx, int* __restrict__ counts, int nrows)
{
    __shared__ int hist[NEXP];
    int tid = threadIdx.x;
    if (tid < NEXP) hist[tid] = 0;
    __syncthreads();
    int n = blockIdx.x * 256 + tid;
    if (n < nrows) {
        atomicAdd(&hist[top_idx[n*2+0]], 1);
        atomicAdd(&hist[top_idx[n*2+1]], 1);
    }
    __syncthreads();
    if (tid < NEXP && hist[tid] > 0) atomicAdd(&counts[tid], hist[tid]);
}

__global__ void scan_kernel(const int* __restrict__ counts, int* __restrict__ offsets,
                            int* __restrict__ cursor)
{
    int s = 0;
    for (int e = 0; e < NEXP; ++e) { offsets[e] = s; cursor[e] = s; s += counts[e]; }
}

__global__ __launch_bounds__(256) void scatter_kernel(
    const int* __restrict__ top_idx,
    int* __restrict__ cursor, int* __restrict__ pair_tok, int* __restrict__ tok_pair, int nrows)
{
    __shared__ int lcnt[NEXP];
    __shared__ int lbase[NEXP];
    int tid = threadIdx.x;
    if (tid < NEXP) lcnt[tid] = 0;
    __syncthreads();
    int n = blockIdx.x * 256 + tid;
    int e0 = 0, e1 = 0, p0 = 0, p1 = 0;
    bool act = n < nrows;
    if (act) {
        e0 = top_idx[n*2+0]; e1 = top_idx[n*2+1];
        p0 = atomicAdd(&lcnt[e0], 1);
        p1 = atomicAdd(&lcnt[e1], 1);
    }
    __syncthreads();
    if (tid < NEXP) lbase[tid] = (lcnt[tid] > 0) ? atomicAdd(&cursor[tid], lcnt[tid]) : 0;
    __syncthreads();
    if (act) {
        int q0 = lbase[e0] + p0, q1 = lbase[e1] + p1;
        pair_tok[q0] = n; pair_tok[q1] = n;
        tok_pair[n*2+0] = q0; tok_pair[n*2+1] = q1;
    }
}

// ---------------- small fp32 MoE GEMMs (block-1) ----------------
__global__ __launch_bounds__(256) void moe_gemm1(
    const float* __restrict__ X, const float* __restrict__ W1base,
    const float* __restrict__ b1base, const int* __restrict__ pair_tok,
    const int* __restrict__ offsets, const int* __restrict__ counts,
    float* __restrict__ hbuf)
{
    int e = blockIdx.z;
    int cnt = counts[e];
    int r0 = blockIdx.x * 64;
    if (r0 >= cnt) return;
    int off = offsets[e];
    int c0 = blockIdx.y * 64;
    const float* W = W1base + (size_t)e * H * H;
    const float* bias = b1base + (size_t)e * H;
    __shared__ float As[16][68];
    __shared__ float Bs[16][68];
    int tid = threadIdx.x, tx = tid & 15, ty = tid >> 4;
    int lrow = tid >> 2, lkg = (tid & 3) << 2;
    float acc[4][4] = {};
    for (int kk = 0; kk < H; kk += 16) {
        float4 av = make_float4(0.f,0.f,0.f,0.f);
        int pr = r0 + lrow;
        if (pr < cnt) {
            int tok = pair_tok[off + pr];
            av = *(const float4*)(X + (size_t)tok*H + kk + lkg);
        }
        As[lkg+0][lrow]=av.x; As[lkg+1][lrow]=av.y; As[lkg+2][lrow]=av.z; As[lkg+3][lrow]=av.w;
        float4 wv = *(const float4*)(W + (size_t)(kk+ty)*H + c0 + (tx<<2));
        *(float4*)&Bs[ty][tx<<2] = wv;
        __syncthreads();
        #pragma unroll
        for (int k = 0; k < 16; ++k) {
            float4 a = *(const float4*)&As[k][ty<<2];
            float4 bv = *(const float4*)&Bs[k][tx<<2];
            float aa[4] = {a.x,a.y,a.z,a.w};
            float bb[4] = {bv.x,bv.y,bv.z,bv.w};
            #pragma unroll
            for (int ii = 0; ii < 4; ++ii)
                #pragma unroll
                for (int jj = 0; jj < 4; ++jj)
                    acc[ii][jj] += aa[ii] * bb[jj];
        }
        __syncthreads();
    }
    #pragma unroll
    for (int ii = 0; ii < 4; ++ii) {
        int pr = r0 + (ty<<2) + ii;
        if (pr < cnt) {
            #pragma unroll
            for (int jj = 0; jj < 4; ++jj) {
                int gc = c0 + (tx<<2) + jj;
                hbuf[(size_t)(off+pr)*H + gc] = fmaxf(acc[ii][jj] + bias[gc], 0.f);
            }
        }
    }
}

__global__ __launch_bounds__(256) void moe_gemm2(
    const float* __restrict__ Hbuf, const float* __restrict__ W2base,
    const float* __restrict__ b2base, const int* __restrict__ offsets,
    const int* __restrict__ counts, float* __restrict__ ybuf)
{
    int e = blockIdx.z;
    int cnt = counts[e];
    int r0 = blockIdx.x * 64;
    if (r0 >= cnt) return;
    int off = offsets[e];
    int c0 = blockIdx.y * 64;
    const float* W = W2base + (size_t)e * H * H;
    const float* bias = b2base + (size_t)e * H;
    __shared__ float As[16][68];
    __shared__ float Bs[16][68];
    int tid = threadIdx.x, tx = tid & 15, ty = tid >> 4;
    int lrow = tid >> 2, lkg = (tid & 3) << 2;
    float acc[4][4] = {};
    for (int kk = 0; kk < H; kk += 16) {
        float4 av = make_float4(0.f,0.f,0.f,0.f);
        int pr = r0 + lrow;
        if (pr < cnt) av = *(const float4*)(Hbuf + (size_t)(off+pr)*H + kk + lkg);
        As[lkg+0][lrow]=av.x; As[lkg+1][lrow]=av.y; As[lkg+2][lrow]=av.z; As[lkg+3][lrow]=av.w;
        float4 wv = *(const float4*)(W + (size_t)(kk+ty)*H + c0 + (tx<<2));
        *(float4*)&Bs[ty][tx<<2] = wv;
        __syncthreads();
        #pragma unroll
        for (int k = 0; k < 16; ++k) {
            float4 a = *(const float4*)&As[k][ty<<2];
            float4 bv = *(const float4*)&Bs[k][tx<<2];
            float aa[4] = {a.x,a.y,a.z,a.w};
            float bb[4] = {bv.x,bv.y,bv.z,bv.w};
            #pragma unroll
            for (int ii = 0; ii < 4; ++ii)
                #pragma unroll
                for (int jj = 0; jj < 4; ++jj)
                    acc[ii][jj] += aa[ii] * bb[jj];
        }
        __syncthreads();
    }
    #pragma unroll
    for (int ii = 0; ii < 4; ++ii) {
        int pr = r0 + (ty<<2) + ii;
        if (pr < cnt) {
            #pragma unroll
            for (int jj = 0; jj < 4; ++jj) {
                int gc = c0 + (tx<<2) + jj;
                ybuf[(size_t)(off+pr)*H + gc] = acc[ii][jj] + bias[gc];
            }
        }
    }
}

__global__ void zero_kernel(float* __restrict__ p, int n) {
    int i = blockIdx.x * 256 + threadIdx.x;
    if (i < n) p[i] = 0.f;
}

// ---------------- final ----------------
__global__ __launch_bounds__(256) void final_kernel(
    const float* __restrict__ xf, const float* __restrict__ lnw, const float* __restrict__ lnb,
    const float* __restrict__ user_emb, const float* __restrict__ item_emb,
    const int* __restrict__ user_ids, const int* __restrict__ item_ids, float* __restrict__ out)
{
    __shared__ float s4[4];
    int bb = blockIdx.x, t = threadIdx.x;
    float v = xf[(size_t)bb*H + t];
    float mean = blk_sum256(v, s4) * (1.f/H);
    float d = v - mean;
    float var = blk_sum256(d*d, s4) * (1.f/H);
    float lnv = d * rsqrtf(var + 1e-8f) * lnw[t] + lnb[t];
    float fin = lnv + user_emb[(size_t)user_ids[bb]*H + t];
    float prod = fin * item_emb[(size_t)item_ids[bb]*H + t];
    float tot = blk_sum256(prod, s4);
    if (t == 0) out[bb] = tot;
}

// ---------------- launch ----------------
extern "C" void kernel_launch(void* const* d_in, const int* in_sizes, int n_in,
                              void* d_out, int out_size, void* d_ws, size_t ws_size,
                              hipStream_t stream)
{
    (void)in_sizes; (void)n_in; (void)out_size; (void)ws_size;
    const int*   user_ids  = (const int*)d_in[0];
    const int*   log_seqs  = (const int*)d_in[1];
    const int*   item_ids  = (const int*)d_in[2];
    const float* item_emb  = (const float*)d_in[3];
    const float* pos_emb   = (const float*)d_in[4];
    const float* user_emb  = (const float*)d_in[5];
    const float* ln1_w     = (const float*)d_in[6];
    const float* ln1_b     = (const float*)d_in[7];
    const float* inproj_w  = (const float*)d_in[8];
    const float* inproj_b  = (const float*)d_in[9];
    const float* outproj_w = (const float*)d_in[10];
    const float* outproj_b = (const float*)d_in[11];
    const float* ln2_w     = (const float*)d_in[12];
    const float* ln2_b     = (const float*)d_in[13];
    const float* gate_w    = (const float*)d_in[14];
    const float* gate_b    = (const float*)d_in[15];
    const float* e_w1      = (const float*)d_in[16];
    const float* e_b1      = (const float*)d_in[17];
    const float* e_w2      = (const float*)d_in[18];
    const float* e_b2      = (const float*)d_in[19];
    const float* moeln_w   = (const float*)d_in[20];
    const float* moeln_b   = (const float*)d_in[21];
    const float* lastln_w  = (const float*)d_in[22];
    const float* lastln_b  = (const float*)d_in[23];

    float* ws = (float*)d_ws;
    const size_t NFH = (size_t)NF * H;
    float* buf0 = ws;
    float* buf1 = buf0 + NFH;
    float* buf2 = buf1 + NFH;
    float* buf3 = buf2 + NFH;
    float* buf4 = buf3 + NFH;
    float* s0   = buf4 + NFH;
    float* s1   = s0 + (size_t)BATCH*H;
    float* s2   = s1 + (size_t)BATCH*H;
    float* s3   = s2 + (size_t)BATCH*H;
    float* s6   = s3 + (size_t)BATCH*H;
    float* s4   = s6 + (size_t)BATCH*H;
    float* s5   = s4 + (size_t)2*BATCH*H;
    float* top_w   = s5 + (size_t)2*BATCH*H;
    int*   top_idx = (int*)(top_w + (size_t)NF*2);
    int*   pair_tok= top_idx + (size_t)NF*2;
    int*   tok_pair= pair_tok + (size_t)NF*2;
    int*   counts  = tok_pair + (size_t)NF*2;
    int*   offsets = counts + NEXP;
    int*   cursor  = offsets + NEXP;
    // bf16 split-weight regions
    const size_t W_IP = (size_t)2*3*H*H;
    const size_t W_OP = (size_t)2*H*H;
    const size_t W_E  = (size_t)2*NEXP*H*H;
    __bf16* ip_hi = (__bf16*)(cursor + 64);
    __bf16* ip_lo = ip_hi + W_IP;
    __bf16* op_hi = ip_lo + W_IP;
    __bf16* op_lo = op_hi + W_OP;
    __bf16* e1_hi = op_lo + W_OP;
    __bf16* e1_lo = e1_hi + W_E;
    __bf16* e2_hi = e1_lo + W_E;
    __bf16* e2_lo = e2_hi + W_E;

    dim3 blk(256);
    dim3 ablk(512);
    dim3 m64z3(NF/64, 1, 3);
    dim3 m64z2(NF/64, 1, 2);
    dim3 m64z1(NF/64, 1, 1);
    dim3 m64e(NF/64, 1, NEXP);
    dim3 gsmall((BATCH+63)/64, H/64);
    dim3 msmall((BATCH+63)/64, H/64, NEXP);

    // pre-split weights (once per launch)
    split_plain<<<512, blk, 0, stream>>>(inproj_w,  ip_hi, ip_lo, (int)W_IP);
    split_plain<<<256, blk, 0, stream>>>(outproj_w, op_hi, op_lo, (int)W_OP);
    split_trans<<<1024, blk, 0, stream>>>(e_w1, e1_hi, e1_lo, 2*NEXP);
    split_trans<<<1024, blk, 0, stream>>>(e_w2, e2_hi, e2_lo, 2*NEXP);

    // ================= block 0 =================
    {
        const int i = 0;
        const float* bq = inproj_b + (size_t)i*3*H;
        embed_ln_kernel<<<NF, blk, 0, stream>>>(log_seqs, item_emb, pos_emb, buf0, buf1,
                                                ln1_w + i*H, ln1_b + i*H);
        mfma_z<<<m64z3, blk, 0, stream>>>(buf1, buf0, ip_hi, ip_lo, bq, buf2, NF);
        attn_kernel<<<dim3(BATCH, NHEAD, (SEQL+QT-1)/QT), ablk, 0, stream>>>(buf2, buf3, buf4, buf2, SEQL);
        mfma_z<<<m64z1, blk, 0, stream>>>(buf2, buf2, op_hi, op_lo, outproj_b, buf3, NF);
        ln2_gate_kernel<<<NF, blk, 0, stream>>>(buf1, buf3, buf0, ln2_w + i*H, ln2_b + i*H,
                                                gate_w + (size_t)i*NEXP*H, gate_b + i*NEXP,
                                                top_idx, top_w);
        zero_kernel<<<1, 32, 0, stream>>>((float*)counts, NEXP);
        count_kernel<<<(NF+255)/256, blk, 0, stream>>>(top_idx, counts, NF);
        scan_kernel<<<1, 1, 0, stream>>>(counts, offsets, cursor);
        scatter_kernel<<<(NF+255)/256, blk, 0, stream>>>(top_idx, cursor, pair_tok, tok_pair, NF);
        mfma_moe1<<<m64e, blk, 0, stream>>>(buf0, e1_hi, e1_lo, e_b1 + (size_t)i*NEXP*H,
                                            pair_tok, offsets, counts, buf3);
        mfma_moe2<<<m64e, blk, 0, stream>>>(buf3, e2_hi, e2_lo, e_b2 + (size_t)i*NEXP*H,
                                            offsets, counts, buf1);
        moe_ln_kernel<<<NF, blk, 0, stream>>>(buf0, buf1, tok_pair, top_w, buf3,
                                              moeln_w + i*H, moeln_b + i*H, 1e-5f);
    }

    // ================= block 1 =================
    {
        const int i = 1;
        const float* Wq = inproj_w + (size_t)i*3*H*H;
        const float* bq = inproj_b + (size_t)i*3*H;
        float* X = buf3;
        ln_kernel<<<BATCH, blk, 0, stream>>>(X, nullptr, s0, ln1_w + i*H, ln1_b + i*H, 1e-8f, SEQL-1, SEQL);
        gemm_nt<<<gsmall, blk, 0, stream>>>(s0, Wq, bq, s1, BATCH);
        mfma_z<<<m64z2, blk, 0, stream>>>(X, X, ip_hi + (size_t)3*H*H + (size_t)H*H,
                                          ip_lo + (size_t)3*H*H + (size_t)H*H, bq + H, buf0, NF);
        attn_kernel<<<dim3(BATCH, NHEAD, 1), ablk, 0, stream>>>(s1, buf0, buf1, s2, 1);
        gemm_nt<<<gsmall, blk, 0, stream>>>(s2, outproj_w + (size_t)i*H*H, outproj_b + i*H, s3, BATCH);
        ln2_gate_kernel<<<BATCH, blk, 0, stream>>>(s0, s3, s2, ln2_w + i*H, ln2_b + i*H,
                                                   gate_w + (size_t)i*NEXP*H, gate_b + i*NEXP,
                                                   top_idx, top_w);
        zero_kernel<<<1, 32, 0, stream>>>((float*)counts, NEXP);
        count_kernel<<<1, blk, 0, stream>>>(top_idx, counts, BATCH);
        scan_kernel<<<1, 1, 0, stream>>>(counts, offsets, cursor);
        scatter_kernel<<<1, blk, 0, stream>>>(top_idx, cursor, pair_tok, tok_pair, BATCH);
        moe_gemm1<<<msmall, blk, 0, stream>>>(s2, e_w1 + (size_t)i*NEXP*H*H, e_b1 + (size_t)i*NEXP*H,
                                              pair_tok, offsets, counts, s4);
        moe_gemm2<<<msmall, blk, 0, stream>>>(s4, e_w2 + (size_t)i*NEXP*H*H, e_b2 + (size_t)i*NEXP*H,
                                              offsets, counts, s5);
        moe_ln_kernel<<<BATCH, blk, 0, stream>>>(s2, s5, tok_pair, top_w, s6,
                                                 moeln_w + i*H, moeln_b + i*H, 1e-5f);
    }

    final_kernel<<<BATCH, blk, 0, stream>>>(s6, lastln_w, lastln_b, user_emb, item_emb,
                                            user_ids, item_ids, (float*)d_out);
}

// Round 19
// 891.557 us; speedup vs baseline: 1.0606x; 1.0007x over previous
//
#include <hip/hip_runtime.h>
#include <math.h>

#define H 256
#define NHEAD 4
#define HD 64
#define NEXP 8
#define SEQL 200
#define BATCH 128
#define NF (BATCH*SEQL)
#define KT 64
#define QT 64
#define QW 8

typedef __bf16 bf16x8 __attribute__((ext_vector_type(8)));
typedef float  f32x4  __attribute__((ext_vector_type(4)));

__device__ __forceinline__ void split8(const float* __restrict__ p, bf16x8& hi, bf16x8& lo, bool valid) {
    if (valid) {
        float4 a = *(const float4*)p;
        float4 b = *(const float4*)(p + 4);
        float x[8] = {a.x,a.y,a.z,a.w,b.x,b.y,b.z,b.w};
        #pragma unroll
        for (int j = 0; j < 8; ++j) {
            __bf16 h = (__bf16)x[j];
            hi[j] = h;
            lo[j] = (__bf16)(x[j] - (float)h);
        }
    } else {
        #pragma unroll
        for (int j = 0; j < 8; ++j) { hi[j] = (__bf16)0.f; lo[j] = (__bf16)0.f; }
    }
}

#define MFMA3(AH,AL,BH,BL,ACC) \
    ACC = __builtin_amdgcn_mfma_f32_16x16x32_bf16(AH, BH, ACC, 0, 0, 0); \
    ACC = __builtin_amdgcn_mfma_f32_16x16x32_bf16(AH, BL, ACC, 0, 0, 0); \
    ACC = __builtin_amdgcn_mfma_f32_16x16x32_bf16(AL, BH, ACC, 0, 0, 0);

// ---------------- helpers ----------------
__device__ __forceinline__ float blk_sum256(float v, float* s4) {
    #pragma unroll
    for (int o = 32; o > 0; o >>= 1) v += __shfl_xor(v, o, 64);
    __syncthreads();
    if ((threadIdx.x & 63) == 0) s4[threadIdx.x >> 6] = v;
    __syncthreads();
    return s4[0] + s4[1] + s4[2] + s4[3];
}

// ---------------- weight pre-split ----------------
__global__ __launch_bounds__(256) void split_plain(
    const float* __restrict__ in, __bf16* __restrict__ hi, __bf16* __restrict__ lo, int n)
{
    for (int i = blockIdx.x * 256 + threadIdx.x; i < n; i += gridDim.x * 256) {
        float x = in[i];
        __bf16 h = (__bf16)x;
        hi[i] = h;
        lo[i] = (__bf16)(x - (float)h);
    }
}

// experts: in [m][k][n] -> out [m][n][k]
__global__ __launch_bounds__(256) void split_trans(
    const float* __restrict__ in, __bf16* __restrict__ hi, __bf16* __restrict__ lo, int nmats)
{
    int n = nmats * H * H;
    for (int i = blockIdx.x * 256 + threadIdx.x; i < n; i += gridDim.x * 256) {
        int m = i / (H*H), rem = i % (H*H);
        int nn = rem / H, k = rem % H;
        float x = in[(size_t)m*H*H + (size_t)k*H + nn];
        __bf16 h = (__bf16)x;
        hi[i] = h;
        lo[i] = (__bf16)(x - (float)h);
    }
}

// ---------------- fused embedding + LN1 ----------------
__global__ __launch_bounds__(256) void embed_ln_kernel(
    const int* __restrict__ seqs, const float* __restrict__ item_emb,
    const float* __restrict__ pos_emb, float* __restrict__ x,
    float* __restrict__ xln, const float* __restrict__ w, const float* __restrict__ b)
{
    __shared__ float s4[4];
    int n = blockIdx.x, t = threadIdx.x;
    int id = seqs[n];
    int pos = (id != 0) ? (n % SEQL) + 1 : 0;
    float v = item_emb[(size_t)id*H + t] * 16.0f + pos_emb[(size_t)pos*H + t];
    x[(size_t)n*H + t] = v;
    float mean = blk_sum256(v, s4) * (1.f/H);
    float d = v - mean;
    float var = blk_sum256(d*d, s4) * (1.f/H);
    xln[(size_t)n*H + t] = d * rsqrtf(var + 1e-8f) * w[t] + b[t];
}

// ---------------- layernorm ----------------
__global__ __launch_bounds__(256) void ln_kernel(
    const float* __restrict__ in, const float* __restrict__ res,
    float* __restrict__ out, const float* __restrict__ w, const float* __restrict__ b,
    float eps, int base, int step)
{
    __shared__ float s4[4];
    int r = blockIdx.x, t = threadIdx.x;
    float v = in[(size_t)(base + r*step)*H + t];
    if (res) v += res[(size_t)r*H + t];
    float mean = blk_sum256(v, s4) * (1.f/H);
    float d = v - mean;
    float var = blk_sum256(d*d, s4) * (1.f/H);
    out[(size_t)r*H + t] = d * rsqrtf(var + eps) * w[t] + b[t];
}

// ---------------- fused LN2 + gate top-2 ----------------
__global__ __launch_bounds__(256) void ln2_gate_kernel(
    const float* __restrict__ in, const float* __restrict__ res,
    float* __restrict__ out, const float* __restrict__ w, const float* __restrict__ b,
    const float* __restrict__ gw, const float* __restrict__ gb,
    int* __restrict__ top_idx, float* __restrict__ top_w)
{
    __shared__ float s4[4];
    __shared__ float xs[H];
    __shared__ float gl[NEXP];
    int n = blockIdx.x, t = threadIdx.x;
    float v = in[(size_t)n*H + t] + res[(size_t)n*H + t];
    float mean = blk_sum256(v, s4) * (1.f/H);
    float d = v - mean;
    float var = blk_sum256(d*d, s4) * (1.f/H);
    float r = d * rsqrtf(var + 1e-8f) * w[t] + b[t];
    out[(size_t)n*H + t] = r;
    xs[t] = r;
    __syncthreads();
    int wv = t >> 6, lane = t & 63;
    float xv[4];
    #pragma unroll
    for (int c = 0; c < 4; ++c) xv[c] = xs[lane + (c<<6)];
    #pragma unroll
    for (int s = 0; s < 2; ++s) {
        int e = wv*2 + s;
        float acc = 0.f;
        #pragma unroll
        for (int c = 0; c < 4; ++c) acc += xv[c] * gw[(size_t)e*H + lane + (c<<6)];
        #pragma unroll
        for (int o = 32; o > 0; o >>= 1) acc += __shfl_xor(acc, o, 64);
        if (lane == 0) gl[e] = acc + gb[e];
    }
    __syncthreads();
    if (t == 0) {
        int i0 = 0;
        for (int e = 1; e < NEXP; ++e) if (gl[e] > gl[i0]) i0 = e;
        int i1 = -1;
        for (int e = 0; e < NEXP; ++e) { if (e == i0) continue; if (i1 < 0 || gl[e] > gl[i1]) i1 = e; }
        float e1 = expf(gl[i1] - gl[i0]);
        float w0 = 1.f / (1.f + e1);
        top_idx[n*2+0] = i0; top_idx[n*2+1] = i1;
        top_w[n*2+0] = w0;  top_w[n*2+1] = 1.f - w0;
    }
}

// ---------------- fused moe combine + layernorm ----------------
__global__ __launch_bounds__(256) void moe_ln_kernel(
    const float* __restrict__ x, const float* __restrict__ ybuf,
    const int* __restrict__ tok_pair, const float* __restrict__ top_w,
    float* __restrict__ out, const float* __restrict__ w, const float* __restrict__ b,
    float eps)
{
    __shared__ float s4[4];
    int r = blockIdx.x, t = threadIdx.x;
    int p0 = tok_pair[r*2], p1 = tok_pair[r*2+1];
    float v = x[(size_t)r*H + t]
            + top_w[r*2+0] * ybuf[(size_t)p0*H + t]
            + top_w[r*2+1] * ybuf[(size_t)p1*H + t];
    float mean = blk_sum256(v, s4) * (1.f/H);
    float d = v - mean;
    float var = blk_sum256(d*d, s4) * (1.f/H);
    out[(size_t)r*H + t] = d * rsqrtf(var + eps) * w[t] + b[t];
}

// ---------------- small fp32 GEMM (64x64) — proven, block-1 paths ----------------
__global__ __launch_bounds__(256) void gemm_nt(
    const float* __restrict__ A, const float* __restrict__ W,
    const float* __restrict__ bias, float* __restrict__ out, int nrows)
{
    __shared__ float As[16][68];
    __shared__ float Ws[16][68];
    int r0 = blockIdx.x * 64;
    if (r0 >= nrows) return;
    int c0 = blockIdx.y * 64;
    int tid = threadIdx.x;
    int tx = tid & 15, ty = tid >> 4;
    int lrow = tid >> 2, lkg = (tid & 3) << 2;
    float acc[4][4] = {};
    for (int kk = 0; kk < H; kk += 16) {
        float4 av = make_float4(0.f,0.f,0.f,0.f);
        int gr = r0 + lrow;
        if (gr < nrows) av = *(const float4*)(A + (size_t)gr*H + kk + lkg);
        As[lkg+0][lrow]=av.x; As[lkg+1][lrow]=av.y; As[lkg+2][lrow]=av.z; As[lkg+3][lrow]=av.w;
        float4 wv = *(const float4*)(W + (size_t)(c0+lrow)*H + kk + lkg);
        Ws[lkg+0][lrow]=wv.x; Ws[lkg+1][lrow]=wv.y; Ws[lkg+2][lrow]=wv.z; Ws[lkg+3][lrow]=wv.w;
        __syncthreads();
        #pragma unroll
        for (int k = 0; k < 16; ++k) {
            float4 a = *(const float4*)&As[k][ty<<2];
            float4 bv = *(const float4*)&Ws[k][tx<<2];
            float aa[4] = {a.x,a.y,a.z,a.w};
            float bb[4] = {bv.x,bv.y,bv.z,bv.w};
            #pragma unroll
            for (int ii = 0; ii < 4; ++ii)
                #pragma unroll
                for (int jj = 0; jj < 4; ++jj)
                    acc[ii][jj] += aa[ii] * bb[jj];
        }
        __syncthreads();
    }
    #pragma unroll
    for (int ii = 0; ii < 4; ++ii) {
        int gr = r0 + (ty<<2) + ii;
        if (gr < nrows) {
            #pragma unroll
            for (int jj = 0; jj < 4; ++jj) {
                int gc = c0 + (tx<<2) + jj;
                out[(size_t)gr*H + gc] = acc[ii][jj] + bias[gc];
            }
        }
    }
}

// ---------------- block-1: fold q through Wk -> qt[h][b][256], qbk[b][h] ----------------
__global__ __launch_bounds__(256) void qfold_kernel(
    const float* __restrict__ q, const float* __restrict__ Wk, const float* __restrict__ bk,
    float* __restrict__ qt, float* __restrict__ qbk)
{
    __shared__ float qs[H];
    int b = blockIdx.x, t = threadIdx.x;
    qs[t] = q[(size_t)b*H + t];
    __syncthreads();
    #pragma unroll
    for (int h = 0; h < NHEAD; ++h) {
        float acc = 0.f;
        #pragma unroll 8
        for (int d = 0; d < HD; ++d)
            acc += qs[h*HD + d] * Wk[(size_t)(h*HD + d)*H + t];
        qt[((size_t)h*BATCH + b)*H + t] = acc;
    }
    if (t < NHEAD) {
        float acc = 0.f;
        for (int d = 0; d < HD; ++d) acc += qs[t*HD + d] * bk[t*HD + d];
        qbk[b*NHEAD + t] = acc;
    }
}

// ---------------- block-1: folded attention over raw X -> xbar[h][b][256] --------------
__global__ __launch_bounds__(256) void attn1_kernel(
    const float* __restrict__ qt, const float* __restrict__ qbk,
    const float* __restrict__ X, float* __restrict__ xbar)
{
    __shared__ float qts[NHEAD][H];
    __shared__ float as[NHEAD][SEQL];
    int b = blockIdx.x;
    int tid = threadIdx.x, w = tid >> 6, lane = tid & 63;
    for (int i = tid; i < NHEAD*H; i += 256) {
        int h = i >> 8, j = i & (H-1);
        qts[h][j] = qt[((size_t)h*BATCH + b)*H + j];
    }
    __syncthreads();
    float qb = qbk[b*NHEAD + w];
    const float4 qv = *(const float4*)&qts[w][lane<<2];
    for (int key = 0; key < SEQL; ++key) {
        const float4 xv = *(const float4*)(X + (size_t)(b*SEQL + key)*H + (lane<<2));
        float p = xv.x*qv.x + xv.y*qv.y + xv.z*qv.z + xv.w*qv.w;
        #pragma unroll
        for (int o = 32; o > 0; o >>= 1) p += __shfl_xor(p, o, 64);
        if (lane == 0) as[w][key] = (p + qb) * 0.125f;
    }
    __syncthreads();
    float m = -3e30f;
    for (int key = lane; key < SEQL; key += 64) m = fmaxf(m, as[w][key]);
    #pragma unroll
    for (int o = 32; o > 0; o >>= 1) m = fmaxf(m, __shfl_xor(m, o, 64));
    float sum = 0.f;
    for (int key = lane; key < SEQL; key += 64) {
        float e = expf(as[w][key] - m);
        sum += e;
    }
    #pragma unroll
    for (int o = 32; o > 0; o >>= 1) sum += __shfl_xor(sum, o, 64);
    float inv = 1.f / sum;
    __syncthreads();
    for (int key = lane; key < SEQL; key += 64)
        as[w][key] = expf(as[w][key] - m) * inv;
    __syncthreads();
    float4 acc = make_float4(0.f,0.f,0.f,0.f);
    for (int key = 0; key < SEQL; ++key) {
        float a = as[w][key];
        const float4 xv = *(const float4*)(X + (size_t)(b*SEQL + key)*H + (lane<<2));
        acc.x += a*xv.x; acc.y += a*xv.y; acc.z += a*xv.z; acc.w += a*xv.w;
    }
    *(float4*)(xbar + ((size_t)w*BATCH + b)*H + (lane<<2)) = acc;
}

// ---------------- block-1: ctx = xbar_h @ Wv_h^T + bv_h (per-head small GEMM) ----------
__global__ __launch_bounds__(256) void ctx_gemm(
    const float* __restrict__ xbar, const float* __restrict__ Wv,
    const float* __restrict__ bv, float* __restrict__ out)
{
    int h = blockIdx.z;
    const float* A = xbar + (size_t)h*BATCH*H;
    const float* W = Wv + (size_t)h*HD*H;
    const float* bias = bv + h*HD;
    float* O = out + h*HD;
    __shared__ float As[16][68];
    __shared__ float Ws[16][68];
    int r0 = blockIdx.x * 64;
    int tid = threadIdx.x;
    int tx = tid & 15, ty = tid >> 4;
    int lrow = tid >> 2, lkg = (tid & 3) << 2;
    float acc[4][4] = {};
    for (int kk = 0; kk < H; kk += 16) {
        float4 av = *(const float4*)(A + (size_t)(r0 + lrow)*H + kk + lkg);
        As[lkg+0][lrow]=av.x; As[lkg+1][lrow]=av.y; As[lkg+2][lrow]=av.z; As[lkg+3][lrow]=av.w;
        float4 wv;
        if (lrow < HD) wv = *(const float4*)(W + (size_t)lrow*H + kk + lkg);
        else wv = make_float4(0.f,0.f,0.f,0.f);
        Ws[lkg+0][lrow]=wv.x; Ws[lkg+1][lrow]=wv.y; Ws[lkg+2][lrow]=wv.z; Ws[lkg+3][lrow]=wv.w;
        __syncthreads();
        #pragma unroll
        for (int k = 0; k < 16; ++k) {
            float4 a = *(const float4*)&As[k][ty<<2];
            float4 bv4 = *(const float4*)&Ws[k][tx<<2];
            float aa[4] = {a.x,a.y,a.z,a.w};
            float bb[4] = {bv4.x,bv4.y,bv4.z,bv4.w};
            #pragma unroll
            for (int ii = 0; ii < 4; ++ii)
                #pragma unroll
                for (int jj = 0; jj < 4; ++jj)
                    acc[ii][jj] += aa[ii] * bb[jj];
        }
        __syncthreads();
    }
    #pragma unroll
    for (int ii = 0; ii < 4; ++ii) {
        int gr = r0 + (ty<<2) + ii;
        #pragma unroll
        for (int jj = 0; jj < 4; ++jj) {
            int gc = (tx<<2) + jj;
            if (gc < HD) O[(size_t)gr*H + gc] = acc[ii][jj] + bias[gc];
        }
    }
}

// ---------------- split-bf16 MFMA GEMM body: 64-row stripe, ALL 4 column tiles ----------
template<int GATHER, int RELU>
__device__ __forceinline__ void mfma64_body(
    const float* __restrict__ A, const __bf16* __restrict__ Whi, const __bf16* __restrict__ Wlo,
    const float* __restrict__ bias, float* __restrict__ out, int nrows,
    const int* __restrict__ pair_tok)
{
    int r0 = blockIdx.x * 64;
    if (r0 >= nrows) return;
    int tid = threadIdx.x;
    int wid = tid >> 6, lane = tid & 63;
    int wm = wid >> 1, wn = wid & 1;
    int rbase = r0 + wm*32;
    int lr = lane & 15, lk = (lane >> 4) << 3;
    f32x4 acc[4][2][2] = {};
    int ar0 = rbase + lr, ar1 = ar0 + 16;
    bool v0 = ar0 < nrows, v1 = ar1 < nrows;
    int ga0 = ar0, ga1 = ar1;
    if (GATHER) { ga0 = v0 ? pair_tok[ar0] : 0; ga1 = v1 ? pair_tok[ar1] : 0; }
    const float* ap0 = A + (size_t)(v0 ? ga0 : 0)*H + lk;
    const float* ap1 = A + (size_t)(v1 ? ga1 : 0)*H + lk;
    size_t woff = (size_t)(wn*32 + lr)*H + lk;
    #pragma unroll
    for (int kk = 0; kk < H; kk += 32) {
        bf16x8 ah0, al0, ah1, al1;
        split8(ap0 + kk, ah0, al0, v0);
        split8(ap1 + kk, ah1, al1, v1);
        #pragma unroll
        for (int ct = 0; ct < 4; ++ct) {
            size_t wo = woff + (size_t)ct*64*H + kk;
            bf16x8 bh0 = *(const bf16x8*)(Whi + wo);
            bf16x8 bl0 = *(const bf16x8*)(Wlo + wo);
            bf16x8 bh1 = *(const bf16x8*)(Whi + wo + (size_t)16*H);
            bf16x8 bl1 = *(const bf16x8*)(Wlo + wo + (size_t)16*H);
            MFMA3(ah0, al0, bh0, bl0, acc[ct][0][0]);
            MFMA3(ah0, al0, bh1, bl1, acc[ct][0][1]);
            MFMA3(ah1, al1, bh0, bl0, acc[ct][1][0]);
            MFMA3(ah1, al1, bh1, bl1, acc[ct][1][1]);
        }
    }
    int lro = (lane >> 4) << 2;
    #pragma unroll
    for (int ct = 0; ct < 4; ++ct)
        #pragma unroll
        for (int mi = 0; mi < 2; ++mi)
            #pragma unroll
            for (int ni = 0; ni < 2; ++ni)
                #pragma unroll
                for (int j = 0; j < 4; ++j) {
                    int row = rbase + mi*16 + lro + j;
                    int col = ct*64 + wn*32 + ni*16 + lr;
                    if (row < nrows) {
                        float o = acc[ct][mi][ni][j] + bias[col];
                        if (RELU) o = fmaxf(o, 0.f);
                        out[(size_t)row*H + col] = o;
                    }
                }
}

__global__ __launch_bounds__(256) void mfma_z(
    const float* __restrict__ A0, const float* __restrict__ A1,
    const __bf16* __restrict__ Whi, const __bf16* __restrict__ Wlo,
    const float* __restrict__ biasbase, float* __restrict__ outbase, int nrows)
{
    int z = blockIdx.z;
    const float* A = (z == 0) ? A0 : A1;
    mfma64_body<0,0>(A, Whi + (size_t)z*H*H, Wlo + (size_t)z*H*H,
                     biasbase + (size_t)z*H, outbase + (size_t)z*NF*H, nrows, nullptr);
}

__global__ __launch_bounds__(256) void mfma_moe1(
    const float* __restrict__ X, const __bf16* __restrict__ Whi, const __bf16* __restrict__ Wlo,
    const float* __restrict__ b1base, const int* __restrict__ pair_tok,
    const int* __restrict__ offsets, const int* __restrict__ counts,
    float* __restrict__ hbuf)
{
    int e = blockIdx.z;
    int cnt = counts[e], off = offsets[e];
    mfma64_body<1,1>(X, Whi + (size_t)e*H*H, Wlo + (size_t)e*H*H,
                     b1base + (size_t)e*H, hbuf + (size_t)off*H, cnt, pair_tok + off);
}

__global__ __launch_bounds__(256) void mfma_moe2(
    const float* __restrict__ Hbuf, const __bf16* __restrict__ Whi, const __bf16* __restrict__ Wlo,
    const float* __restrict__ b2base, const int* __restrict__ offsets,
    const int* __restrict__ counts, float* __restrict__ ybuf)
{
    int e = blockIdx.z;
    int cnt = counts[e], off = offsets[e];
    mfma64_body<0,0>(Hbuf + (size_t)off*H, Whi + (size_t)e*H*H, Wlo + (size_t)e*H*H,
                     b2base + (size_t)e*H, ybuf + (size_t)off*H, cnt, nullptr);
}

// ---------------- flash attention — EXACT R15 kernel (proven 175us, 3D grid) ----------
__global__ __launch_bounds__(512) void attn_kernel(
    const float* __restrict__ qbuf, const float* __restrict__ kbuf,
    const float* __restrict__ vbuf, float* __restrict__ ctx, int nq)
{
    __shared__ float kv[KT*(HD+4)];
    __shared__ float qs[QT][HD+4];
    __shared__ float ps[QT][KT+4];
    int b = blockIdx.x, h = blockIdx.y, z = blockIdx.z;
    int qbase = z * QT;
    int nqt = nq - qbase;
    if (nqt <= 0) return;
    if (nqt > QT) nqt = QT;
    int tid = threadIdx.x, w = tid >> 6, lane = tid & 63;
    int off = SEQL - nq;
    for (int i = tid; i < QT*(HD/4); i += 512) {
        int row = i >> 4, c4 = (i & 15) << 2;
        float4 qv = make_float4(0.f,0.f,0.f,0.f);
        if (row < nqt) qv = *(const float4*)(qbuf + (size_t)(b*nq + qbase + row)*H + h*HD + c4);
        *(float4*)&qs[row][c4] = qv;
    }
    float m[QW], l[QW], acc[QW];
    #pragma unroll
    for (int i = 0; i < QW; ++i) { m[i] = -3e30f; l[i] = 0.f; acc[i] = 0.f; }
    int wq0 = w * QW;
    int wqn = nqt - wq0; if (wqn > QW) wqn = QW;
    int wmaxpos = qbase + wq0 + (wqn > 0 ? wqn - 1 : 0) + off;
    int ntiles = (qbase + nqt - 1 + off) / KT + 1;
    int q_sub = lane >> 3, kq = lane & 7;
    for (int t = 0; t < ntiles; ++t) {
        int kbase = t * KT;
        bool active = (wqn > 0) && (kbase <= wmaxpos);
        __syncthreads();
        for (int i = tid; i < KT*(HD/4); i += 512) {
            int row = i >> 4, c4 = (i & 15) << 2;
            int key = kbase + row;
            float4 kvv = make_float4(0.f,0.f,0.f,0.f);
            if (key < SEQL) kvv = *(const float4*)(kbuf + (size_t)(b*SEQL + key)*H + h*HD + c4);
            *(float4*)&kv[row*(HD+4) + c4] = kvv;
        }
        __syncthreads();
        if (active) {
            float s[QW];
            #pragma unroll
            for (int qi = 0; qi < QW; ++qi) s[qi] = 0.f;
            #pragma unroll 4
            for (int d4 = 0; d4 < HD; d4 += 4) {
                float4 k4 = *(const float4*)&kv[lane*(HD+4) + d4];
                #pragma unroll
                for (int qi = 0; qi < QW; ++qi) {
                    float4 q4 = *(const float4*)&qs[wq0+qi][d4];
                    s[qi] += k4.x*q4.x + k4.y*q4.y + k4.z*q4.z + k4.w*q4.w;
                }
            }
            #pragma unroll
            for (int qi = 0; qi < QW; ++qi) {
                if (qi < wqn) {
                    int qpos = qbase + wq0 + qi + off;
                    bool valid = (kbase + lane) <= qpos;
                    ps[wq0+qi][lane] = valid ? s[qi]*0.125f : -3e30f;
                }
            }
        }
        __syncthreads();
        {
            int key = kbase + lane;
            bool kval = key < SEQL;
            const float* vp = vbuf + (size_t)(b*SEQL + (kval ? key : 0))*H + h*HD;
            #pragma unroll
            for (int it = 0; it < 2; ++it) {
                int c4 = ((it << 3) + w) << 2;
                float4 vv = make_float4(0.f,0.f,0.f,0.f);
                if (kval) vv = *(const float4*)(vp + c4);
                kv[(c4+0)*(KT+4) + lane] = vv.x;
                kv[(c4+1)*(KT+4) + lane] = vv.y;
                kv[(c4+2)*(KT+4) + lane] = vv.z;
                kv[(c4+3)*(KT+4) + lane] = vv.w;
            }
        }
        __syncthreads();
        if (active) {
            float mq = m[0];
            #pragma unroll
            for (int i = 1; i < QW; ++i) if (q_sub == i) mq = m[i];
            const float2* pr = (const float2*)&ps[wq0+q_sub][kq*8];
            float2 a0 = pr[0], a1 = pr[1], a2 = pr[2], a3 = pr[3];
            float mloc = fmaxf(fmaxf(fmaxf(a0.x,a0.y), fmaxf(a1.x,a1.y)),
                               fmaxf(fmaxf(a2.x,a2.y), fmaxf(a3.x,a3.y)));
            float tm = mloc;
            #pragma unroll
            for (int o = 1; o < 8; o <<= 1) tm = fmaxf(tm, __shfl_xor(tm, o, 64));
            float mn = fmaxf(mq, tm);
            float p0 = expf(a0.x-mn), p1 = expf(a0.y-mn), p2 = expf(a1.x-mn), p3 = expf(a1.y-mn);
            float p4 = expf(a2.x-mn), p5 = expf(a2.y-mn), p6 = expf(a3.x-mn), p7 = expf(a3.y-mn);
            float psum = ((p0+p1)+(p2+p3)) + ((p4+p5)+(p6+p7));
            #pragma unroll
            for (int o = 1; o < 8; o <<= 1) psum += __shfl_xor(psum, o, 64);
            float2* pw = (float2*)&ps[wq0+q_sub][kq*8];
            pw[0] = make_float2(p0,p1); pw[1] = make_float2(p2,p3);
            pw[2] = make_float2(p4,p5); pw[3] = make_float2(p6,p7);
            #pragma unroll
            for (int qi = 0; qi < QW; ++qi) {
                float tmv = __shfl(tm, qi*8, 64);
                float psv = __shfl(psum, qi*8, 64);
                if (qi < wqn) {
                    float mn2 = fmaxf(m[qi], tmv);
                    float scl = expf(m[qi] - mn2);
                    l[qi] = l[qi]*scl + psv;
                    acc[qi] *= scl;
                    m[qi] = mn2;
                }
            }
            #pragma unroll 4
            for (int k4 = 0; k4 < KT; k4 += 4) {
                float4 v4 = *(const float4*)&kv[lane*(KT+4) + k4];
                #pragma unroll
                for (int qi = 0; qi < QW; ++qi) {
                    if (qi < wqn) {
                        float4 p4v = *(const float4*)&ps[wq0+qi][k4];
                        acc[qi] += p4v.x*v4.x + p4v.y*v4.y + p4v.z*v4.z + p4v.w*v4.w;
                    }
                }
            }
        }
    }
    #pragma unroll
    for (int qi = 0; qi < QW; ++qi) {
        if (qi < wqn) {
            ctx[(size_t)(b*nq + qbase + wq0 + qi)*H + h*HD + lane] = acc[qi] / l[qi];
        }
    }
}

// ---------------- count / scan / scatter ----------------
__global__ __launch_bounds__(256) void count_kernel(
    const int* __restrict__ top_idx, int* __restrict__ counts, int nrows)
{
    __shared__ int hist[NEXP];
    int tid = threadIdx.x;
    if (tid < NEXP) hist[tid] = 0;
    __syncthreads();
    int n = blockIdx.x * 256 + tid;
    if (n < nrows) {
        atomicAdd(&hist[top_idx[n*2+0]], 1);
        atomicAdd(&hist[top_idx[n*2+1]], 1);
    }
    __syncthreads();
    if (tid < NEXP && hist[tid] > 0) atomicAdd(&counts[tid], hist[tid]);
}

__global__ void scan_kernel(const int* __restrict__ counts, int* __restrict__ offsets,
                            int* __restrict__ cursor)
{
    int s = 0;
    for (int e = 0; e < NEXP; ++e) { offsets[e] = s; cursor[e] = s; s += counts[e]; }
}

__global__ __launch_bounds__(256) void scatter_kernel(
    const int* __restrict__ top_idx,
    int* __restrict__ cursor, int* __restrict__ pair_tok, int* __restrict__ tok_pair, int nrows)
{
    __shared__ int lcnt[NEXP];
    __shared__ int lbase[NEXP];
    int tid = threadIdx.x;
    if (tid < NEXP) lcnt[tid] = 0;
    __syncthreads();
    int n = blockIdx.x * 256 + tid;
    int e0 = 0, e1 = 0, p0 = 0, p1 = 0;
    bool act = n < nrows;
    if (act) {
        e0 = top_idx[n*2+0]; e1 = top_idx[n*2+1];
        p0 = atomicAdd(&lcnt[e0], 1);
        p1 = atomicAdd(&lcnt[e1], 1);
    }
    __syncthreads();
    if (tid < NEXP) lbase[tid] = (lcnt[tid] > 0) ? atomicAdd(&cursor[tid], lcnt[tid]) : 0;
    __syncthreads();
    if (act) {
        int q0 = lbase[e0] + p0, q1 = lbase[e1] + p1;
        pair_tok[q0] = n; pair_tok[q1] = n;
        tok_pair[n*2+0] = q0; tok_pair[n*2+1] = q1;
    }
}

// ---------------- small fp32 MoE GEMMs (block-1) ----------------
__global__ __launch_bounds__(256) void moe_gemm1(
    const float* __restrict__ X, const float* __restrict__ W1base,
    const float* __restrict__ b1base, const int* __restrict__ pair_tok,
    const int* __restrict__ offsets, const int* __restrict__ counts,
    float* __restrict__ hbuf)
{
    int e = blockIdx.z;
    int cnt = counts[e];
    int r0 = blockIdx.x * 64;
    if (r0 >= cnt) return;
    int off = offsets[e];
    int c0 = blockIdx.y * 64;
    const float* W = W1base + (size_t)e * H * H;
    const float* bias = b1base + (size_t)e * H;
    __shared__ float As[16][68];
    __shared__ float Bs[16][68];
    int tid = threadIdx.x, tx = tid & 15, ty = tid >> 4;
    int lrow = tid >> 2, lkg = (tid & 3) << 2;
    float acc[4][4] = {};
    for (int kk = 0; kk < H; kk += 16) {
        float4 av = make_float4(0.f,0.f,0.f,0.f);
        int pr = r0 + lrow;
        if (pr < cnt) {
            int tok = pair_tok[off + pr];
            av = *(const float4*)(X + (size_t)tok*H + kk + lkg);
        }
        As[lkg+0][lrow]=av.x; As[lkg+1][lrow]=av.y; As[lkg+2][lrow]=av.z; As[lkg+3][lrow]=av.w;
        float4 wv = *(const float4*)(W + (size_t)(kk+ty)*H + c0 + (tx<<2));
        *(float4*)&Bs[ty][tx<<2] = wv;
        __syncthreads();
        #pragma unroll
        for (int k = 0; k < 16; ++k) {
            float4 a = *(const float4*)&As[k][ty<<2];
            float4 bv = *(const float4*)&Bs[k][tx<<2];
            float aa[4] = {a.x,a.y,a.z,a.w};
            float bb[4] = {bv.x,bv.y,bv.z,bv.w};
            #pragma unroll
            for (int ii = 0; ii < 4; ++ii)
                #pragma unroll
                for (int jj = 0; jj < 4; ++jj)
                    acc[ii][jj] += aa[ii] * bb[jj];
        }
        __syncthreads();
    }
    #pragma unroll
    for (int ii = 0; ii < 4; ++ii) {
        int pr = r0 + (ty<<2) + ii;
        if (pr < cnt) {
            #pragma unroll
            for (int jj = 0; jj < 4; ++jj) {
                int gc = c0 + (tx<<2) + jj;
                hbuf[(size_t)(off+pr)*H + gc] = fmaxf(acc[ii][jj] + bias[gc], 0.f);
            }
        }
    }
}

__global__ __launch_bounds__(256) void moe_gemm2(
    const float* __restrict__ Hbuf, const float* __restrict__ W2base,
    const float* __restrict__ b2base, const int* __restrict__ offsets,
    const int* __restrict__ counts, float* __restrict__ ybuf)
{
    int e = blockIdx.z;
    int cnt = counts[e];
    int r0 = blockIdx.x * 64;
    if (r0 >= cnt) return;
    int off = offsets[e];
    int c0 = blockIdx.y * 64;
    const float* W = W2base + (size_t)e * H * H;
    const float* bias = b2base + (size_t)e * H;
    __shared__ float As[16][68];
    __shared__ float Bs[16][68];
    int tid = threadIdx.x, tx = tid & 15, ty = tid >> 4;
    int lrow = tid >> 2, lkg = (tid & 3) << 2;
    float acc[4][4] = {};
    for (int kk = 0; kk < H; kk += 16) {
        float4 av = make_float4(0.f,0.f,0.f,0.f);
        int pr = r0 + lrow;
        if (pr < cnt) av = *(const float4*)(Hbuf + (size_t)(off+pr)*H + kk + lkg);
        As[lkg+0][lrow]=av.x; As[lkg+1][lrow]=av.y; As[lkg+2][lrow]=av.z; As[lkg+3][lrow]=av.w;
        float4 wv = *(const float4*)(W + (size_t)(kk+ty)*H + c0 + (tx<<2));
        *(float4*)&Bs[ty][tx<<2] = wv;
        __syncthreads();
        #pragma unroll
        for (int k = 0; k < 16; ++k) {
            float4 a = *(const float4*)&As[k][ty<<2];
            float4 bv = *(const float4*)&Bs[k][tx<<2];
            float aa[4] = {a.x,a.y,a.z,a.w};
            float bb[4] = {bv.x,bv.y,bv.z,bv.w};
            #pragma unroll
            for (int ii = 0; ii < 4; ++ii)
                #pragma unroll
                for (int jj = 0; jj < 4; ++jj)
                    acc[ii][jj] += aa[ii] * bb[jj];
        }
        __syncthreads();
    }
    #pragma unroll
    for (int ii = 0; ii < 4; ++ii) {
        int pr = r0 + (ty<<2) + ii;
        if (pr < cnt) {
            #pragma unroll
            for (int jj = 0; jj < 4; ++jj) {
                int gc = c0 + (tx<<2) + jj;
                ybuf[(size_t)(off+pr)*H + gc] = acc[ii][jj] + bias[gc];
            }
        }
    }
}

__global__ void zero_kernel(float* __restrict__ p, int n) {
    int i = blockIdx.x * 256 + threadIdx.x;
    if (i < n) p[i] = 0.f;
}

// ---------------- final ----------------
__global__ __launch_bounds__(256) void final_kernel(
    const float* __restrict__ xf, const float* __restrict__ lnw, const float* __restrict__ lnb,
    const float* __restrict__ user_emb, const float* __restrict__ item_emb,
    const int* __restrict__ user_ids, const int* __restrict__ item_ids, float* __restrict__ out)
{
    __shared__ float s4[4];
    int bb = blockIdx.x, t = threadIdx.x;
    float v = xf[(size_t)bb*H + t];
    float mean = blk_sum256(v, s4) * (1.f/H);
    float d = v - mean;
    float var = blk_sum256(d*d, s4) * (1.f/H);
    float lnv = d * rsqrtf(var + 1e-8f) * lnw[t] + lnb[t];
    float fin = lnv + user_emb[(size_t)user_ids[bb]*H + t];
    float prod = fin * item_emb[(size_t)item_ids[bb]*H + t];
    float tot = blk_sum256(prod, s4);
    if (t == 0) out[bb] = tot;
}

// ---------------- launch ----------------
extern "C" void kernel_launch(void* const* d_in, const int* in_sizes, int n_in,
                              void* d_out, int out_size, void* d_ws, size_t ws_size,
                              hipStream_t stream)
{
    (void)in_sizes; (void)n_in; (void)out_size; (void)ws_size;
    const int*   user_ids  = (const int*)d_in[0];
    const int*   log_seqs  = (const int*)d_in[1];
    const int*   item_ids  = (const int*)d_in[2];
    const float* item_emb  = (const float*)d_in[3];
    const float* pos_emb   = (const float*)d_in[4];
    const float* user_emb  = (const float*)d_in[5];
    const float* ln1_w     = (const float*)d_in[6];
    const float* ln1_b     = (const float*)d_in[7];
    const float* inproj_w  = (const float*)d_in[8];
    const float* inproj_b  = (const float*)d_in[9];
    const float* outproj_w = (const float*)d_in[10];
    const float* outproj_b = (const float*)d_in[11];
    const float* ln2_w     = (const float*)d_in[12];
    const float* ln2_b     = (const float*)d_in[13];
    const float* gate_w    = (const float*)d_in[14];
    const float* gate_b    = (const float*)d_in[15];
    const float* e_w1      = (const float*)d_in[16];
    const float* e_b1      = (const float*)d_in[17];
    const float* e_w2      = (const float*)d_in[18];
    const float* e_b2      = (const float*)d_in[19];
    const float* moeln_w   = (const float*)d_in[20];
    const float* moeln_b   = (const float*)d_in[21];
    const float* lastln_w  = (const float*)d_in[22];
    const float* lastln_b  = (const float*)d_in[23];

    float* ws = (float*)d_ws;
    const size_t NFH = (size_t)NF * H;
    float* buf0 = ws;
    float* buf1 = buf0 + NFH;
    float* buf2 = buf1 + NFH;
    float* buf3 = buf2 + NFH;
    float* buf4 = buf3 + NFH;
    float* s0   = buf4 + NFH;
    float* s1   = s0 + (size_t)BATCH*H;
    float* s2   = s1 + (size_t)BATCH*H;
    float* s3   = s2 + (size_t)BATCH*H;
    float* s6   = s3 + (size_t)BATCH*H;
    float* s4   = s6 + (size_t)BATCH*H;
    float* s5   = s4 + (size_t)2*BATCH*H;
    float* top_w   = s5 + (size_t)2*BATCH*H;
    int*   top_idx = (int*)(top_w + (size_t)NF*2);
    int*   pair_tok= top_idx + (size_t)NF*2;
    int*   tok_pair= pair_tok + (size_t)NF*2;
    int*   counts  = tok_pair + (size_t)NF*2;
    int*   offsets = counts + NEXP;
    int*   cursor  = offsets + NEXP;
    // bf16 split-weight regions
    const size_t W_IP = (size_t)2*3*H*H;
    const size_t W_OP = (size_t)2*H*H;
    const size_t W_E  = (size_t)2*NEXP*H*H;
    __bf16* ip_hi = (__bf16*)(cursor + 64);
    __bf16* ip_lo = ip_hi + W_IP;
    __bf16* op_hi = ip_lo + W_IP;
    __bf16* op_lo = op_hi + W_OP;
    __bf16* e1_hi = op_lo + W_OP;
    __bf16* e1_lo = e1_hi + W_E;
    __bf16* e2_hi = e1_lo + W_E;
    __bf16* e2_lo = e2_hi + W_E;
    // block-1 folded-attention scratch (buf4 free during block 1)
    float* qt   = buf4;
    float* xbar = qt + (size_t)NHEAD*BATCH*H;
    float* qbk  = xbar + (size_t)NHEAD*BATCH*H;

    dim3 blk(256);
    dim3 ablk(512);
    dim3 m64z3(NF/64, 1, 3);
    dim3 m64z1(NF/64, 1, 1);
    dim3 m64e(NF/64, 1, NEXP);
    dim3 gsmall((BATCH+63)/64, H/64);
    dim3 msmall((BATCH+63)/64, H/64, NEXP);

    // pre-split weights (once per launch)
    split_plain<<<512, blk, 0, stream>>>(inproj_w,  ip_hi, ip_lo, (int)W_IP);
    split_plain<<<256, blk, 0, stream>>>(outproj_w, op_hi, op_lo, (int)W_OP);
    split_trans<<<1024, blk, 0, stream>>>(e_w1, e1_hi, e1_lo, 2*NEXP);
    split_trans<<<1024, blk, 0, stream>>>(e_w2, e2_hi, e2_lo, 2*NEXP);

    // ================= block 0 =================
    {
        const int i = 0;
        const float* bq = inproj_b + (size_t)i*3*H;
        embed_ln_kernel<<<NF, blk, 0, stream>>>(log_seqs, item_emb, pos_emb, buf0, buf1,
                                                ln1_w + i*H, ln1_b + i*H);
        mfma_z<<<m64z3, blk, 0, stream>>>(buf1, buf0, ip_hi, ip_lo, bq, buf2, NF);
        attn_kernel<<<dim3(BATCH, NHEAD, (SEQL+QT-1)/QT), ablk, 0, stream>>>(buf2, buf3, buf4, buf2, SEQL);
        mfma_z<<<m64z1, blk, 0, stream>>>(buf2, buf2, op_hi, op_lo, outproj_b, buf3, NF);
        ln2_gate_kernel<<<NF, blk, 0, stream>>>(buf1, buf3, buf0, ln2_w + i*H, ln2_b + i*H,
                                                gate_w + (size_t)i*NEXP*H, gate_b + i*NEXP,
                                                top_idx, top_w);
        zero_kernel<<<1, 32, 0, stream>>>((float*)counts, NEXP);
        count_kernel<<<(NF+255)/256, blk, 0, stream>>>(top_idx, counts, NF);
        scan_kernel<<<1, 1, 0, stream>>>(counts, offsets, cursor);
        scatter_kernel<<<(NF+255)/256, blk, 0, stream>>>(top_idx, cursor, pair_tok, tok_pair, NF);
        mfma_moe1<<<m64e, blk, 0, stream>>>(buf0, e1_hi, e1_lo, e_b1 + (size_t)i*NEXP*H,
                                            pair_tok, offsets, counts, buf3);
        mfma_moe2<<<m64e, blk, 0, stream>>>(buf3, e2_hi, e2_lo, e_b2 + (size_t)i*NEXP*H,
                                            offsets, counts, buf1);
        moe_ln_kernel<<<NF, blk, 0, stream>>>(buf0, buf1, tok_pair, top_w, buf3,
                                              moeln_w + i*H, moeln_b + i*H, 1e-5f);
    }

    // ================= block 1 : folded attention (K/V GEMMs eliminated) ==============
    {
        const int i = 1;
        const float* Wq = inproj_w + (size_t)i*3*H*H;
        const float* Wk = Wq + (size_t)H*H;
        const float* Wv = Wk + (size_t)H*H;
        const float* bq = inproj_b + (size_t)i*3*H;
        float* X = buf3;
        ln_kernel<<<BATCH, blk, 0, stream>>>(X, nullptr, s0, ln1_w + i*H, ln1_b + i*H, 1e-8f, SEQL-1, SEQL);
        gemm_nt<<<gsmall, blk, 0, stream>>>(s0, Wq, bq, s1, BATCH);
        qfold_kernel<<<BATCH, blk, 0, stream>>>(s1, Wk, bq + H, qt, qbk);
        attn1_kernel<<<BATCH, blk, 0, stream>>>(qt, qbk, X, xbar);
        ctx_gemm<<<dim3(BATCH/64, 1, NHEAD), blk, 0, stream>>>(xbar, Wv, bq + 2*H, s2);
        gemm_nt<<<gsmall, blk, 0, stream>>>(s2, outproj_w + (size_t)i*H*H, outproj_b + i*H, s3, BATCH);
        ln2_gate_kernel<<<BATCH, blk, 0, stream>>>(s0, s3, s2, ln2_w + i*H, ln2_b + i*H,
                                                   gate_w + (size_t)i*NEXP*H, gate_b + i*NEXP,
                                                   top_idx, top_w);
        zero_kernel<<<1, 32, 0, stream>>>((float*)counts, NEXP);
        count_kernel<<<1, blk, 0, stream>>>(top_idx, counts, BATCH);
        scan_kernel<<<1, 1, 0, stream>>>(counts, offsets, cursor);
        scatter_kernel<<<1, blk, 0, stream>>>(top_idx, cursor, pair_tok, tok_pair, BATCH);
        moe_gemm1<<<msmall, blk, 0, stream>>>(s2, e_w1 + (size_t)i*NEXP*H*H, e_b1 + (size_t)i*NEXP*H,
                                              pair_tok, offsets, counts, s4);
        moe_gemm2<<<msmall, blk, 0, stream>>>(s4, e_w2 + (size_t)i*NEXP*H*H, e_b2 + (size_t)i*NEXP*H,
                                              offsets, counts, s5);
        moe_ln_kernel<<<BATCH, blk, 0, stream>>>(s2, s5, tok_pair, top_w, s6,
                                                 moeln_w + i*H, moeln_b + i*H, 1e-5f);
    }

    final_kernel<<<BATCH, blk, 0, stream>>>(s6, lastln_w, lastln_b, user_emb, item_emb,
                                            user_ids, item_ids, (float*)d_out);
}

// Round 20
// 848.274 us; speedup vs baseline: 1.1148x; 1.0510x over previous
//
#include <hip/hip_runtime.h>
#include <math.h>

#define H 256
#define NHEAD 4
#define HD 64
#define NEXP 8
#define SEQL 200
#define BATCH 128
#define NF (BATCH*SEQL)
#define KT 64
#define QT 64
#define QW 8

typedef __bf16 bf16x8 __attribute__((ext_vector_type(8)));
typedef float  f32x4  __attribute__((ext_vector_type(4)));

__device__ __forceinline__ void split8(const float* __restrict__ p, bf16x8& hi, bf16x8& lo, bool valid) {
    if (valid) {
        float4 a = *(const float4*)p;
        float4 b = *(const float4*)(p + 4);
        float x[8] = {a.x,a.y,a.z,a.w,b.x,b.y,b.z,b.w};
        #pragma unroll
        for (int j = 0; j < 8; ++j) {
            __bf16 h = (__bf16)x[j];
            hi[j] = h;
            lo[j] = (__bf16)(x[j] - (float)h);
        }
    } else {
        #pragma unroll
        for (int j = 0; j < 8; ++j) { hi[j] = (__bf16)0.f; lo[j] = (__bf16)0.f; }
    }
}

#define MFMA3(AH,AL,BH,BL,ACC) \
    ACC = __builtin_amdgcn_mfma_f32_16x16x32_bf16(AH, BH, ACC, 0, 0, 0); \
    ACC = __builtin_amdgcn_mfma_f32_16x16x32_bf16(AH, BL, ACC, 0, 0, 0); \
    ACC = __builtin_amdgcn_mfma_f32_16x16x32_bf16(AL, BH, ACC, 0, 0, 0);

// ---------------- helpers ----------------
__device__ __forceinline__ float blk_sum256(float v, float* s4) {
    #pragma unroll
    for (int o = 32; o > 0; o >>= 1) v += __shfl_xor(v, o, 64);
    __syncthreads();
    if ((threadIdx.x & 63) == 0) s4[threadIdx.x >> 6] = v;
    __syncthreads();
    return s4[0] + s4[1] + s4[2] + s4[3];
}

// ---------------- fused weight pre-split (1 dispatch) ----------------
__global__ __launch_bounds__(256) void split_all(
    const float* __restrict__ ipw, const float* __restrict__ opw,
    const float* __restrict__ ew1, const float* __restrict__ ew2,
    __bf16* __restrict__ ip_hi, __bf16* __restrict__ ip_lo,
    __bf16* __restrict__ op_hi, __bf16* __restrict__ op_lo,
    __bf16* __restrict__ e1_hi, __bf16* __restrict__ e1_lo,
    __bf16* __restrict__ e2_hi, __bf16* __restrict__ e2_lo)
{
    const int N_IP = 2*3*H*H;
    const int N_OP = 2*H*H;
    const int N_E  = 2*NEXP*H*H;
    const int TOT  = N_IP + N_OP + 2*N_E;
    for (int i = blockIdx.x*256 + threadIdx.x; i < TOT; i += gridDim.x*256) {
        float x; __bf16 *hi, *lo; int idx;
        if (i < N_IP) {
            idx = i; x = ipw[idx]; hi = ip_hi; lo = ip_lo;
        } else if (i < N_IP + N_OP) {
            idx = i - N_IP; x = opw[idx]; hi = op_hi; lo = op_lo;
        } else if (i < N_IP + N_OP + N_E) {
            idx = i - N_IP - N_OP;
            int m = idx/(H*H), rem = idx%(H*H); int nn = rem/H, k = rem%H;
            x = ew1[(size_t)m*H*H + (size_t)k*H + nn]; hi = e1_hi; lo = e1_lo;
        } else {
            idx = i - N_IP - N_OP - N_E;
            int m = idx/(H*H), rem = idx%(H*H); int nn = rem/H, k = rem%H;
            x = ew2[(size_t)m*H*H + (size_t)k*H + nn]; hi = e2_hi; lo = e2_lo;
        }
        __bf16 h = (__bf16)x;
        hi[idx] = h;
        lo[idx] = (__bf16)(x - (float)h);
    }
}

// ---------------- fused embedding + LN1 ----------------
__global__ __launch_bounds__(256) void embed_ln_kernel(
    const int* __restrict__ seqs, const float* __restrict__ item_emb,
    const float* __restrict__ pos_emb, float* __restrict__ x,
    float* __restrict__ xln, const float* __restrict__ w, const float* __restrict__ b)
{
    __shared__ float s4[4];
    int n = blockIdx.x, t = threadIdx.x;
    int id = seqs[n];
    int pos = (id != 0) ? (n % SEQL) + 1 : 0;
    float v = item_emb[(size_t)id*H + t] * 16.0f + pos_emb[(size_t)pos*H + t];
    x[(size_t)n*H + t] = v;
    float mean = blk_sum256(v, s4) * (1.f/H);
    float d = v - mean;
    float var = blk_sum256(d*d, s4) * (1.f/H);
    xln[(size_t)n*H + t] = d * rsqrtf(var + 1e-8f) * w[t] + b[t];
}

// ---------------- fused LN2 + gate top-2 (block 0) ----------------
__global__ __launch_bounds__(256) void ln2_gate_kernel(
    const float* __restrict__ in, const float* __restrict__ res,
    float* __restrict__ out, const float* __restrict__ w, const float* __restrict__ b,
    const float* __restrict__ gw, const float* __restrict__ gb,
    int* __restrict__ top_idx, float* __restrict__ top_w)
{
    __shared__ float s4[4];
    __shared__ float xs[H];
    __shared__ float gl[NEXP];
    int n = blockIdx.x, t = threadIdx.x;
    float v = in[(size_t)n*H + t] + res[(size_t)n*H + t];
    float mean = blk_sum256(v, s4) * (1.f/H);
    float d = v - mean;
    float var = blk_sum256(d*d, s4) * (1.f/H);
    float r = d * rsqrtf(var + 1e-8f) * w[t] + b[t];
    out[(size_t)n*H + t] = r;
    xs[t] = r;
    __syncthreads();
    int wv = t >> 6, lane = t & 63;
    float xv[4];
    #pragma unroll
    for (int c = 0; c < 4; ++c) xv[c] = xs[lane + (c<<6)];
    #pragma unroll
    for (int s = 0; s < 2; ++s) {
        int e = wv*2 + s;
        float acc = 0.f;
        #pragma unroll
        for (int c = 0; c < 4; ++c) acc += xv[c] * gw[(size_t)e*H + lane + (c<<6)];
        #pragma unroll
        for (int o = 32; o > 0; o >>= 1) acc += __shfl_xor(acc, o, 64);
        if (lane == 0) gl[e] = acc + gb[e];
    }
    __syncthreads();
    if (t == 0) {
        int i0 = 0;
        for (int e = 1; e < NEXP; ++e) if (gl[e] > gl[i0]) i0 = e;
        int i1 = -1;
        for (int e = 0; e < NEXP; ++e) { if (e == i0) continue; if (i1 < 0 || gl[e] > gl[i1]) i1 = e; }
        float e1 = expf(gl[i1] - gl[i0]);
        float w0 = 1.f / (1.f + e1);
        top_idx[n*2+0] = i0; top_idx[n*2+1] = i1;
        top_w[n*2+0] = w0;  top_w[n*2+1] = 1.f - w0;
    }
}

// ---------------- fused moe combine + layernorm ----------------
__global__ __launch_bounds__(256) void moe_ln_kernel(
    const float* __restrict__ x, const float* __restrict__ ybuf,
    const int* __restrict__ tok_pair, const float* __restrict__ top_w,
    float* __restrict__ out, const float* __restrict__ w, const float* __restrict__ b,
    float eps)
{
    __shared__ float s4[4];
    int r = blockIdx.x, t = threadIdx.x;
    int p0 = tok_pair[r*2], p1 = tok_pair[r*2+1];
    float v = x[(size_t)r*H + t]
            + top_w[r*2+0] * ybuf[(size_t)p0*H + t]
            + top_w[r*2+1] * ybuf[(size_t)p1*H + t];
    float mean = blk_sum256(v, s4) * (1.f/H);
    float d = v - mean;
    float var = blk_sum256(d*d, s4) * (1.f/H);
    out[(size_t)r*H + t] = d * rsqrtf(var + eps) * w[t] + b[t];
}

// ---------------- block-1: ENTIRE per-row chain in one kernel ----------------
// LN1 -> q GEMV -> q-fold -> folded attention over X -> ctx GEMV -> outproj GEMV
// -> LN2 -> gate top-2 (+ counts atomics). grid = BATCH, 256 threads.
__global__ __launch_bounds__(256) void block1_fused(
    const float* __restrict__ X,
    const float* __restrict__ ln1w, const float* __restrict__ ln1b,
    const float* __restrict__ Wq, const float* __restrict__ bq,
    const float* __restrict__ Wk, const float* __restrict__ bk,
    const float* __restrict__ Wv, const float* __restrict__ bv,
    const float* __restrict__ Wo, const float* __restrict__ bo,
    const float* __restrict__ ln2w, const float* __restrict__ ln2b,
    const float* __restrict__ gw, const float* __restrict__ gb,
    float* __restrict__ s2_out, int* __restrict__ top_idx, float* __restrict__ top_w,
    int* __restrict__ counts)
{
    __shared__ float s4r[4];
    __shared__ float s0s[H];
    __shared__ float qs[H];
    __shared__ float qts[NHEAD][H];
    __shared__ float qbks[NHEAD];
    __shared__ float as_[NHEAD][SEQL];
    __shared__ float xbars[NHEAD][H];
    __shared__ float ctxs[H];
    __shared__ float gl[NEXP];
    int b = blockIdx.x, t = threadIdx.x;
    int w = t >> 6, lane = t & 63;
    // ---- LN1 on last row ----
    float v = X[(size_t)(b*SEQL + SEQL-1)*H + t];
    float mean = blk_sum256(v, s4r) * (1.f/H);
    float d = v - mean;
    float var = blk_sum256(d*d, s4r) * (1.f/H);
    float s0v = d * rsqrtf(var + 1e-8f) * ln1w[t] + ln1b[t];
    s0s[t] = s0v;
    __syncthreads();
    // ---- q = s0 @ Wq^T + bq ----
    {
        const float* wr = Wq + (size_t)t*H;
        float acc = 0.f;
        for (int dd = 0; dd < H; dd += 4) {
            float4 w4 = *(const float4*)(wr + dd);
            acc += s0s[dd]*w4.x + s0s[dd+1]*w4.y + s0s[dd+2]*w4.z + s0s[dd+3]*w4.w;
        }
        qs[t] = acc + bq[t];
    }
    __syncthreads();
    // ---- fold q through Wk: qt_h[t] = sum_d q[h*64+d] * Wk[(h*64+d)*H + t] ----
    #pragma unroll
    for (int h = 0; h < NHEAD; ++h) {
        float acc = 0.f;
        #pragma unroll 8
        for (int dd = 0; dd < HD; ++dd)
            acc += qs[h*HD + dd] * Wk[(size_t)(h*HD + dd)*H + t];
        qts[h][t] = acc;
    }
    if (t < NHEAD) {
        float acc = 0.f;
        for (int dd = 0; dd < HD; ++dd) acc += qs[t*HD + dd] * bk[t*HD + dd];
        qbks[t] = acc;
    }
    __syncthreads();
    // ---- folded attention: wave w = head ----
    {
        float qb = qbks[w];
        const float4 qv = *(const float4*)&qts[w][lane<<2];
        for (int key = 0; key < SEQL; ++key) {
            const float4 xv = *(const float4*)(X + (size_t)(b*SEQL + key)*H + (lane<<2));
            float p = xv.x*qv.x + xv.y*qv.y + xv.z*qv.z + xv.w*qv.w;
            #pragma unroll
            for (int o = 32; o > 0; o >>= 1) p += __shfl_xor(p, o, 64);
            if (lane == 0) as_[w][key] = (p + qb) * 0.125f;
        }
        __syncthreads();
        float m = -3e30f;
        for (int key = lane; key < SEQL; key += 64) m = fmaxf(m, as_[w][key]);
        #pragma unroll
        for (int o = 32; o > 0; o >>= 1) m = fmaxf(m, __shfl_xor(m, o, 64));
        float sum = 0.f;
        for (int key = lane; key < SEQL; key += 64) sum += expf(as_[w][key] - m);
        #pragma unroll
        for (int o = 32; o > 0; o >>= 1) sum += __shfl_xor(sum, o, 64);
        float inv = 1.f / sum;
        __syncthreads();
        for (int key = lane; key < SEQL; key += 64)
            as_[w][key] = expf(as_[w][key] - m) * inv;
        __syncthreads();
        float4 acc4 = make_float4(0.f,0.f,0.f,0.f);
        for (int key = 0; key < SEQL; ++key) {
            float a = as_[w][key];
            const float4 xv = *(const float4*)(X + (size_t)(b*SEQL + key)*H + (lane<<2));
            acc4.x += a*xv.x; acc4.y += a*xv.y; acc4.z += a*xv.z; acc4.w += a*xv.w;
        }
        *(float4*)&xbars[w][lane<<2] = acc4;
    }
    __syncthreads();
    // ---- ctx[t] = xbar_{t>>6} @ Wv[t]^T + bv[t] ----
    {
        int h = t >> 6;
        const float* wr = Wv + (size_t)t*H;
        float acc = 0.f;
        for (int dd = 0; dd < H; dd += 4) {
            float4 w4 = *(const float4*)(wr + dd);
            acc += xbars[h][dd]*w4.x + xbars[h][dd+1]*w4.y + xbars[h][dd+2]*w4.z + xbars[h][dd+3]*w4.w;
        }
        ctxs[t] = acc + bv[t];
    }
    __syncthreads();
    // ---- mha = ctx @ Wo^T + bo ----
    float mha;
    {
        const float* wr = Wo + (size_t)t*H;
        float acc = 0.f;
        for (int dd = 0; dd < H; dd += 4) {
            float4 w4 = *(const float4*)(wr + dd);
            acc += ctxs[dd]*w4.x + ctxs[dd+1]*w4.y + ctxs[dd+2]*w4.z + ctxs[dd+3]*w4.w;
        }
        mha = acc + bo[t];
    }
    // ---- LN2 + gate ----
    float v2 = s0s[t] + mha;
    mean = blk_sum256(v2, s4r) * (1.f/H);
    d = v2 - mean;
    var = blk_sum256(d*d, s4r) * (1.f/H);
    float r = d * rsqrtf(var + 1e-8f) * ln2w[t] + ln2b[t];
    s2_out[(size_t)b*H + t] = r;
    __syncthreads();
    s0s[t] = r;   // reuse as gate input
    __syncthreads();
    float xv[4];
    #pragma unroll
    for (int c = 0; c < 4; ++c) xv[c] = s0s[lane + (c<<6)];
    #pragma unroll
    for (int s = 0; s < 2; ++s) {
        int e = w*2 + s;
        float acc = 0.f;
        #pragma unroll
        for (int c = 0; c < 4; ++c) acc += xv[c] * gw[(size_t)e*H + lane + (c<<6)];
        #pragma unroll
        for (int o = 32; o > 0; o >>= 1) acc += __shfl_xor(acc, o, 64);
        if (lane == 0) gl[e] = acc + gb[e];
    }
    __syncthreads();
    if (t == 0) {
        int i0 = 0;
        for (int e = 1; e < NEXP; ++e) if (gl[e] > gl[i0]) i0 = e;
        int i1 = -1;
        for (int e = 0; e < NEXP; ++e) { if (e == i0) continue; if (i1 < 0 || gl[e] > gl[i1]) i1 = e; }
        float e1 = expf(gl[i1] - gl[i0]);
        float w0 = 1.f / (1.f + e1);
        top_idx[b*2+0] = i0; top_idx[b*2+1] = i1;
        top_w[b*2+0] = w0;  top_w[b*2+1] = 1.f - w0;
        atomicAdd(&counts[i0], 1);
        atomicAdd(&counts[i1], 1);
    }
}

// ---------------- split-bf16 MFMA GEMM body: 64-row stripe, ALL 4 column tiles ----------
template<int GATHER, int RELU>
__device__ __forceinline__ void mfma64_body(
    const float* __restrict__ A, const __bf16* __restrict__ Whi, const __bf16* __restrict__ Wlo,
    const float* __restrict__ bias, float* __restrict__ out, int nrows,
    const int* __restrict__ pair_tok)
{
    int r0 = blockIdx.x * 64;
    if (r0 >= nrows) return;
    int tid = threadIdx.x;
    int wid = tid >> 6, lane = tid & 63;
    int wm = wid >> 1, wn = wid & 1;
    int rbase = r0 + wm*32;
    int lr = lane & 15, lk = (lane >> 4) << 3;
    f32x4 acc[4][2][2] = {};
    int ar0 = rbase + lr, ar1 = ar0 + 16;
    bool v0 = ar0 < nrows, v1 = ar1 < nrows;
    int ga0 = ar0, ga1 = ar1;
    if (GATHER) { ga0 = v0 ? pair_tok[ar0] : 0; ga1 = v1 ? pair_tok[ar1] : 0; }
    const float* ap0 = A + (size_t)(v0 ? ga0 : 0)*H + lk;
    const float* ap1 = A + (size_t)(v1 ? ga1 : 0)*H + lk;
    size_t woff = (size_t)(wn*32 + lr)*H + lk;
    #pragma unroll
    for (int kk = 0; kk < H; kk += 32) {
        bf16x8 ah0, al0, ah1, al1;
        split8(ap0 + kk, ah0, al0, v0);
        split8(ap1 + kk, ah1, al1, v1);
        #pragma unroll
        for (int ct = 0; ct < 4; ++ct) {
            size_t wo = woff + (size_t)ct*64*H + kk;
            bf16x8 bh0 = *(const bf16x8*)(Whi + wo);
            bf16x8 bl0 = *(const bf16x8*)(Wlo + wo);
            bf16x8 bh1 = *(const bf16x8*)(Whi + wo + (size_t)16*H);
            bf16x8 bl1 = *(const bf16x8*)(Wlo + wo + (size_t)16*H);
            MFMA3(ah0, al0, bh0, bl0, acc[ct][0][0]);
            MFMA3(ah0, al0, bh1, bl1, acc[ct][0][1]);
            MFMA3(ah1, al1, bh0, bl0, acc[ct][1][0]);
            MFMA3(ah1, al1, bh1, bl1, acc[ct][1][1]);
        }
    }
    int lro = (lane >> 4) << 2;
    #pragma unroll
    for (int ct = 0; ct < 4; ++ct)
        #pragma unroll
        for (int mi = 0; mi < 2; ++mi)
            #pragma unroll
            for (int ni = 0; ni < 2; ++ni)
                #pragma unroll
                for (int j = 0; j < 4; ++j) {
                    int row = rbase + mi*16 + lro + j;
                    int col = ct*64 + wn*32 + ni*16 + lr;
                    if (row < nrows) {
                        float o = acc[ct][mi][ni][j] + bias[col];
                        if (RELU) o = fmaxf(o, 0.f);
                        out[(size_t)row*H + col] = o;
                    }
                }
}

__global__ __launch_bounds__(256) void mfma_z(
    const float* __restrict__ A0, const float* __restrict__ A1,
    const __bf16* __restrict__ Whi, const __bf16* __restrict__ Wlo,
    const float* __restrict__ biasbase, float* __restrict__ outbase, int nrows)
{
    int z = blockIdx.z;
    const float* A = (z == 0) ? A0 : A1;
    mfma64_body<0,0>(A, Whi + (size_t)z*H*H, Wlo + (size_t)z*H*H,
                     biasbase + (size_t)z*H, outbase + (size_t)z*NF*H, nrows, nullptr);
}

__global__ __launch_bounds__(256) void mfma_moe1(
    const float* __restrict__ X, const __bf16* __restrict__ Whi, const __bf16* __restrict__ Wlo,
    const float* __restrict__ b1base, const int* __restrict__ pair_tok,
    const int* __restrict__ offsets, const int* __restrict__ counts,
    float* __restrict__ hbuf)
{
    int e = blockIdx.z;
    int cnt = counts[e], off = offsets[e];
    mfma64_body<1,1>(X, Whi + (size_t)e*H*H, Wlo + (size_t)e*H*H,
                     b1base + (size_t)e*H, hbuf + (size_t)off*H, cnt, pair_tok + off);
}

__global__ __launch_bounds__(256) void mfma_moe2(
    const float* __restrict__ Hbuf, const __bf16* __restrict__ Whi, const __bf16* __restrict__ Wlo,
    const float* __restrict__ b2base, const int* __restrict__ offsets,
    const int* __restrict__ counts, float* __restrict__ ybuf)
{
    int e = blockIdx.z;
    int cnt = counts[e], off = offsets[e];
    mfma64_body<0,0>(Hbuf + (size_t)off*H, Whi + (size_t)e*H*H, Wlo + (size_t)e*H*H,
                     b2base + (size_t)e*H, ybuf + (size_t)off*H, cnt, nullptr);
}

// ---------------- flash attention — EXACT R15 kernel (proven 175us, 3D grid) ----------
__global__ __launch_bounds__(512) void attn_kernel(
    const float* __restrict__ qbuf, const float* __restrict__ kbuf,
    const float* __restrict__ vbuf, float* __restrict__ ctx, int nq)
{
    __shared__ float kv[KT*(HD+4)];
    __shared__ float qs[QT][HD+4];
    __shared__ float ps[QT][KT+4];
    int b = blockIdx.x, h = blockIdx.y, z = blockIdx.z;
    int qbase = z * QT;
    int nqt = nq - qbase;
    if (nqt <= 0) return;
    if (nqt > QT) nqt = QT;
    int tid = threadIdx.x, w = tid >> 6, lane = tid & 63;
    int off = SEQL - nq;
    for (int i = tid; i < QT*(HD/4); i += 512) {
        int row = i >> 4, c4 = (i & 15) << 2;
        float4 qv = make_float4(0.f,0.f,0.f,0.f);
        if (row < nqt) qv = *(const float4*)(qbuf + (size_t)(b*nq + qbase + row)*H + h*HD + c4);
        *(float4*)&qs[row][c4] = qv;
    }
    float m[QW], l[QW], acc[QW];
    #pragma unroll
    for (int i = 0; i < QW; ++i) { m[i] = -3e30f; l[i] = 0.f; acc[i] = 0.f; }
    int wq0 = w * QW;
    int wqn = nqt - wq0; if (wqn > QW) wqn = QW;
    int wmaxpos = qbase + wq0 + (wqn > 0 ? wqn - 1 : 0) + off;
    int ntiles = (qbase + nqt - 1 + off) / KT + 1;
    int q_sub = lane >> 3, kq = lane & 7;
    for (int t = 0; t < ntiles; ++t) {
        int kbase = t * KT;
        bool active = (wqn > 0) && (kbase <= wmaxpos);
        __syncthreads();
        for (int i = tid; i < KT*(HD/4); i += 512) {
            int row = i >> 4, c4 = (i & 15) << 2;
            int key = kbase + row;
            float4 kvv = make_float4(0.f,0.f,0.f,0.f);
            if (key < SEQL) kvv = *(const float4*)(kbuf + (size_t)(b*SEQL + key)*H + h*HD + c4);
            *(float4*)&kv[row*(HD+4) + c4] = kvv;
        }
        __syncthreads();
        if (active) {
            float s[QW];
            #pragma unroll
            for (int qi = 0; qi < QW; ++qi) s[qi] = 0.f;
            #pragma unroll 4
            for (int d4 = 0; d4 < HD; d4 += 4) {
                float4 k4 = *(const float4*)&kv[lane*(HD+4) + d4];
                #pragma unroll
                for (int qi = 0; qi < QW; ++qi) {
                    float4 q4 = *(const float4*)&qs[wq0+qi][d4];
                    s[qi] += k4.x*q4.x + k4.y*q4.y + k4.z*q4.z + k4.w*q4.w;
                }
            }
            #pragma unroll
            for (int qi = 0; qi < QW; ++qi) {
                if (qi < wqn) {
                    int qpos = qbase + wq0 + qi + off;
                    bool valid = (kbase + lane) <= qpos;
                    ps[wq0+qi][lane] = valid ? s[qi]*0.125f : -3e30f;
                }
            }
        }
        __syncthreads();
        {
            int key = kbase + lane;
            bool kval = key < SEQL;
            const float* vp = vbuf + (size_t)(b*SEQL + (kval ? key : 0))*H + h*HD;
            #pragma unroll
            for (int it = 0; it < 2; ++it) {
                int c4 = ((it << 3) + w) << 2;
                float4 vv = make_float4(0.f,0.f,0.f,0.f);
                if (kval) vv = *(const float4*)(vp + c4);
                kv[(c4+0)*(KT+4) + lane] = vv.x;
                kv[(c4+1)*(KT+4) + lane] = vv.y;
                kv[(c4+2)*(KT+4) + lane] = vv.z;
                kv[(c4+3)*(KT+4) + lane] = vv.w;
            }
        }
        __syncthreads();
        if (active) {
            float mq = m[0];
            #pragma unroll
            for (int i = 1; i < QW; ++i) if (q_sub == i) mq = m[i];
            const float2* pr = (const float2*)&ps[wq0+q_sub][kq*8];
            float2 a0 = pr[0], a1 = pr[1], a2 = pr[2], a3 = pr[3];
            float mloc = fmaxf(fmaxf(fmaxf(a0.x,a0.y), fmaxf(a1.x,a1.y)),
                               fmaxf(fmaxf(a2.x,a2.y), fmaxf(a3.x,a3.y)));
            float tm = mloc;
            #pragma unroll
            for (int o = 1; o < 8; o <<= 1) tm = fmaxf(tm, __shfl_xor(tm, o, 64));
            float mn = fmaxf(mq, tm);
            float p0 = expf(a0.x-mn), p1 = expf(a0.y-mn), p2 = expf(a1.x-mn), p3 = expf(a1.y-mn);
            float p4 = expf(a2.x-mn), p5 = expf(a2.y-mn), p6 = expf(a3.x-mn), p7 = expf(a3.y-mn);
            float psum = ((p0+p1)+(p2+p3)) + ((p4+p5)+(p6+p7));
            #pragma unroll
            for (int o = 1; o < 8; o <<= 1) psum += __shfl_xor(psum, o, 64);
            float2* pw = (float2*)&ps[wq0+q_sub][kq*8];
            pw[0] = make_float2(p0,p1); pw[1] = make_float2(p2,p3);
            pw[2] = make_float2(p4,p5); pw[3] = make_float2(p6,p7);
            #pragma unroll
            for (int qi = 0; qi < QW; ++qi) {
                float tmv = __shfl(tm, qi*8, 64);
                float psv = __shfl(psum, qi*8, 64);
                if (qi < wqn) {
                    float mn2 = fmaxf(m[qi], tmv);
                    float scl = expf(m[qi] - mn2);
                    l[qi] = l[qi]*scl + psv;
                    acc[qi] *= scl;
                    m[qi] = mn2;
                }
            }
            #pragma unroll 4
            for (int k4 = 0; k4 < KT; k4 += 4) {
                float4 v4 = *(const float4*)&kv[lane*(KT+4) + k4];
                #pragma unroll
                for (int qi = 0; qi < QW; ++qi) {
                    if (qi < wqn) {
                        float4 p4v = *(const float4*)&ps[wq0+qi][k4];
                        acc[qi] += p4v.x*v4.x + p4v.y*v4.y + p4v.z*v4.z + p4v.w*v4.w;
                    }
                }
            }
        }
    }
    #pragma unroll
    for (int qi = 0; qi < QW; ++qi) {
        if (qi < wqn) {
            ctx[(size_t)(b*nq + qbase + wq0 + qi)*H + h*HD + lane] = acc[qi] / l[qi];
        }
    }
}

// ---------------- count / scan / scatter ----------------
__global__ __launch_bounds__(256) void count_kernel(
    const int* __restrict__ top_idx, int* __restrict__ counts, int nrows)
{
    __shared__ int hist[NEXP];
    int tid = threadIdx.x;
    if (tid < NEXP) hist[tid] = 0;
    __syncthreads();
    int n = blockIdx.x * 256 + tid;
    if (n < nrows) {
        atomicAdd(&hist[top_idx[n*2+0]], 1);
        atomicAdd(&hist[top_idx[n*2+1]], 1);
    }
    __syncthreads();
    if (tid < NEXP && hist[tid] > 0) atomicAdd(&counts[tid], hist[tid]);
}

__global__ void scan_kernel(const int* __restrict__ counts, int* __restrict__ offsets,
                            int* __restrict__ cursor)
{
    int s = 0;
    for (int e = 0; e < NEXP; ++e) { offsets[e] = s; cursor[e] = s; s += counts[e]; }
}

__global__ __launch_bounds__(256) void scatter_kernel(
    const int* __restrict__ top_idx,
    int* __restrict__ cursor, int* __restrict__ pair_tok, int* __restrict__ tok_pair, int nrows)
{
    __shared__ int lcnt[NEXP];
    __shared__ int lbase[NEXP];
    int tid = threadIdx.x;
    if (tid < NEXP) lcnt[tid] = 0;
    __syncthreads();
    int n = blockIdx.x * 256 + tid;
    int e0 = 0, e1 = 0, p0 = 0, p1 = 0;
    bool act = n < nrows;
    if (act) {
        e0 = top_idx[n*2+0]; e1 = top_idx[n*2+1];
        p0 = atomicAdd(&lcnt[e0], 1);
        p1 = atomicAdd(&lcnt[e1], 1);
    }
    __syncthreads();
    if (tid < NEXP) lbase[tid] = (lcnt[tid] > 0) ? atomicAdd(&cursor[tid], lcnt[tid]) : 0;
    __syncthreads();
    if (act) {
        int q0 = lbase[e0] + p0, q1 = lbase[e1] + p1;
        pair_tok[q0] = n; pair_tok[q1] = n;
        tok_pair[n*2+0] = q0; tok_pair[n*2+1] = q1;
    }
}

// ---------------- small fp32 MoE GEMMs (block-1) ----------------
__global__ __launch_bounds__(256) void moe_gemm1(
    const float* __restrict__ X, const float* __restrict__ W1base,
    const float* __restrict__ b1base, const int* __restrict__ pair_tok,
    const int* __restrict__ offsets, const int* __restrict__ counts,
    float* __restrict__ hbuf)
{
    int e = blockIdx.z;
    int cnt = counts[e];
    int r0 = blockIdx.x * 64;
    if (r0 >= cnt) return;
    int off = offsets[e];
    int c0 = blockIdx.y * 64;
    const float* W = W1base + (size_t)e * H * H;
    const float* bias = b1base + (size_t)e * H;
    __shared__ float As[16][68];
    __shared__ float Bs[16][68];
    int tid = threadIdx.x, tx = tid & 15, ty = tid >> 4;
    int lrow = tid >> 2, lkg = (tid & 3) << 2;
    float acc[4][4] = {};
    for (int kk = 0; kk < H; kk += 16) {
        float4 av = make_float4(0.f,0.f,0.f,0.f);
        int pr = r0 + lrow;
        if (pr < cnt) {
            int tok = pair_tok[off + pr];
            av = *(const float4*)(X + (size_t)tok*H + kk + lkg);
        }
        As[lkg+0][lrow]=av.x; As[lkg+1][lrow]=av.y; As[lkg+2][lrow]=av.z; As[lkg+3][lrow]=av.w;
        float4 wv = *(const float4*)(W + (size_t)(kk+ty)*H + c0 + (tx<<2));
        *(float4*)&Bs[ty][tx<<2] = wv;
        __syncthreads();
        #pragma unroll
        for (int k = 0; k < 16; ++k) {
            float4 a = *(const float4*)&As[k][ty<<2];
            float4 bv = *(const float4*)&Bs[k][tx<<2];
            float aa[4] = {a.x,a.y,a.z,a.w};
            float bb[4] = {bv.x,bv.y,bv.z,bv.w};
            #pragma unroll
            for (int ii = 0; ii < 4; ++ii)
                #pragma unroll
                for (int jj = 0; jj < 4; ++jj)
                    acc[ii][jj] += aa[ii] * bb[jj];
        }
        __syncthreads();
    }
    #pragma unroll
    for (int ii = 0; ii < 4; ++ii) {
        int pr = r0 + (ty<<2) + ii;
        if (pr < cnt) {
            #pragma unroll
            for (int jj = 0; jj < 4; ++jj) {
                int gc = c0 + (tx<<2) + jj;
                hbuf[(size_t)(off+pr)*H + gc] = fmaxf(acc[ii][jj] + bias[gc], 0.f);
            }
        }
    }
}

__global__ __launch_bounds__(256) void moe_gemm2(
    const float* __restrict__ Hbuf, const float* __restrict__ W2base,
    const float* __restrict__ b2base, const int* __restrict__ offsets,
    const int* __restrict__ counts, float* __restrict__ ybuf)
{
    int e = blockIdx.z;
    int cnt = counts[e];
    int r0 = blockIdx.x * 64;
    if (r0 >= cnt) return;
    int off = offsets[e];
    int c0 = blockIdx.y * 64;
    const float* W = W2base + (size_t)e * H * H;
    const float* bias = b2base + (size_t)e * H;
    __shared__ float As[16][68];
    __shared__ float Bs[16][68];
    int tid = threadIdx.x, tx = tid & 15, ty = tid >> 4;
    int lrow = tid >> 2, lkg = (tid & 3) << 2;
    float acc[4][4] = {};
    for (int kk = 0; kk < H; kk += 16) {
        float4 av = make_float4(0.f,0.f,0.f,0.f);
        int pr = r0 + lrow;
        if (pr < cnt) av = *(const float4*)(Hbuf + (size_t)(off+pr)*H + kk + lkg);
        As[lkg+0][lrow]=av.x; As[lkg+1][lrow]=av.y; As[lkg+2][lrow]=av.z; As[lkg+3][lrow]=av.w;
        float4 wv = *(const float4*)(W + (size_t)(kk+ty)*H + c0 + (tx<<2));
        *(float4*)&Bs[ty][tx<<2] = wv;
        __syncthreads();
        #pragma unroll
        for (int k = 0; k < 16; ++k) {
            float4 a = *(const float4*)&As[k][ty<<2];
            float4 bv = *(const float4*)&Bs[k][tx<<2];
            float aa[4] = {a.x,a.y,a.z,a.w};
            float bb[4] = {bv.x,bv.y,bv.z,bv.w};
            #pragma unroll
            for (int ii = 0; ii < 4; ++ii)
                #pragma unroll
                for (int jj = 0; jj < 4; ++jj)
                    acc[ii][jj] += aa[ii] * bb[jj];
        }
        __syncthreads();
    }
    #pragma unroll
    for (int ii = 0; ii < 4; ++ii) {
        int pr = r0 + (ty<<2) + ii;
        if (pr < cnt) {
            #pragma unroll
            for (int jj = 0; jj < 4; ++jj) {
                int gc = c0 + (tx<<2) + jj;
                ybuf[(size_t)(off+pr)*H + gc] = acc[ii][jj] + bias[gc];
            }
        }
    }
}

__global__ void zero_kernel(float* __restrict__ p, int n) {
    int i = blockIdx.x * 256 + threadIdx.x;
    if (i < n) p[i] = 0.f;
}

// ---------------- final ----------------
__global__ __launch_bounds__(256) void final_kernel(
    const float* __restrict__ xf, const float* __restrict__ lnw, const float* __restrict__ lnb,
    const float* __restrict__ user_emb, const float* __restrict__ item_emb,
    const int* __restrict__ user_ids, const int* __restrict__ item_ids, float* __restrict__ out)
{
    __shared__ float s4[4];
    int bb = blockIdx.x, t = threadIdx.x;
    float v = xf[(size_t)bb*H + t];
    float mean = blk_sum256(v, s4) * (1.f/H);
    float d = v - mean;
    float var = blk_sum256(d*d, s4) * (1.f/H);
    float lnv = d * rsqrtf(var + 1e-8f) * lnw[t] + lnb[t];
    float fin = lnv + user_emb[(size_t)user_ids[bb]*H + t];
    float prod = fin * item_emb[(size_t)item_ids[bb]*H + t];
    float tot = blk_sum256(prod, s4);
    if (t == 0) out[bb] = tot;
}

// ---------------- launch ----------------
extern "C" void kernel_launch(void* const* d_in, const int* in_sizes, int n_in,
                              void* d_out, int out_size, void* d_ws, size_t ws_size,
                              hipStream_t stream)
{
    (void)in_sizes; (void)n_in; (void)out_size; (void)ws_size;
    const int*   user_ids  = (const int*)d_in[0];
    const int*   log_seqs  = (const int*)d_in[1];
    const int*   item_ids  = (const int*)d_in[2];
    const float* item_emb  = (const float*)d_in[3];
    const float* pos_emb   = (const float*)d_in[4];
    const float* user_emb  = (const float*)d_in[5];
    const float* ln1_w     = (const float*)d_in[6];
    const float* ln1_b     = (const float*)d_in[7];
    const float* inproj_w  = (const float*)d_in[8];
    const float* inproj_b  = (const float*)d_in[9];
    const float* outproj_w = (const float*)d_in[10];
    const float* outproj_b = (const float*)d_in[11];
    const float* ln2_w     = (const float*)d_in[12];
    const float* ln2_b     = (const float*)d_in[13];
    const float* gate_w    = (const float*)d_in[14];
    const float* gate_b    = (const float*)d_in[15];
    const float* e_w1      = (const float*)d_in[16];
    const float* e_b1      = (const float*)d_in[17];
    const float* e_w2      = (const float*)d_in[18];
    const float* e_b2      = (const float*)d_in[19];
    const float* moeln_w   = (const float*)d_in[20];
    const float* moeln_b   = (const float*)d_in[21];
    const float* lastln_w  = (const float*)d_in[22];
    const float* lastln_b  = (const float*)d_in[23];

    float* ws = (float*)d_ws;
    const size_t NFH = (size_t)NF * H;
    float* buf0 = ws;
    float* buf1 = buf0 + NFH;
    float* buf2 = buf1 + NFH;
    float* buf3 = buf2 + NFH;
    float* buf4 = buf3 + NFH;
    float* s0   = buf4 + NFH;
    float* s1   = s0 + (size_t)BATCH*H;
    float* s2   = s1 + (size_t)BATCH*H;
    float* s3   = s2 + (size_t)BATCH*H;
    float* s6   = s3 + (size_t)BATCH*H;
    float* s4   = s6 + (size_t)BATCH*H;
    float* s5   = s4 + (size_t)2*BATCH*H;
    float* top_w   = s5 + (size_t)2*BATCH*H;
    int*   top_idx = (int*)(top_w + (size_t)NF*2);
    int*   pair_tok= top_idx + (size_t)NF*2;
    int*   tok_pair= pair_tok + (size_t)NF*2;
    int*   counts  = tok_pair + (size_t)NF*2;
    int*   offsets = counts + NEXP;
    int*   cursor  = offsets + NEXP;
    // bf16 split-weight regions
    const size_t W_IP = (size_t)2*3*H*H;
    const size_t W_OP = (size_t)2*H*H;
    const size_t W_E  = (size_t)2*NEXP*H*H;
    __bf16* ip_hi = (__bf16*)(cursor + 64);
    __bf16* ip_lo = ip_hi + W_IP;
    __bf16* op_hi = ip_lo + W_IP;
    __bf16* op_lo = op_hi + W_OP;
    __bf16* e1_hi = op_lo + W_OP;
    __bf16* e1_lo = e1_hi + W_E;
    __bf16* e2_hi = e1_lo + W_E;
    __bf16* e2_lo = e2_hi + W_E;

    dim3 blk(256);
    dim3 ablk(512);
    dim3 m64z3(NF/64, 1, 3);
    dim3 m64z1(NF/64, 1, 1);
    dim3 m64e(NF/64, 1, NEXP);
    dim3 msmall((BATCH+63)/64, H/64, NEXP);

    // pre-split all weights (one dispatch)
    split_all<<<2048, blk, 0, stream>>>(inproj_w, outproj_w, e_w1, e_w2,
                                        ip_hi, ip_lo, op_hi, op_lo,
                                        e1_hi, e1_lo, e2_hi, e2_lo);

    // ================= block 0 =================
    {
        const int i = 0;
        const float* bq = inproj_b + (size_t)i*3*H;
        embed_ln_kernel<<<NF, blk, 0, stream>>>(log_seqs, item_emb, pos_emb, buf0, buf1,
                                                ln1_w + i*H, ln1_b + i*H);
        mfma_z<<<m64z3, blk, 0, stream>>>(buf1, buf0, ip_hi, ip_lo, bq, buf2, NF);
        attn_kernel<<<dim3(BATCH, NHEAD, (SEQL+QT-1)/QT), ablk, 0, stream>>>(buf2, buf3, buf4, buf2, SEQL);
        mfma_z<<<m64z1, blk, 0, stream>>>(buf2, buf2, op_hi, op_lo, outproj_b, buf3, NF);
        ln2_gate_kernel<<<NF, blk, 0, stream>>>(buf1, buf3, buf0, ln2_w + i*H, ln2_b + i*H,
                                                gate_w + (size_t)i*NEXP*H, gate_b + i*NEXP,
                                                top_idx, top_w);
        zero_kernel<<<1, 32, 0, stream>>>((float*)counts, NEXP);
        count_kernel<<<(NF+255)/256, blk, 0, stream>>>(top_idx, counts, NF);
        scan_kernel<<<1, 1, 0, stream>>>(counts, offsets, cursor);
        scatter_kernel<<<(NF+255)/256, blk, 0, stream>>>(top_idx, cursor, pair_tok, tok_pair, NF);
        mfma_moe1<<<m64e, blk, 0, stream>>>(buf0, e1_hi, e1_lo, e_b1 + (size_t)i*NEXP*H,
                                            pair_tok, offsets, counts, buf3);
        mfma_moe2<<<m64e, blk, 0, stream>>>(buf3, e2_hi, e2_lo, e_b2 + (size_t)i*NEXP*H,
                                            offsets, counts, buf1);
        moe_ln_kernel<<<NF, blk, 0, stream>>>(buf0, buf1, tok_pair, top_w, buf3,
                                              moeln_w + i*H, moeln_b + i*H, 1e-5f);
    }

    // ================= block 1 : fully fused per-row chain =================
    {
        const int i = 1;
        const float* Wq = inproj_w + (size_t)i*3*H*H;
        const float* Wk = Wq + (size_t)H*H;
        const float* Wv = Wk + (size_t)H*H;
        const float* bq = inproj_b + (size_t)i*3*H;
        float* X = buf3;
        zero_kernel<<<1, 32, 0, stream>>>((float*)counts, NEXP);
        block1_fused<<<BATCH, blk, 0, stream>>>(
            X, ln1_w + i*H, ln1_b + i*H,
            Wq, bq, Wk, bq + H, Wv, bq + 2*H,
            outproj_w + (size_t)i*H*H, outproj_b + i*H,
            ln2_w + i*H, ln2_b + i*H,
            gate_w + (size_t)i*NEXP*H, gate_b + i*NEXP,
            s2, top_idx, top_w, counts);
        scan_kernel<<<1, 1, 0, stream>>>(counts, offsets, cursor);
        scatter_kernel<<<1, blk, 0, stream>>>(top_idx, cursor, pair_tok, tok_pair, BATCH);
        moe_gemm1<<<msmall, blk, 0, stream>>>(s2, e_w1 + (size_t)i*NEXP*H*H, e_b1 + (size_t)i*NEXP*H,
                                              pair_tok, offsets, counts, s4);
        moe_gemm2<<<msmall, blk, 0, stream>>>(s4, e_w2 + (size_t)i*NEXP*H*H, e_b2 + (size_t)i*NEXP*H,
                                              offsets, counts, s5);
        moe_ln_kernel<<<BATCH, blk, 0, stream>>>(s2, s5, tok_pair, top_w, s6,
                                                 moeln_w + i*H, moeln_b + i*H, 1e-5f);
    }

    final_kernel<<<BATCH, blk, 0, stream>>>(s6, lastln_w, lastln_b, user_emb, item_emb,
                                            user_ids, item_ids, (float*)d_out);
}

// Round 21
// 827.992 us; speedup vs baseline: 1.1421x; 1.0245x over previous
//
#include <hip/hip_runtime.h>
#include <math.h>

#define H 256
#define NHEAD 4
#define HD 64
#define NEXP 8
#define SEQL 200
#define BATCH 128
#define NF (BATCH*SEQL)
#define KT 64
#define QT 64
#define QW 8

typedef __bf16 bf16x8 __attribute__((ext_vector_type(8)));
typedef float  f32x4  __attribute__((ext_vector_type(4)));

__device__ __forceinline__ void split8(const float* __restrict__ p, bf16x8& hi, bf16x8& lo, bool valid) {
    if (valid) {
        float4 a = *(const float4*)p;
        float4 b = *(const float4*)(p + 4);
        float x[8] = {a.x,a.y,a.z,a.w,b.x,b.y,b.z,b.w};
        #pragma unroll
        for (int j = 0; j < 8; ++j) {
            __bf16 h = (__bf16)x[j];
            hi[j] = h;
            lo[j] = (__bf16)(x[j] - (float)h);
        }
    } else {
        #pragma unroll
        for (int j = 0; j < 8; ++j) { hi[j] = (__bf16)0.f; lo[j] = (__bf16)0.f; }
    }
}

#define MFMA3(AH,AL,BH,BL,ACC) \
    ACC = __builtin_amdgcn_mfma_f32_16x16x32_bf16(AH, BH, ACC, 0, 0, 0); \
    ACC = __builtin_amdgcn_mfma_f32_16x16x32_bf16(AH, BL, ACC, 0, 0, 0); \
    ACC = __builtin_amdgcn_mfma_f32_16x16x32_bf16(AL, BH, ACC, 0, 0, 0);

// ---------------- helpers ----------------
__device__ __forceinline__ float blk_sum256(float v, float* s4) {
    #pragma unroll
    for (int o = 32; o > 0; o >>= 1) v += __shfl_xor(v, o, 64);
    __syncthreads();
    if ((threadIdx.x & 63) == 0) s4[threadIdx.x >> 6] = v;
    __syncthreads();
    return s4[0] + s4[1] + s4[2] + s4[3];
}

// ---------------- fused weight pre-split (1 dispatch) + counts zero ----------------
__global__ __launch_bounds__(256) void split_all(
    const float* __restrict__ ipw, const float* __restrict__ opw,
    const float* __restrict__ ew1, const float* __restrict__ ew2,
    __bf16* __restrict__ ip_hi, __bf16* __restrict__ ip_lo,
    __bf16* __restrict__ op_hi, __bf16* __restrict__ op_lo,
    __bf16* __restrict__ e1_hi, __bf16* __restrict__ e1_lo,
    __bf16* __restrict__ e2_hi, __bf16* __restrict__ e2_lo,
    int* __restrict__ counts0)
{
    if (blockIdx.x == 0 && threadIdx.x < NEXP) counts0[threadIdx.x] = 0;
    const int N_IP = 2*3*H*H;
    const int N_OP = 2*H*H;
    const int N_E  = 2*NEXP*H*H;
    const int TOT  = N_IP + N_OP + 2*N_E;
    for (int i = blockIdx.x*256 + threadIdx.x; i < TOT; i += gridDim.x*256) {
        float x; __bf16 *hi, *lo; int idx;
        if (i < N_IP) {
            idx = i; x = ipw[idx]; hi = ip_hi; lo = ip_lo;
        } else if (i < N_IP + N_OP) {
            idx = i - N_IP; x = opw[idx]; hi = op_hi; lo = op_lo;
        } else if (i < N_IP + N_OP + N_E) {
            idx = i - N_IP - N_OP;
            int m = idx/(H*H), rem = idx%(H*H); int nn = rem/H, k = rem%H;
            x = ew1[(size_t)m*H*H + (size_t)k*H + nn]; hi = e1_hi; lo = e1_lo;
        } else {
            idx = i - N_IP - N_OP - N_E;
            int m = idx/(H*H), rem = idx%(H*H); int nn = rem/H, k = rem%H;
            x = ew2[(size_t)m*H*H + (size_t)k*H + nn]; hi = e2_hi; lo = e2_lo;
        }
        __bf16 h = (__bf16)x;
        hi[idx] = h;
        lo[idx] = (__bf16)(x - (float)h);
    }
}

// ---------------- fused embedding + LN1 ----------------
__global__ __launch_bounds__(256) void embed_ln_kernel(
    const int* __restrict__ seqs, const float* __restrict__ item_emb,
    const float* __restrict__ pos_emb, float* __restrict__ x,
    float* __restrict__ xln, const float* __restrict__ w, const float* __restrict__ b)
{
    __shared__ float s4[4];
    int n = blockIdx.x, t = threadIdx.x;
    int id = seqs[n];
    int pos = (id != 0) ? (n % SEQL) + 1 : 0;
    float v = item_emb[(size_t)id*H + t] * 16.0f + pos_emb[(size_t)pos*H + t];
    x[(size_t)n*H + t] = v;
    float mean = blk_sum256(v, s4) * (1.f/H);
    float d = v - mean;
    float var = blk_sum256(d*d, s4) * (1.f/H);
    xln[(size_t)n*H + t] = d * rsqrtf(var + 1e-8f) * w[t] + b[t];
}

// ---------------- fused LN2 + gate top-2 (block 0) ----------------
__global__ __launch_bounds__(256) void ln2_gate_kernel(
    const float* __restrict__ in, const float* __restrict__ res,
    float* __restrict__ out, const float* __restrict__ w, const float* __restrict__ b,
    const float* __restrict__ gw, const float* __restrict__ gb,
    int* __restrict__ top_idx, float* __restrict__ top_w)
{
    __shared__ float s4[4];
    __shared__ float xs[H];
    __shared__ float gl[NEXP];
    int n = blockIdx.x, t = threadIdx.x;
    float v = in[(size_t)n*H + t] + res[(size_t)n*H + t];
    float mean = blk_sum256(v, s4) * (1.f/H);
    float d = v - mean;
    float var = blk_sum256(d*d, s4) * (1.f/H);
    float r = d * rsqrtf(var + 1e-8f) * w[t] + b[t];
    out[(size_t)n*H + t] = r;
    xs[t] = r;
    __syncthreads();
    int wv = t >> 6, lane = t & 63;
    float xv[4];
    #pragma unroll
    for (int c = 0; c < 4; ++c) xv[c] = xs[lane + (c<<6)];
    #pragma unroll
    for (int s = 0; s < 2; ++s) {
        int e = wv*2 + s;
        float acc = 0.f;
        #pragma unroll
        for (int c = 0; c < 4; ++c) acc += xv[c] * gw[(size_t)e*H + lane + (c<<6)];
        #pragma unroll
        for (int o = 32; o > 0; o >>= 1) acc += __shfl_xor(acc, o, 64);
        if (lane == 0) gl[e] = acc + gb[e];
    }
    __syncthreads();
    if (t == 0) {
        int i0 = 0;
        for (int e = 1; e < NEXP; ++e) if (gl[e] > gl[i0]) i0 = e;
        int i1 = -1;
        for (int e = 0; e < NEXP; ++e) { if (e == i0) continue; if (i1 < 0 || gl[e] > gl[i1]) i1 = e; }
        float e1 = expf(gl[i1] - gl[i0]);
        float w0 = 1.f / (1.f + e1);
        top_idx[n*2+0] = i0; top_idx[n*2+1] = i1;
        top_w[n*2+0] = w0;  top_w[n*2+1] = 1.f - w0;
    }
}

// ---------------- fused moe combine + layernorm (block 0) ----------------
__global__ __launch_bounds__(256) void moe_ln_kernel(
    const float* __restrict__ x, const float* __restrict__ ybuf,
    const int* __restrict__ tok_pair, const float* __restrict__ top_w,
    float* __restrict__ out, const float* __restrict__ w, const float* __restrict__ b,
    float eps)
{
    __shared__ float s4[4];
    int r = blockIdx.x, t = threadIdx.x;
    int p0 = tok_pair[r*2], p1 = tok_pair[r*2+1];
    float v = x[(size_t)r*H + t]
            + top_w[r*2+0] * ybuf[(size_t)p0*H + t]
            + top_w[r*2+1] * ybuf[(size_t)p1*H + t];
    float mean = blk_sum256(v, s4) * (1.f/H);
    float d = v - mean;
    float var = blk_sum256(d*d, s4) * (1.f/H);
    out[(size_t)r*H + t] = d * rsqrtf(var + eps) * w[t] + b[t];
}

// ---------------- block-1: ENTIRE per-row attention chain in one kernel ----------------
__global__ __launch_bounds__(256) void block1_fused(
    const float* __restrict__ X,
    const float* __restrict__ ln1w, const float* __restrict__ ln1b,
    const float* __restrict__ Wq, const float* __restrict__ bq,
    const float* __restrict__ Wk, const float* __restrict__ bk,
    const float* __restrict__ Wv, const float* __restrict__ bv,
    const float* __restrict__ Wo, const float* __restrict__ bo,
    const float* __restrict__ ln2w, const float* __restrict__ ln2b,
    const float* __restrict__ gw, const float* __restrict__ gb,
    float* __restrict__ s2_out, int* __restrict__ top_idx, float* __restrict__ top_w)
{
    __shared__ float s4r[4];
    __shared__ float s0s[H];
    __shared__ float qs[H];
    __shared__ float qts[NHEAD][H];
    __shared__ float qbks[NHEAD];
    __shared__ float as_[NHEAD][SEQL];
    __shared__ float xbars[NHEAD][H];
    __shared__ float ctxs[H];
    __shared__ float gl[NEXP];
    int b = blockIdx.x, t = threadIdx.x;
    int w = t >> 6, lane = t & 63;
    // ---- LN1 on last row ----
    float v = X[(size_t)(b*SEQL + SEQL-1)*H + t];
    float mean = blk_sum256(v, s4r) * (1.f/H);
    float d = v - mean;
    float var = blk_sum256(d*d, s4r) * (1.f/H);
    float s0v = d * rsqrtf(var + 1e-8f) * ln1w[t] + ln1b[t];
    s0s[t] = s0v;
    __syncthreads();
    // ---- q = s0 @ Wq^T + bq ----
    {
        const float* wr = Wq + (size_t)t*H;
        float acc = 0.f;
        for (int dd = 0; dd < H; dd += 4) {
            float4 w4 = *(const float4*)(wr + dd);
            acc += s0s[dd]*w4.x + s0s[dd+1]*w4.y + s0s[dd+2]*w4.z + s0s[dd+3]*w4.w;
        }
        qs[t] = acc + bq[t];
    }
    __syncthreads();
    // ---- fold q through Wk ----
    #pragma unroll
    for (int h = 0; h < NHEAD; ++h) {
        float acc = 0.f;
        #pragma unroll 8
        for (int dd = 0; dd < HD; ++dd)
            acc += qs[h*HD + dd] * Wk[(size_t)(h*HD + dd)*H + t];
        qts[h][t] = acc;
    }
    if (t < NHEAD) {
        float acc = 0.f;
        for (int dd = 0; dd < HD; ++dd) acc += qs[t*HD + dd] * bk[t*HD + dd];
        qbks[t] = acc;
    }
    __syncthreads();
    // ---- folded attention: wave w = head ----
    {
        float qb = qbks[w];
        const float4 qv = *(const float4*)&qts[w][lane<<2];
        for (int key = 0; key < SEQL; ++key) {
            const float4 xv = *(const float4*)(X + (size_t)(b*SEQL + key)*H + (lane<<2));
            float p = xv.x*qv.x + xv.y*qv.y + xv.z*qv.z + xv.w*qv.w;
            #pragma unroll
            for (int o = 32; o > 0; o >>= 1) p += __shfl_xor(p, o, 64);
            if (lane == 0) as_[w][key] = (p + qb) * 0.125f;
        }
        __syncthreads();
        float m = -3e30f;
        for (int key = lane; key < SEQL; key += 64) m = fmaxf(m, as_[w][key]);
        #pragma unroll
        for (int o = 32; o > 0; o >>= 1) m = fmaxf(m, __shfl_xor(m, o, 64));
        float sum = 0.f;
        for (int key = lane; key < SEQL; key += 64) sum += expf(as_[w][key] - m);
        #pragma unroll
        for (int o = 32; o > 0; o >>= 1) sum += __shfl_xor(sum, o, 64);
        float inv = 1.f / sum;
        __syncthreads();
        for (int key = lane; key < SEQL; key += 64)
            as_[w][key] = expf(as_[w][key] - m) * inv;
        __syncthreads();
        float4 acc4 = make_float4(0.f,0.f,0.f,0.f);
        for (int key = 0; key < SEQL; ++key) {
            float a = as_[w][key];
            const float4 xv = *(const float4*)(X + (size_t)(b*SEQL + key)*H + (lane<<2));
            acc4.x += a*xv.x; acc4.y += a*xv.y; acc4.z += a*xv.z; acc4.w += a*xv.w;
        }
        *(float4*)&xbars[w][lane<<2] = acc4;
    }
    __syncthreads();
    // ---- ctx ----
    {
        int h = t >> 6;
        const float* wr = Wv + (size_t)t*H;
        float acc = 0.f;
        for (int dd = 0; dd < H; dd += 4) {
            float4 w4 = *(const float4*)(wr + dd);
            acc += xbars[h][dd]*w4.x + xbars[h][dd+1]*w4.y + xbars[h][dd+2]*w4.z + xbars[h][dd+3]*w4.w;
        }
        ctxs[t] = acc + bv[t];
    }
    __syncthreads();
    // ---- outproj ----
    float mha;
    {
        const float* wr = Wo + (size_t)t*H;
        float acc = 0.f;
        for (int dd = 0; dd < H; dd += 4) {
            float4 w4 = *(const float4*)(wr + dd);
            acc += ctxs[dd]*w4.x + ctxs[dd+1]*w4.y + ctxs[dd+2]*w4.z + ctxs[dd+3]*w4.w;
        }
        mha = acc + bo[t];
    }
    // ---- LN2 + gate ----
    float v2 = s0s[t] + mha;
    mean = blk_sum256(v2, s4r) * (1.f/H);
    d = v2 - mean;
    var = blk_sum256(d*d, s4r) * (1.f/H);
    float r = d * rsqrtf(var + 1e-8f) * ln2w[t] + ln2b[t];
    s2_out[(size_t)b*H + t] = r;
    __syncthreads();
    s0s[t] = r;
    __syncthreads();
    float xv[4];
    #pragma unroll
    for (int c = 0; c < 4; ++c) xv[c] = s0s[lane + (c<<6)];
    #pragma unroll
    for (int s = 0; s < 2; ++s) {
        int e = w*2 + s;
        float acc = 0.f;
        #pragma unroll
        for (int c = 0; c < 4; ++c) acc += xv[c] * gw[(size_t)e*H + lane + (c<<6)];
        #pragma unroll
        for (int o = 32; o > 0; o >>= 1) acc += __shfl_xor(acc, o, 64);
        if (lane == 0) gl[e] = acc + gb[e];
    }
    __syncthreads();
    if (t == 0) {
        int i0 = 0;
        for (int e = 1; e < NEXP; ++e) if (gl[e] > gl[i0]) i0 = e;
        int i1 = -1;
        for (int e = 0; e < NEXP; ++e) { if (e == i0) continue; if (i1 < 0 || gl[e] > gl[i1]) i1 = e; }
        float e1 = expf(gl[i1] - gl[i0]);
        float w0 = 1.f / (1.f + e1);
        top_idx[b*2+0] = i0; top_idx[b*2+1] = i1;
        top_w[b*2+0] = w0;  top_w[b*2+1] = 1.f - w0;
    }
}

// ---------------- block-1: per-token dense top-2 MoE + combine + LN (1 dispatch) -------
__global__ __launch_bounds__(256) void block1_moe(
    const float* __restrict__ s2, const int* __restrict__ top_idx,
    const float* __restrict__ top_w,
    const float* __restrict__ ew1, const float* __restrict__ eb1,
    const float* __restrict__ ew2, const float* __restrict__ eb2,
    const float* __restrict__ lnw, const float* __restrict__ lnb,
    float* __restrict__ out)
{
    __shared__ float s4[4];
    __shared__ float xs[H];
    __shared__ float hs[H];
    int b = blockIdx.x, t = threadIdx.x;
    xs[t] = s2[(size_t)b*H + t];
    __syncthreads();
    float comb = 0.f;
    #pragma unroll
    for (int s = 0; s < 2; ++s) {
        int e = top_idx[b*2+s];
        float wgt = top_w[b*2+s];
        const float* W1 = ew1 + (size_t)e*H*H;
        const float* W2 = ew2 + (size_t)e*H*H;
        float acc = 0.f;
        for (int k = 0; k < H; ++k) acc += xs[k] * W1[(size_t)k*H + t];
        float h = fmaxf(acc + eb1[e*H + t], 0.f);
        __syncthreads();
        hs[t] = h;
        __syncthreads();
        float acc2 = 0.f;
        for (int k = 0; k < H; ++k) acc2 += hs[k] * W2[(size_t)k*H + t];
        comb += wgt * (acc2 + eb2[e*H + t]);
    }
    float v = xs[t] + comb;
    float mean = blk_sum256(v, s4) * (1.f/H);
    float d = v - mean;
    float var = blk_sum256(d*d, s4) * (1.f/H);
    out[(size_t)b*H + t] = d * rsqrtf(var + 1e-5f) * lnw[t] + lnb[t];
}

// ---------------- split-bf16 MFMA GEMM body: 64-row stripe, ALL 4 column tiles ----------
template<int GATHER, int RELU>
__device__ __forceinline__ void mfma64_body(
    const float* __restrict__ A, const __bf16* __restrict__ Whi, const __bf16* __restrict__ Wlo,
    const float* __restrict__ bias, float* __restrict__ out, int nrows,
    const int* __restrict__ pair_tok)
{
    int r0 = blockIdx.x * 64;
    if (r0 >= nrows) return;
    int tid = threadIdx.x;
    int wid = tid >> 6, lane = tid & 63;
    int wm = wid >> 1, wn = wid & 1;
    int rbase = r0 + wm*32;
    int lr = lane & 15, lk = (lane >> 4) << 3;
    f32x4 acc[4][2][2] = {};
    int ar0 = rbase + lr, ar1 = ar0 + 16;
    bool v0 = ar0 < nrows, v1 = ar1 < nrows;
    int ga0 = ar0, ga1 = ar1;
    if (GATHER) { ga0 = v0 ? pair_tok[ar0] : 0; ga1 = v1 ? pair_tok[ar1] : 0; }
    const float* ap0 = A + (size_t)(v0 ? ga0 : 0)*H + lk;
    const float* ap1 = A + (size_t)(v1 ? ga1 : 0)*H + lk;
    size_t woff = (size_t)(wn*32 + lr)*H + lk;
    #pragma unroll
    for (int kk = 0; kk < H; kk += 32) {
        bf16x8 ah0, al0, ah1, al1;
        split8(ap0 + kk, ah0, al0, v0);
        split8(ap1 + kk, ah1, al1, v1);
        #pragma unroll
        for (int ct = 0; ct < 4; ++ct) {
            size_t wo = woff + (size_t)ct*64*H + kk;
            bf16x8 bh0 = *(const bf16x8*)(Whi + wo);
            bf16x8 bl0 = *(const bf16x8*)(Wlo + wo);
            bf16x8 bh1 = *(const bf16x8*)(Whi + wo + (size_t)16*H);
            bf16x8 bl1 = *(const bf16x8*)(Wlo + wo + (size_t)16*H);
            MFMA3(ah0, al0, bh0, bl0, acc[ct][0][0]);
            MFMA3(ah0, al0, bh1, bl1, acc[ct][0][1]);
            MFMA3(ah1, al1, bh0, bl0, acc[ct][1][0]);
            MFMA3(ah1, al1, bh1, bl1, acc[ct][1][1]);
        }
    }
    int lro = (lane >> 4) << 2;
    #pragma unroll
    for (int ct = 0; ct < 4; ++ct)
        #pragma unroll
        for (int mi = 0; mi < 2; ++mi)
            #pragma unroll
            for (int ni = 0; ni < 2; ++ni)
                #pragma unroll
                for (int j = 0; j < 4; ++j) {
                    int row = rbase + mi*16 + lro + j;
                    int col = ct*64 + wn*32 + ni*16 + lr;
                    if (row < nrows) {
                        float o = acc[ct][mi][ni][j] + bias[col];
                        if (RELU) o = fmaxf(o, 0.f);
                        out[(size_t)row*H + col] = o;
                    }
                }
}

__global__ __launch_bounds__(256) void mfma_z(
    const float* __restrict__ A0, const float* __restrict__ A1,
    const __bf16* __restrict__ Whi, const __bf16* __restrict__ Wlo,
    const float* __restrict__ biasbase, float* __restrict__ outbase, int nrows)
{
    int z = blockIdx.z;
    const float* A = (z == 0) ? A0 : A1;
    mfma64_body<0,0>(A, Whi + (size_t)z*H*H, Wlo + (size_t)z*H*H,
                     biasbase + (size_t)z*H, outbase + (size_t)z*NF*H, nrows, nullptr);
}

__global__ __launch_bounds__(256) void mfma_moe1(
    const float* __restrict__ X, const __bf16* __restrict__ Whi, const __bf16* __restrict__ Wlo,
    const float* __restrict__ b1base, const int* __restrict__ pair_tok,
    const int* __restrict__ offsets, const int* __restrict__ counts,
    float* __restrict__ hbuf)
{
    int e = blockIdx.z;
    int cnt = counts[e], off = offsets[e];
    mfma64_body<1,1>(X, Whi + (size_t)e*H*H, Wlo + (size_t)e*H*H,
                     b1base + (size_t)e*H, hbuf + (size_t)off*H, cnt, pair_tok + off);
}

__global__ __launch_bounds__(256) void mfma_moe2(
    const float* __restrict__ Hbuf, const __bf16* __restrict__ Whi, const __bf16* __restrict__ Wlo,
    const float* __restrict__ b2base, const int* __restrict__ offsets,
    const int* __restrict__ counts, float* __restrict__ ybuf)
{
    int e = blockIdx.z;
    int cnt = counts[e], off = offsets[e];
    mfma64_body<0,0>(Hbuf + (size_t)off*H, Whi + (size_t)e*H*H, Wlo + (size_t)e*H*H,
                     b2base + (size_t)e*H, ybuf + (size_t)off*H, cnt, nullptr);
}

// ---------------- flash attention — EXACT R15 kernel (proven 175us, 3D grid) ----------
__global__ __launch_bounds__(512) void attn_kernel(
    const float* __restrict__ qbuf, const float* __restrict__ kbuf,
    const float* __restrict__ vbuf, float* __restrict__ ctx, int nq)
{
    __shared__ float kv[KT*(HD+4)];
    __shared__ float qs[QT][HD+4];
    __shared__ float ps[QT][KT+4];
    int b = blockIdx.x, h = blockIdx.y, z = blockIdx.z;
    int qbase = z * QT;
    int nqt = nq - qbase;
    if (nqt <= 0) return;
    if (nqt > QT) nqt = QT;
    int tid = threadIdx.x, w = tid >> 6, lane = tid & 63;
    int off = SEQL - nq;
    for (int i = tid; i < QT*(HD/4); i += 512) {
        int row = i >> 4, c4 = (i & 15) << 2;
        float4 qv = make_float4(0.f,0.f,0.f,0.f);
        if (row < nqt) qv = *(const float4*)(qbuf + (size_t)(b*nq + qbase + row)*H + h*HD + c4);
        *(float4*)&qs[row][c4] = qv;
    }
    float m[QW], l[QW], acc[QW];
    #pragma unroll
    for (int i = 0; i < QW; ++i) { m[i] = -3e30f; l[i] = 0.f; acc[i] = 0.f; }
    int wq0 = w * QW;
    int wqn = nqt - wq0; if (wqn > QW) wqn = QW;
    int wmaxpos = qbase + wq0 + (wqn > 0 ? wqn - 1 : 0) + off;
    int ntiles = (qbase + nqt - 1 + off) / KT + 1;
    int q_sub = lane >> 3, kq = lane & 7;
    for (int t = 0; t < ntiles; ++t) {
        int kbase = t * KT;
        bool active = (wqn > 0) && (kbase <= wmaxpos);
        __syncthreads();
        for (int i = tid; i < KT*(HD/4); i += 512) {
            int row = i >> 4, c4 = (i & 15) << 2;
            int key = kbase + row;
            float4 kvv = make_float4(0.f,0.f,0.f,0.f);
            if (key < SEQL) kvv = *(const float4*)(kbuf + (size_t)(b*SEQL + key)*H + h*HD + c4);
            *(float4*)&kv[row*(HD+4) + c4] = kvv;
        }
        __syncthreads();
        if (active) {
            float s[QW];
            #pragma unroll
            for (int qi = 0; qi < QW; ++qi) s[qi] = 0.f;
            #pragma unroll 4
            for (int d4 = 0; d4 < HD; d4 += 4) {
                float4 k4 = *(const float4*)&kv[lane*(HD+4) + d4];
                #pragma unroll
                for (int qi = 0; qi < QW; ++qi) {
                    float4 q4 = *(const float4*)&qs[wq0+qi][d4];
                    s[qi] += k4.x*q4.x + k4.y*q4.y + k4.z*q4.z + k4.w*q4.w;
                }
            }
            #pragma unroll
            for (int qi = 0; qi < QW; ++qi) {
                if (qi < wqn) {
                    int qpos = qbase + wq0 + qi + off;
                    bool valid = (kbase + lane) <= qpos;
                    ps[wq0+qi][lane] = valid ? s[qi]*0.125f : -3e30f;
                }
            }
        }
        __syncthreads();
        {
            int key = kbase + lane;
            bool kval = key < SEQL;
            const float* vp = vbuf + (size_t)(b*SEQL + (kval ? key : 0))*H + h*HD;
            #pragma unroll
            for (int it = 0; it < 2; ++it) {
                int c4 = ((it << 3) + w) << 2;
                float4 vv = make_float4(0.f,0.f,0.f,0.f);
                if (kval) vv = *(const float4*)(vp + c4);
                kv[(c4+0)*(KT+4) + lane] = vv.x;
                kv[(c4+1)*(KT+4) + lane] = vv.y;
                kv[(c4+2)*(KT+4) + lane] = vv.z;
                kv[(c4+3)*(KT+4) + lane] = vv.w;
            }
        }
        __syncthreads();
        if (active) {
            float mq = m[0];
            #pragma unroll
            for (int i = 1; i < QW; ++i) if (q_sub == i) mq = m[i];
            const float2* pr = (const float2*)&ps[wq0+q_sub][kq*8];
            float2 a0 = pr[0], a1 = pr[1], a2 = pr[2], a3 = pr[3];
            float mloc = fmaxf(fmaxf(fmaxf(a0.x,a0.y), fmaxf(a1.x,a1.y)),
                               fmaxf(fmaxf(a2.x,a2.y), fmaxf(a3.x,a3.y)));
            float tm = mloc;
            #pragma unroll
            for (int o = 1; o < 8; o <<= 1) tm = fmaxf(tm, __shfl_xor(tm, o, 64));
            float mn = fmaxf(mq, tm);
            float p0 = expf(a0.x-mn), p1 = expf(a0.y-mn), p2 = expf(a1.x-mn), p3 = expf(a1.y-mn);
            float p4 = expf(a2.x-mn), p5 = expf(a2.y-mn), p6 = expf(a3.x-mn), p7 = expf(a3.y-mn);
            float psum = ((p0+p1)+(p2+p3)) + ((p4+p5)+(p6+p7));
            #pragma unroll
            for (int o = 1; o < 8; o <<= 1) psum += __shfl_xor(psum, o, 64);
            float2* pw = (float2*)&ps[wq0+q_sub][kq*8];
            pw[0] = make_float2(p0,p1); pw[1] = make_float2(p2,p3);
            pw[2] = make_float2(p4,p5); pw[3] = make_float2(p6,p7);
            #pragma unroll
            for (int qi = 0; qi < QW; ++qi) {
                float tmv = __shfl(tm, qi*8, 64);
                float psv = __shfl(psum, qi*8, 64);
                if (qi < wqn) {
                    float mn2 = fmaxf(m[qi], tmv);
                    float scl = expf(m[qi] - mn2);
                    l[qi] = l[qi]*scl + psv;
                    acc[qi] *= scl;
                    m[qi] = mn2;
                }
            }
            #pragma unroll 4
            for (int k4 = 0; k4 < KT; k4 += 4) {
                float4 v4 = *(const float4*)&kv[lane*(KT+4) + k4];
                #pragma unroll
                for (int qi = 0; qi < QW; ++qi) {
                    if (qi < wqn) {
                        float4 p4v = *(const float4*)&ps[wq0+qi][k4];
                        acc[qi] += p4v.x*v4.x + p4v.y*v4.y + p4v.z*v4.z + p4v.w*v4.w;
                    }
                }
            }
        }
    }
    #pragma unroll
    for (int qi = 0; qi < QW; ++qi) {
        if (qi < wqn) {
            ctx[(size_t)(b*nq + qbase + wq0 + qi)*H + h*HD + lane] = acc[qi] / l[qi];
        }
    }
}

// ---------------- count / scan / scatter (block 0) ----------------
__global__ __launch_bounds__(256) void count_kernel(
    const int* __restrict__ top_idx, int* __restrict__ counts, int nrows)
{
    __shared__ int hist[NEXP];
    int tid = threadIdx.x;
    if (tid < NEXP) hist[tid] = 0;
    __syncthreads();
    int n = blockIdx.x * 256 + tid;
    if (n < nrows) {
        atomicAdd(&hist[top_idx[n*2+0]], 1);
        atomicAdd(&hist[top_idx[n*2+1]], 1);
    }
    __syncthreads();
    if (tid < NEXP && hist[tid] > 0) atomicAdd(&counts[tid], hist[tid]);
}

__global__ void scan_kernel(const int* __restrict__ counts, int* __restrict__ offsets,
                            int* __restrict__ cursor)
{
    int s = 0;
    for (int e = 0; e < NEXP; ++e) { offsets[e] = s; cursor[e] = s; s += counts[e]; }
}

__global__ __launch_bounds__(256) void scatter_kernel(
    const int* __restrict__ top_idx,
    int* __restrict__ cursor, int* __restrict__ pair_tok, int* __restrict__ tok_pair, int nrows)
{
    __shared__ int lcnt[NEXP];
    __shared__ int lbase[NEXP];
    int tid = threadIdx.x;
    if (tid < NEXP) lcnt[tid] = 0;
    __syncthreads();
    int n = blockIdx.x * 256 + tid;
    int e0 = 0, e1 = 0, p0 = 0, p1 = 0;
    bool act = n < nrows;
    if (act) {
        e0 = top_idx[n*2+0]; e1 = top_idx[n*2+1];
        p0 = atomicAdd(&lcnt[e0], 1);
        p1 = atomicAdd(&lcnt[e1], 1);
    }
    __syncthreads();
    if (tid < NEXP) lbase[tid] = (lcnt[tid] > 0) ? atomicAdd(&cursor[tid], lcnt[tid]) : 0;
    __syncthreads();
    if (act) {
        int q0 = lbase[e0] + p0, q1 = lbase[e1] + p1;
        pair_tok[q0] = n; pair_tok[q1] = n;
        tok_pair[n*2+0] = q0; tok_pair[n*2+1] = q1;
    }
}

// ---------------- final ----------------
__global__ __launch_bounds__(256) void final_kernel(
    const float* __restrict__ xf, const float* __restrict__ lnw, const float* __restrict__ lnb,
    const float* __restrict__ user_emb, const float* __restrict__ item_emb,
    const int* __restrict__ user_ids, const int* __restrict__ item_ids, float* __restrict__ out)
{
    __shared__ float s4[4];
    int bb = blockIdx.x, t = threadIdx.x;
    float v = xf[(size_t)bb*H + t];
    float mean = blk_sum256(v, s4) * (1.f/H);
    float d = v - mean;
    float var = blk_sum256(d*d, s4) * (1.f/H);
    float lnv = d * rsqrtf(var + 1e-8f) * lnw[t] + lnb[t];
    float fin = lnv + user_emb[(size_t)user_ids[bb]*H + t];
    float prod = fin * item_emb[(size_t)item_ids[bb]*H + t];
    float tot = blk_sum256(prod, s4);
    if (t == 0) out[bb] = tot;
}

// ---------------- launch ----------------
extern "C" void kernel_launch(void* const* d_in, const int* in_sizes, int n_in,
                              void* d_out, int out_size, void* d_ws, size_t ws_size,
                              hipStream_t stream)
{
    (void)in_sizes; (void)n_in; (void)out_size; (void)ws_size;
    const int*   user_ids  = (const int*)d_in[0];
    const int*   log_seqs  = (const int*)d_in[1];
    const int*   item_ids  = (const int*)d_in[2];
    const float* item_emb  = (const float*)d_in[3];
    const float* pos_emb   = (const float*)d_in[4];
    const float* user_emb  = (const float*)d_in[5];
    const float* ln1_w     = (const float*)d_in[6];
    const float* ln1_b     = (const float*)d_in[7];
    const float* inproj_w  = (const float*)d_in[8];
    const float* inproj_b  = (const float*)d_in[9];
    const float* outproj_w = (const float*)d_in[10];
    const float* outproj_b = (const float*)d_in[11];
    const float* ln2_w     = (const float*)d_in[12];
    const float* ln2_b     = (const float*)d_in[13];
    const float* gate_w    = (const float*)d_in[14];
    const float* gate_b    = (const float*)d_in[15];
    const float* e_w1      = (const float*)d_in[16];
    const float* e_b1      = (const float*)d_in[17];
    const float* e_w2      = (const float*)d_in[18];
    const float* e_b2      = (const float*)d_in[19];
    const float* moeln_w   = (const float*)d_in[20];
    const float* moeln_b   = (const float*)d_in[21];
    const float* lastln_w  = (const float*)d_in[22];
    const float* lastln_b  = (const float*)d_in[23];

    float* ws = (float*)d_ws;
    const size_t NFH = (size_t)NF * H;
    float* buf0 = ws;
    float* buf1 = buf0 + NFH;
    float* buf2 = buf1 + NFH;
    float* buf3 = buf2 + NFH;
    float* buf4 = buf3 + NFH;
    float* s0   = buf4 + NFH;
    float* s1   = s0 + (size_t)BATCH*H;
    float* s2   = s1 + (size_t)BATCH*H;
    float* s3   = s2 + (size_t)BATCH*H;
    float* s6   = s3 + (size_t)BATCH*H;
    float* s4   = s6 + (size_t)BATCH*H;
    float* s5   = s4 + (size_t)2*BATCH*H;
    float* top_w   = s5 + (size_t)2*BATCH*H;
    int*   top_idx = (int*)(top_w + (size_t)NF*2);
    int*   pair_tok= top_idx + (size_t)NF*2;
    int*   tok_pair= pair_tok + (size_t)NF*2;
    int*   counts  = tok_pair + (size_t)NF*2;
    int*   offsets = counts + NEXP;
    int*   cursor  = offsets + NEXP;
    // bf16 split-weight regions
    const size_t W_IP = (size_t)2*3*H*H;
    const size_t W_OP = (size_t)2*H*H;
    const size_t W_E  = (size_t)2*NEXP*H*H;
    __bf16* ip_hi = (__bf16*)(cursor + 64);
    __bf16* ip_lo = ip_hi + W_IP;
    __bf16* op_hi = ip_lo + W_IP;
    __bf16* op_lo = op_hi + W_OP;
    __bf16* e1_hi = op_lo + W_OP;
    __bf16* e1_lo = e1_hi + W_E;
    __bf16* e2_hi = e1_lo + W_E;
    __bf16* e2_lo = e2_hi + W_E;

    dim3 blk(256);
    dim3 ablk(512);
    dim3 m64z3(NF/64, 1, 3);
    dim3 m64z1(NF/64, 1, 1);
    dim3 m64e(NF/64, 1, NEXP);

    // pre-split all weights + zero counts (one dispatch)
    split_all<<<2048, blk, 0, stream>>>(inproj_w, outproj_w, e_w1, e_w2,
                                        ip_hi, ip_lo, op_hi, op_lo,
                                        e1_hi, e1_lo, e2_hi, e2_lo, counts);

    // ================= block 0 =================
    {
        const int i = 0;
        const float* bq = inproj_b + (size_t)i*3*H;
        embed_ln_kernel<<<NF, blk, 0, stream>>>(log_seqs, item_emb, pos_emb, buf0, buf1,
                                                ln1_w + i*H, ln1_b + i*H);
        mfma_z<<<m64z3, blk, 0, stream>>>(buf1, buf0, ip_hi, ip_lo, bq, buf2, NF);
        attn_kernel<<<dim3(BATCH, NHEAD, (SEQL+QT-1)/QT), ablk, 0, stream>>>(buf2, buf3, buf4, buf2, SEQL);
        mfma_z<<<m64z1, blk, 0, stream>>>(buf2, buf2, op_hi, op_lo, outproj_b, buf3, NF);
        ln2_gate_kernel<<<NF, blk, 0, stream>>>(buf1, buf3, buf0, ln2_w + i*H, ln2_b + i*H,
                                                gate_w + (size_t)i*NEXP*H, gate_b + i*NEXP,
                                                top_idx, top_w);
        count_kernel<<<(NF+255)/256, blk, 0, stream>>>(top_idx, counts, NF);
        scan_kernel<<<1, 1, 0, stream>>>(counts, offsets, cursor);
        scatter_kernel<<<(NF+255)/256, blk, 0, stream>>>(top_idx, cursor, pair_tok, tok_pair, NF);
        mfma_moe1<<<m64e, blk, 0, stream>>>(buf0, e1_hi, e1_lo, e_b1 + (size_t)i*NEXP*H,
                                            pair_tok, offsets, counts, buf3);
        mfma_moe2<<<m64e, blk, 0, stream>>>(buf3, e2_hi, e2_lo, e_b2 + (size_t)i*NEXP*H,
                                            offsets, counts, buf1);
        moe_ln_kernel<<<NF, blk, 0, stream>>>(buf0, buf1, tok_pair, top_w, buf3,
                                              moeln_w + i*H, moeln_b + i*H, 1e-5f);
    }

    // ================= block 1 : 2 fused dispatches =================
    {
        const int i = 1;
        const float* Wq = inproj_w + (size_t)i*3*H*H;
        const float* Wk = Wq + (size_t)H*H;
        const float* Wv = Wk + (size_t)H*H;
        const float* bq = inproj_b + (size_t)i*3*H;
        float* X = buf3;
        block1_fused<<<BATCH, blk, 0, stream>>>(
            X, ln1_w + i*H, ln1_b + i*H,
            Wq, bq, Wk, bq + H, Wv, bq + 2*H,
            outproj_w + (size_t)i*H*H, outproj_b + i*H,
            ln2_w + i*H, ln2_b + i*H,
            gate_w + (size_t)i*NEXP*H, gate_b + i*NEXP,
            s2, top_idx, top_w);
        block1_moe<<<BATCH, blk, 0, stream>>>(
            s2, top_idx, top_w,
            e_w1 + (size_t)i*NEXP*H*H, e_b1 + (size_t)i*NEXP*H,
            e_w2 + (size_t)i*NEXP*H*H, e_b2 + (size_t)i*NEXP*H,
            moeln_w + i*H, moeln_b + i*H, s6);
    }

    final_kernel<<<BATCH, blk, 0, stream>>>(s6, lastln_w, lastln_b, user_emb, item_emb,
                                            user_ids, item_ids, (float*)d_out);
}